// Round 3
// baseline (523.663 us; speedup 1.0000x reference)
//
#include <hip/hip_runtime.h>
#include <math.h>

// Problem: NERRelationModel_84963043050124
// B=64 S=512 H=768 E=32 P=16 K=9 R=6 HEADS=4 C1=128 C2=64 FEAT=257
// Outputs: ner_logits [B,S,K]=294912, z [R,B,P]=6144, total [1] -> 301057 f32

#define NB 64
#define NS 512
#define NH 768
#define NE 32
#define NP 16
#define NK 9
#define NR 6
#define NHEADS 4
#define NC1 128
#define NC2 64
#define SEGS 16
#define SEGLEN 32

#define ZOFF 294912
#define TOTOFF 301056

// ---- workspace layout (float offsets) ----
#define WS_ENT   0u           // [B,E,768]  (reused: WRT/WFET/SEG after k_g1)
#define WS_HG1   1572864u     // [B,E,512]
#define WS_X1    2621440u     // [B,E,512]
#define WS_H2    3670016u     // [B,E,64]
#define WS_X2    3801088u     // [B,E,64]
#define WS_S1    3932160u     // [B,4,E]
#define WS_D1    3940352u
#define WS_S2    3948544u     // [B,E]
#define WS_D2    3950592u
#define WS_CTX   3952640u     // [B,64]
#define WS_PF    3956736u     // [B*P, 260] padded pitch
#define WS_FE    4222976u     // bf16 [B,P,512]
#define WS_CRF   4747264u     // [64]
#define WS_REL   4747328u     // [1]
#define WS_W1T   4747392u     // bf16 w1s swizzled [96][256][8] = 98304 floats
// overlapped into dead ENT region (valid after k_g1 consumed ent):
#define WS_WRT   0u           // bf16 [R*256][512] = 393216 floats
#define WS_WFET  393216u      // bf16 [512][320]   = 81920 floats
#define WS_SEG   475136u      // f32 [B][SEGS][81] = 82944 floats

typedef __attribute__((ext_vector_type(8))) short bf16x8;
typedef __attribute__((ext_vector_type(4))) float f32x4;

__device__ __forceinline__ unsigned short f2bf(float x) {
  union { float f; unsigned u; } v; v.f = x;
  unsigned r = v.u + 0x7FFFu + ((v.u >> 16) & 1u);
  return (unsigned short)(r >> 16);
}

// HW packed f32->bf16 (RNE, identical to f2bf for finite inputs)
__device__ __forceinline__ unsigned cvt2bf(float lo, float hi) {
  unsigned r;
  asm("v_cvt_pk_bf16_f32 %0, %1, %2" : "=v"(r) : "v"(lo), "v"(hi));
  return r;
}

__device__ __forceinline__ bf16x8 packbf8(float4 f0, float4 f1) {
  union { unsigned u[4]; bf16x8 v; } r;
  r.u[0] = cvt2bf(f0.x, f0.y);
  r.u[1] = cvt2bf(f0.z, f0.w);
  r.u[2] = cvt2bf(f1.x, f1.y);
  r.u[3] = cvt2bf(f1.z, f1.w);
  return r.v;
}

__device__ __forceinline__ float logsigf(float x) {
  if (x >= 0.f) return -log1pf(__expf(-x));
  return x - log1pf(__expf(x));
}

// ---------------- w_ner1 [k(768)][col(256)] -> bf16 swizzled [k>>3][col][k&7] ----------------
// Layout makes k_ner's B-frag loads lane-contiguous (lanes l15 -> consecutive 16B).
__global__ __launch_bounds__(256) void k_w1s(const float* __restrict__ w1,
    unsigned short* __restrict__ w1s) {
  const int b = blockIdx.x, t = threadIdx.x;  // b: k-group 0..95, t: col
  union { unsigned short s[8]; uint4 u; } v;
#pragma unroll
  for (int j = 0; j < 8; j++) v.s[j] = f2bf(w1[(size_t)(b * 8 + j) * 256 + t]);
  *reinterpret_cast<uint4*>(&w1s[((size_t)(b * 256) + t) * 8]) = v.u;
}

// ---------------- w_rc1 [r][k(512)][col(256)] -> bf16 [r*256+col][512] ----------------
__global__ __launch_bounds__(256) void k_wrt(const float* __restrict__ w1,
    unsigned short* __restrict__ wrt) {
  __shared__ unsigned short tr[256 * 72];
  const int r = blockIdx.x >> 3, kt = blockIdx.x & 7;
  const int k0 = kt * 64, t = threadIdx.x;
#pragma unroll
  for (int i = 0; i < 16; i++) {
    const int slot = t + 256 * i;
    const int row = slot >> 6, c4 = slot & 63;
    const float4 f = *reinterpret_cast<const float4*>(
        &w1[((size_t)(r * 512) + k0 + row) * 256 + c4 * 4]);
    tr[(c4 * 4 + 0) * 72 + row] = f2bf(f.x);
    tr[(c4 * 4 + 1) * 72 + row] = f2bf(f.y);
    tr[(c4 * 4 + 2) * 72 + row] = f2bf(f.z);
    tr[(c4 * 4 + 3) * 72 + row] = f2bf(f.w);
  }
  __syncthreads();
#pragma unroll
  for (int i = 0; i < 8; i++) {
    const int slot = t + 256 * i;
    const int col = slot >> 3, q = slot & 7;
    *reinterpret_cast<uint4*>(&wrt[((size_t)(r * 256 + col)) * 512 + k0 + q * 8]) =
        *reinterpret_cast<const uint4*>(&tr[col * 72 + q * 8]);
  }
}

// ---------------- w_fe [k(257)][col(512)] -> bf16 [col][320] ----------------
__global__ __launch_bounds__(256) void k_wfet(const float* __restrict__ w,
    unsigned short* __restrict__ wt) {
  __shared__ unsigned short tr[256 * 72];
  const int kt = blockIdx.x % 5, cb = blockIdx.x / 5;
  const int k0 = kt * 64, c0 = cb * 256, t = threadIdx.x;
#pragma unroll
  for (int i = 0; i < 16; i++) {
    const int slot = t + 256 * i;
    const int row = slot >> 6, c4 = slot & 63;
    const int k = k0 + row;
    float4 f = {0.f, 0.f, 0.f, 0.f};
    if (k < 257)
      f = *reinterpret_cast<const float4*>(&w[(size_t)k * 512 + c0 + c4 * 4]);
    tr[(c4 * 4 + 0) * 72 + row] = f2bf(f.x);
    tr[(c4 * 4 + 1) * 72 + row] = f2bf(f.y);
    tr[(c4 * 4 + 2) * 72 + row] = f2bf(f.z);
    tr[(c4 * 4 + 3) * 72 + row] = f2bf(f.w);
  }
  __syncthreads();
#pragma unroll
  for (int i = 0; i < 8; i++) {
    const int slot = t + 256 * i;
    const int col = slot >> 3, q = slot & 7;
    *reinterpret_cast<uint4*>(&wt[((size_t)(c0 + col)) * 320 + k0 + q * 8]) =
        *reinterpret_cast<const uint4*>(&tr[col * 72 + q * 8]);
  }
}

// ---------------- NER head: MFMA bf16, barrier-free / LDS-free ----------------
// 1024 single-wave blocks. Each wave owns 32 tokens x all 256 cols:
//   acc[2][16]; A rows are wave-exclusive (seq read exactly once, 100 MB);
//   B from L2-resident swizzled w1s (lane-contiguous 16B loads).
// No LDS, no barriers: compiler free to software-pipeline the fully
// unrolled K-loop with counted vmcnt (the barrier drain was the R0-R2 cap).
__global__ __launch_bounds__(64, 2) void k_ner(const float* __restrict__ seq,
    const unsigned short* __restrict__ w1s, const float* __restrict__ b1,
    const float* __restrict__ w2, const float* __restrict__ b2,
    float* __restrict__ out) {
  const int lane = threadIdx.x;
  const int quad = lane >> 4, l15 = lane & 15;
  const int tok0 = blockIdx.x * 32;

  const float* gA0 = seq + (size_t)(tok0 + l15) * NH + quad * 8;
  const float* gA1 = gA0 + (size_t)16 * NH;
  const unsigned short* gB = w1s + (quad * 256 + l15) * 8;

  f32x4 acc[2][16];
#pragma unroll
  for (int r = 0; r < 2; r++)
#pragma unroll
    for (int c = 0; c < 16; c++) acc[r][c] = (f32x4){0.f, 0.f, 0.f, 0.f};

#pragma unroll
  for (int kt = 0; kt < 24; kt++) {
    const float4 a00 = *reinterpret_cast<const float4*>(gA0 + kt * 32);
    const float4 a01 = *reinterpret_cast<const float4*>(gA0 + kt * 32 + 4);
    const float4 a10 = *reinterpret_cast<const float4*>(gA1 + kt * 32);
    const float4 a11 = *reinterpret_cast<const float4*>(gA1 + kt * 32 + 4);
    bf16x8 bfr[16];
#pragma unroll
    for (int c = 0; c < 16; c++)
      bfr[c] = *reinterpret_cast<const bf16x8*>(gB + (size_t)kt * 8192 + c * 128);
    const bf16x8 a0 = packbf8(a00, a01);
    const bf16x8 a1 = packbf8(a10, a11);
#pragma unroll
    for (int c = 0; c < 16; c++) {
      acc[0][c] = __builtin_amdgcn_mfma_f32_16x16x32_bf16(a0, bfr[c], acc[0][c], 0, 0, 0);
      acc[1][c] = __builtin_amdgcn_mfma_f32_16x16x32_bf16(a1, bfr[c], acc[1][c], 0, 0, 0);
    }
  }

  // ---- epilogue: p[tok][9] = sum over 256 cols of relu(h+b1)*w2, all in-wave ----
  float p[2][4][NK];
#pragma unroll
  for (int r = 0; r < 2; r++)
#pragma unroll
    for (int reg = 0; reg < 4; reg++)
#pragma unroll
      for (int cc = 0; cc < NK; cc++) p[r][reg][cc] = 0.f;

#pragma unroll
  for (int c = 0; c < 16; c++) {
    const int col = c * 16 + l15;
    const float b1v = b1[col];
    float w2v[NK];
#pragma unroll
    for (int cc = 0; cc < NK; cc++) w2v[cc] = w2[col * NK + cc];
#pragma unroll
    for (int r = 0; r < 2; r++)
#pragma unroll
      for (int reg = 0; reg < 4; reg++) {
        const float h = fmaxf(acc[r][c][reg] + b1v, 0.f);
#pragma unroll
        for (int cc = 0; cc < NK; cc++) p[r][reg][cc] = fmaf(h, w2v[cc], p[r][reg][cc]);
      }
  }
  // reduce over the 16 l15 lanes (cols within fragment)
#pragma unroll
  for (int o = 1; o < 16; o <<= 1)
#pragma unroll
    for (int r = 0; r < 2; r++)
#pragma unroll
      for (int reg = 0; reg < 4; reg++)
#pragma unroll
        for (int cc = 0; cc < NK; cc++) p[r][reg][cc] += __shfl_xor(p[r][reg][cc], o);
  if (l15 == 0) {
    float b2v[NK];
#pragma unroll
    for (int cc = 0; cc < NK; cc++) b2v[cc] = b2[cc];
#pragma unroll
    for (int r = 0; r < 2; r++)
#pragma unroll
      for (int reg = 0; reg < 4; reg++) {
        const int tok = tok0 + r * 16 + quad * 4 + reg;
#pragma unroll
        for (int cc = 0; cc < NK; cc++)
          out[(size_t)tok * NK + cc] = p[r][reg][cc] + b2v[cc];
      }
  }
}

// ---------------- CRF segment reduce: 32 steps -> one 9x9 log-semiring matrix ----------------
// grid NB*SEGS (1024), 128 threads.
__global__ __launch_bounds__(128) void k_crf_seg(const float* __restrict__ em,
    const int* __restrict__ mask, const float* __restrict__ trans,
    float* __restrict__ segm) {
  __shared__ float bufA[16 * 81];
  __shared__ float bufB[8 * 81];
  __shared__ float ems[SEGLEN * 9];
  __shared__ int mks[SEGLEN];
  __shared__ float trs[81];
  const int blk = blockIdx.x;
  const int b = blk >> 4, seg = blk & 15;
  const int t = threadIdx.x;
  const int s0 = 1 + seg * SEGLEN;
  const float* emb = em + (size_t)b * NS * NK;
  const int* mk = mask + b * NS;
  if (t < 81) trs[t] = trans[t];
  for (int i = t; i < SEGLEN * 9; i += 128) {
    const int g = s0 * 9 + i;
    ems[i] = (g < NS * 9) ? emb[g] : 0.f;
  }
  if (t < SEGLEN) {
    const int s = s0 + t;
    mks[t] = (s < NS) ? mk[s] : 0;
  }
  __syncthreads();
  // leaves: 16 pair matrices
  for (int idx = t; idx < 16 * 81; idx += 128) {
    const int p = idx / 81, e = idx % 81, i = e / 9, j = e % 9;
    const int la = 2 * p, lb = la + 1;
    const bool ma = mks[la] > 0, mb = mks[lb] > 0;
    float r;
    if (ma && mb) {
      float v[9], mx = -1e30f;
#pragma unroll
      for (int m = 0; m < 9; m++) {
        v[m] = trs[i * 9 + m] + ems[la * 9 + m] + trs[m * 9 + j];
        mx = fmaxf(mx, v[m]);
      }
      float sum = 0.f;
#pragma unroll
      for (int m = 0; m < 9; m++) sum += __expf(v[m] - mx);
      r = mx + __logf(sum) + ems[lb * 9 + j];
    } else if (ma) {
      r = trs[e] + ems[la * 9 + j];
    } else if (mb) {
      r = trs[e] + ems[lb * 9 + j];
    } else {
      r = (i == j) ? 0.f : -1e30f;
    }
    bufA[p * 81 + e] = r;
  }
  float* src = bufA;
  float* dst = bufB;
  for (int n = 16; n > 1; n >>= 1) {
    __syncthreads();
    const int half = n >> 1;
    for (int idx = t; idx < half * 81; idx += 128) {
      const int q = idx / 81, e = idx % 81, i = e / 9, j = e % 9;
      const float* A = src + (size_t)(2 * q) * 81;
      const float* Bm = src + (size_t)(2 * q + 1) * 81;
      float v[9], mx = -1e30f;
#pragma unroll
      for (int m = 0; m < 9; m++) {
        v[m] = A[i * 9 + m] + Bm[m * 9 + j];
        mx = fmaxf(mx, v[m]);
      }
      float sum = 0.f;
#pragma unroll
      for (int m = 0; m < 9; m++) sum += __expf(v[m] - mx);
      dst[q * 81 + e] = mx + __logf(sum);
    }
    float* tmp = src; src = dst; dst = tmp;
  }
  __syncthreads();
  if (t < 81) segm[((size_t)b * SEGS + seg) * 81 + t] = src[t];
}

// ---------------- CRF finalize: numerator + alpha chain through SEGS matrices ----------------
// grid NB, 64 threads (single wave).
__global__ __launch_bounds__(64) void k_crf_fin(const float* __restrict__ em,
    const int* __restrict__ tags, const int* __restrict__ mask,
    const float* __restrict__ startv, const float* __restrict__ endv,
    const float* __restrict__ trans, const float* __restrict__ segm,
    float* __restrict__ lossb) {
  __shared__ float sm[SEGS * 81];
  __shared__ float av[16];
  __shared__ float red[2];
  const int b = blockIdx.x, t = threadIdx.x;
  const float* emb = em + (size_t)b * NS * NK;
  const int* mk = mask + b * NS;
  const int* tg = tags + b * NS;
  for (int i = t; i < SEGS * 81; i += 64) sm[i] = segm[(size_t)b * SEGS * 81 + i];
  {
    float num = 0.f;
    int lastS = 0;
#pragma unroll
    for (int o = 0; o < 8; o++) {
      const int s = t * 8 + o;
      if (s >= 1 && mk[s] > 0) {
        const int cur = tg[s], prv = tg[s - 1];
        num += trans[prv * NK + cur] + emb[s * NK + cur];
        lastS = s;
      }
    }
#pragma unroll
    for (int o = 32; o > 0; o >>= 1) {
      num += __shfl_xor(num, o);
      lastS = max(lastS, __shfl_xor(lastS, o));
    }
    if (t == 0) {
      const int t0 = tg[0];
      red[0] = startv[t0] + emb[t0] + num + endv[tg[lastS]];
    }
  }
  __syncthreads();
  if (t < 9) av[t] = startv[t] + emb[t];
  __syncthreads();
  for (int h = 0; h < SEGS; h++) {
    float nv = 0.f;
    if (t < 9) {
      float v[9], mx = -1e30f;
#pragma unroll
      for (int i2 = 0; i2 < 9; i2++) {
        v[i2] = av[i2] + sm[h * 81 + i2 * 9 + t];
        mx = fmaxf(mx, v[i2]);
      }
      float sum = 0.f;
#pragma unroll
      for (int i2 = 0; i2 < 9; i2++) sum += __expf(v[i2] - mx);
      nv = mx + __logf(sum);
    }
    __syncthreads();
    if (t < 9) av[t] = nv;
    __syncthreads();
  }
  if (t == 0) {
    float mx = -1e30f;
#pragma unroll
    for (int j = 0; j < 9; j++) mx = fmaxf(mx, av[j] + endv[j]);
    float sum = 0.f;
#pragma unroll
    for (int j = 0; j < 9; j++) sum += __expf(av[j] + endv[j] - mx);
    lossb[b] = (mx + __logf(sum)) - red[0];
  }
}

// ---------------- entity span mean pool ----------------
__global__ __launch_bounds__(256) void k_ent(const float* __restrict__ seq,
    const int* __restrict__ est, const int* __restrict__ elen, float* __restrict__ ent) {
  const int be = blockIdx.x;
  const int b = be >> 5, e = be & 31;
  const int st = est[b * NE + e];
  int en = st + elen[b * NE + e];
  en = min(max(en, 0), NS - 1);
  const float inv = 1.f / (float)(en - st + 1);
  for (int c = threadIdx.x; c < NH; c += 256) {
    float s = 0.f;
    for (int r = st; r <= en; r++) s += seq[((size_t)b * NS + r) * NH + c];
    ent[((size_t)b * NE + e) * NH + c] = s * inv;
  }
}

// ---------------- GAT1 GEMM: h = ent @ w_gat1 (768->512) ----------------
__global__ __launch_bounds__(256) void k_g1(const float* __restrict__ ent,
    const float* __restrict__ w, float* __restrict__ hout) {
  __shared__ float As[32 * 36];
  __shared__ float Bs[32 * 128];
  const int b = blockIdx.x >> 2, cb = blockIdx.x & 3;
  const int t = threadIdx.x;
  const int tc = t & 31, tr = t >> 5;
  float acc[4][4];
#pragma unroll
  for (int i = 0; i < 4; i++)
#pragma unroll
    for (int j = 0; j < 4; j++) acc[i][j] = 0.f;
  for (int kt = 0; kt < NH; kt += 32) {
    __syncthreads();
    {
      const int e = t >> 3, k4 = t & 7;
      *reinterpret_cast<float4*>(&As[e * 36 + k4 * 4]) =
          *reinterpret_cast<const float4*>(&ent[((size_t)b * NE + e) * NH + kt + k4 * 4]);
    }
#pragma unroll
    for (int i = 0; i < 4; i++) {
      const int slot = t + 256 * i;
      const int row = slot >> 5, cg = slot & 31;
      *reinterpret_cast<float4*>(&Bs[row * 128 + cg * 4]) =
          *reinterpret_cast<const float4*>(&w[(size_t)(kt + row) * 512 + cb * 128 + cg * 4]);
    }
    __syncthreads();
#pragma unroll
    for (int kg = 0; kg < 8; kg++) {
      float4 a[4];
#pragma unroll
      for (int i = 0; i < 4; i++)
        a[i] = *reinterpret_cast<const float4*>(&As[(tr * 4 + i) * 36 + kg * 4]);
#pragma unroll
      for (int k2 = 0; k2 < 4; k2++) {
        const float4 bv = *reinterpret_cast<const float4*>(&Bs[(kg * 4 + k2) * 128 + tc * 4]);
#pragma unroll
        for (int i = 0; i < 4; i++) {
          const float av = reinterpret_cast<const float*>(&a[i])[k2];
          acc[i][0] = fmaf(av, bv.x, acc[i][0]);
          acc[i][1] = fmaf(av, bv.y, acc[i][1]);
          acc[i][2] = fmaf(av, bv.z, acc[i][2]);
          acc[i][3] = fmaf(av, bv.w, acc[i][3]);
        }
      }
    }
  }
#pragma unroll
  for (int i = 0; i < 4; i++) {
    float4 v;
    v.x = acc[i][0]; v.y = acc[i][1]; v.z = acc[i][2]; v.w = acc[i][3];
    *reinterpret_cast<float4*>(&hout[((size_t)b * NE + tr * 4 + i) * 512 + cb * 128 + tc * 4]) = v;
  }
}

// ---------------- GAT1 attention src/dst dots ----------------
__global__ __launch_bounds__(128) void k_sd1(const float* __restrict__ h,
    const float* __restrict__ as, const float* __restrict__ ad,
    float* __restrict__ s1, float* __restrict__ d1) {
  __shared__ float sm[4];
  const int be = blockIdx.x;
  const int b = be >> 5, e = be & 31;
  const int t = threadIdx.x;
  for (int hd = 0; hd < NHEADS; hd++) {
    const float v = h[((size_t)b * NE + e) * 512 + hd * NC1 + t];
    float sv = v * as[hd * NC1 + t];
    float dv = v * ad[hd * NC1 + t];
#pragma unroll
    for (int o = 32; o > 0; o >>= 1) { sv += __shfl_xor(sv, o); dv += __shfl_xor(dv, o); }
    if ((t & 63) == 0) { sm[(t >> 6) * 2] = sv; sm[(t >> 6) * 2 + 1] = dv; }
    __syncthreads();
    if (t == 0) {
      s1[(b * NHEADS + hd) * NE + e] = sm[0] + sm[2];
      d1[(b * NHEADS + hd) * NE + e] = sm[1] + sm[3];
    }
    __syncthreads();
  }
}

// ---------------- GAT1 attention + aggregate + bias + relu ----------------
__global__ __launch_bounds__(128) void k_att1(const float* __restrict__ h,
    const float* __restrict__ s1, const float* __restrict__ d1,
    const unsigned char* __restrict__ adj, const float* __restrict__ bias,
    float* __restrict__ x1) {
  __shared__ float att[NE];
  const int blk = blockIdx.x;
  const int i = blk & 31, hd = (blk >> 5) & 3, b = blk >> 7;
  const int t = threadIdx.x;
  if (t < NE) {
    float lg = d1[(b * NHEADS + hd) * NE + i] + s1[(b * NHEADS + hd) * NE + t];
    lg = lg >= 0.f ? lg : 0.2f * lg;
    if (!adj[((size_t)b * NE + i) * NE + t]) lg = -1e9f;
    att[t] = lg;
  }
  __syncthreads();
  if (t == 0) {
    float m = -1e30f;
#pragma unroll
    for (int j = 0; j < NE; j++) m = fmaxf(m, att[j]);
    float ex[NE];
    float sum = 0.f;
#pragma unroll
    for (int j = 0; j < NE; j++) { ex[j] = __expf(att[j] - m); sum += ex[j]; }
    const float inv = 1.f / sum;
#pragma unroll
    for (int j = 0; j < NE; j++) att[j] = ex[j] * inv;
  }
  __syncthreads();
  float acc = bias[hd * NC1 + t];
  for (int j = 0; j < NE; j++)
    acc += att[j] * h[((size_t)b * NE + j) * 512 + hd * NC1 + t];
  x1[((size_t)b * NE + i) * 512 + hd * NC1 + t] = fmaxf(acc, 0.f);
}

// ---------------- GAT2 GEMM + src/dst dots ----------------
__global__ __launch_bounds__(256) void k_g2(const float* __restrict__ x1,
    const float* __restrict__ w, const float* __restrict__ as, const float* __restrict__ ad,
    float* __restrict__ h2, float* __restrict__ s2, float* __restrict__ d2) {
  __shared__ float As[32 * 36];
  __shared__ float Bs[32 * 64];
  const int b = blockIdx.x;
  const int t = threadIdx.x;
  const int tc = t & 15, tr = t >> 4;
  float acc[2][4];
#pragma unroll
  for (int i = 0; i < 2; i++)
#pragma unroll
    for (int j = 0; j < 4; j++) acc[i][j] = 0.f;
  for (int kt = 0; kt < 512; kt += 32) {
    __syncthreads();
    {
      const int e = t >> 3, k4 = t & 7;
      *reinterpret_cast<float4*>(&As[e * 36 + k4 * 4]) =
          *reinterpret_cast<const float4*>(&x1[((size_t)b * NE + e) * 512 + kt + k4 * 4]);
    }
#pragma unroll
    for (int i = 0; i < 2; i++) {
      const int slot = t + 256 * i;
      const int row = slot >> 4, cg = slot & 15;
      *reinterpret_cast<float4*>(&Bs[row * 64 + cg * 4]) =
          *reinterpret_cast<const float4*>(&w[(size_t)(kt + row) * NC2 + cg * 4]);
    }
    __syncthreads();
#pragma unroll
    for (int kg = 0; kg < 8; kg++) {
      float4 a[2];
#pragma unroll
      for (int i = 0; i < 2; i++)
        a[i] = *reinterpret_cast<const float4*>(&As[(tr * 2 + i) * 36 + kg * 4]);
#pragma unroll
      for (int k2 = 0; k2 < 4; k2++) {
        const float4 bv = *reinterpret_cast<const float4*>(&Bs[(kg * 4 + k2) * 64 + tc * 4]);
#pragma unroll
        for (int i = 0; i < 2; i++) {
          const float av = reinterpret_cast<const float*>(&a[i])[k2];
          acc[i][0] = fmaf(av, bv.x, acc[i][0]);
          acc[i][1] = fmaf(av, bv.y, acc[i][1]);
          acc[i][2] = fmaf(av, bv.z, acc[i][2]);
          acc[i][3] = fmaf(av, bv.w, acc[i][3]);
        }
      }
    }
  }
  const float4 a4s = *reinterpret_cast<const float4*>(&as[tc * 4]);
  const float4 a4d = *reinterpret_cast<const float4*>(&ad[tc * 4]);
#pragma unroll
  for (int i = 0; i < 2; i++) {
    const int e = tr * 2 + i;
    float4 v;
    v.x = acc[i][0]; v.y = acc[i][1]; v.z = acc[i][2]; v.w = acc[i][3];
    *reinterpret_cast<float4*>(&h2[((size_t)b * NE + e) * NC2 + tc * 4]) = v;
    float sv = v.x * a4s.x + v.y * a4s.y + v.z * a4s.z + v.w * a4s.w;
    float dv = v.x * a4d.x + v.y * a4d.y + v.z * a4d.z + v.w * a4d.w;
#pragma unroll
    for (int o = 8; o > 0; o >>= 1) { sv += __shfl_xor(sv, o); dv += __shfl_xor(dv, o); }
    if (tc == 0) { s2[b * NE + e] = sv; d2[b * NE + e] = dv; }
  }
}

// ---------------- GAT2 attention + aggregate + bias ----------------
__global__ __launch_bounds__(64) void k_att2(const float* __restrict__ h2,
    const float* __restrict__ s2, const float* __restrict__ d2,
    const unsigned char* __restrict__ adj, const float* __restrict__ bias,
    float* __restrict__ x2) {
  __shared__ float att[NE];
  const int be = blockIdx.x;
  const int b = be >> 5, i = be & 31;
  const int t = threadIdx.x;
  if (t < NE) {
    float lg = d2[b * NE + i] + s2[b * NE + t];
    lg = lg >= 0.f ? lg : 0.2f * lg;
    if (!adj[((size_t)b * NE + i) * NE + t]) lg = -1e9f;
    att[t] = lg;
  }
  __syncthreads();
  if (t == 0) {
    float m = -1e30f;
#pragma unroll
    for (int j = 0; j < NE; j++) m = fmaxf(m, att[j]);
    float ex[NE];
    float sum = 0.f;
#pragma unroll
    for (int j = 0; j < NE; j++) { ex[j] = __expf(att[j] - m); sum += ex[j]; }
    const float inv = 1.f / sum;
#pragma unroll
    for (int j = 0; j < NE; j++) att[j] = ex[j] * inv;
  }
  __syncthreads();
  float acc = bias[t];
  for (int j = 0; j < NE; j++)
    acc += att[j] * h2[((size_t)b * NE + j) * NC2 + t];
  x2[((size_t)b * NE + i) * NC2 + t] = acc;
}

// ---------------- ctx = mean over entities ----------------
__global__ __launch_bounds__(64) void k_ctx(const float* __restrict__ x2, float* __restrict__ ctx) {
  const int b = blockIdx.x, t = threadIdx.x;
  float s = 0.f;
  for (int e = 0; e < NE; e++) s += x2[((size_t)b * NE + e) * NC2 + t];
  ctx[b * NC2 + t] = s * (1.f / NE);
}

// ---------------- pair feature build (pitch 260) ----------------
__global__ __launch_bounds__(64) void k_pf(const float* __restrict__ x2,
    const float* __restrict__ ctx, const int* __restrict__ pe1, const int* __restrict__ pe2,
    float* __restrict__ pf) {
  const int bp = blockIdx.x;
  const int b = bp >> 4, p = bp & 15;
  const int t = threadIdx.x;
  const int e1 = pe1[b * NP + p], e2 = pe2[b * NP + p];
  const float v1 = x2[((size_t)b * NE + e1) * NC2 + t];
  const float v2 = x2[((size_t)b * NE + e2) * NC2 + t];
  float* row = pf + (size_t)bp * 260;
  row[t] = v1;
  row[64 + t] = v2;
  row[128 + t] = v1 * v2;
  row[192 + t] = ctx[b * NC2 + t];
  if (t == 0) row[256] = logf(fabsf((float)(e1 - e2)) + 1.f);
  if (t < 3) row[257 + t] = 0.f;
}

// ---------------- fe = leaky(LN(pf @ w_fe + b_fe)) -- MFMA bf16, bf16 out ----------------
__global__ __launch_bounds__(256) void k_fe(const float* __restrict__ pf,
    const unsigned short* __restrict__ wt, const float* __restrict__ bfe,
    const float* __restrict__ g, const float* __restrict__ be,
    unsigned short* __restrict__ feb) {
  __shared__ unsigned short Af[16 * 320];
  __shared__ float Cs[16 * 520];
  const int b = blockIdx.x, t = threadIdx.x;
  const int w = t >> 6, lane = t & 63, quad = lane >> 4, l15 = lane & 15;
  for (int i = t; i < 16 * 320; i += 256) {
    const int p = i / 320, k = i - p * 320;
    Af[i] = (k < 260) ? f2bf(pf[(size_t)(b * NP + p) * 260 + k]) : (unsigned short)0;
  }
  __syncthreads();
  f32x4 acc[8];
#pragma unroll
  for (int c = 0; c < 8; c++) acc[c] = (f32x4){0.f, 0.f, 0.f, 0.f};
#pragma unroll
  for (int kt = 0; kt < 10; kt++) {
    const bf16x8 a = *reinterpret_cast<const bf16x8*>(&Af[l15 * 320 + kt * 32 + quad * 8]);
#pragma unroll
    for (int c = 0; c < 8; c++) {
      const int col = w * 128 + c * 16 + l15;
      const bf16x8 bv = *reinterpret_cast<const bf16x8*>(&wt[(size_t)col * 320 + kt * 32 + quad * 8]);
      acc[c] = __builtin_amdgcn_mfma_f32_16x16x32_bf16(a, bv, acc[c], 0, 0, 0);
    }
  }
#pragma unroll
  for (int c = 0; c < 8; c++)
#pragma unroll
    for (int reg = 0; reg < 4; reg++)
      Cs[(quad * 4 + reg) * 520 + w * 128 + c * 16 + l15] = acc[c][reg];
  __syncthreads();
  float bfev[8], gv[8], bev[8];
#pragma unroll
  for (int ch = 0; ch < 8; ch++) {
    const int col = ch * 64 + lane;
    bfev[ch] = bfe[col]; gv[ch] = g[col]; bev[ch] = be[col];
  }
#pragma unroll
  for (int pp = 0; pp < 4; pp++) {
    const int p = w * 4 + pp;
    float v[8], s = 0.f, sq = 0.f;
#pragma unroll
    for (int ch = 0; ch < 8; ch++) {
      v[ch] = Cs[p * 520 + ch * 64 + lane] + bfev[ch];
      s += v[ch]; sq += v[ch] * v[ch];
    }
#pragma unroll
    for (int o = 32; o > 0; o >>= 1) { s += __shfl_xor(s, o); sq += __shfl_xor(sq, o); }
    const float mean = s * (1.f / 512.f);
    const float var = sq * (1.f / 512.f) - mean * mean;
    const float rr = rsqrtf(var + 1e-5f);
#pragma unroll
    for (int ch = 0; ch < 8; ch++) {
      float n = (v[ch] - mean) * rr * gv[ch] + bev[ch];
      n = n >= 0.f ? n : 0.01f * n;
      feb[(size_t)(b * NP + p) * 512 + ch * 64 + lane] = f2bf(n);
    }
  }
}

// ---------------- relation heads: MFMA bf16 GEMM + LN + leaky + dot + BCE ----------------
__global__ __launch_bounds__(256) void k_rc(const unsigned short* __restrict__ feb,
    const unsigned short* __restrict__ wrt, const float* __restrict__ b1,
    const float* __restrict__ g, const float* __restrict__ be,
    const float* __restrict__ w2, const float* __restrict__ b2,
    const int* __restrict__ ylab, float* __restrict__ zout, float* __restrict__ relacc) {
  __shared__ unsigned short Af[16 * 520];
  __shared__ float Cs[16 * 264];
  const int blk = blockIdx.x;
  const int r = blk >> 6, b = blk & 63;
  const int t = threadIdx.x;
  const int w = t >> 6, lane = t & 63, quad = lane >> 4, l15 = lane & 15;
#pragma unroll
  for (int i = 0; i < 4; i++) {
    const int slot = t + 256 * i;
    const int p = slot >> 6, q = slot & 63;
    *reinterpret_cast<uint4*>(&Af[p * 520 + q * 8]) =
        *reinterpret_cast<const uint4*>(&feb[(size_t)(b * NP + p) * 512 + q * 8]);
  }
  __syncthreads();
  f32x4 acc[4];
#pragma unroll
  for (int c = 0; c < 4; c++) acc[c] = (f32x4){0.f, 0.f, 0.f, 0.f};
#pragma unroll
  for (int kt = 0; kt < 16; kt++) {
    const bf16x8 a = *reinterpret_cast<const bf16x8*>(&Af[l15 * 520 + kt * 32 + quad * 8]);
#pragma unroll
    for (int c = 0; c < 4; c++) {
      const int col = w * 64 + c * 16 + l15;
      const bf16x8 bv = *reinterpret_cast<const bf16x8*>(
          &wrt[(size_t)(r * 256 + col) * 512 + kt * 32 + quad * 8]);
      acc[c] = __builtin_amdgcn_mfma_f32_16x16x32_bf16(a, bv, acc[c], 0, 0, 0);
    }
  }
#pragma unroll
  for (int c = 0; c < 4; c++)
#pragma unroll
    for (int reg = 0; reg < 4; reg++)
      Cs[(quad * 4 + reg) * 264 + w * 64 + c * 16 + l15] = acc[c][reg];
  __syncthreads();
  float b1v[4], gv[4], bev[4], w2v[4];
#pragma unroll
  for (int ch = 0; ch < 4; ch++) {
    const int col = r * 256 + ch * 64 + lane;
    b1v[ch] = b1[col]; gv[ch] = g[col]; bev[ch] = be[col]; w2v[ch] = w2[col];
  }
  const float b2v = b2[r];
  float local = 0.f;
#pragma unroll
  for (int pp = 0; pp < 4; pp++) {
    const int p = w * 4 + pp;
    float v[4], s = 0.f, sq = 0.f;
#pragma unroll
    for (int ch = 0; ch < 4; ch++) {
      v[ch] = Cs[p * 264 + ch * 64 + lane] + b1v[ch];
      s += v[ch]; sq += v[ch] * v[ch];
    }
#pragma unroll
    for (int o = 32; o > 0; o >>= 1) { s += __shfl_xor(s, o); sq += __shfl_xor(sq, o); }
    const float mean = s * (1.f / 256.f);
    const float var = sq * (1.f / 256.f) - mean * mean;
    const float rr = rsqrtf(var + 1e-5f);
    float zdot = 0.f;
#pragma unroll
    for (int ch = 0; ch < 4; ch++) {
      float n = (v[ch] - mean) * rr * gv[ch] + bev[ch];
      n = n >= 0.f ? n : 0.01f * n;
      zdot = fmaf(n, w2v[ch], zdot);
    }
#pragma unroll
    for (int o = 32; o > 0; o >>= 1) zdot += __shfl_xor(zdot, o);
    if (lane == 0) {
      const float zp = zdot + b2v;
      zout[(size_t)(r * NB + b) * NP + p] = zp;
      const float y = (float)ylab[b * NP + p];
      local += -(2.f * y * logsigf(zp) + (1.f - y) * logsigf(-zp));
    }
  }
  if (lane == 0) atomicAdd(relacc, local * (1.f / (NB * NP)));
}

// ---------------- finalize total loss ----------------
__global__ __launch_bounds__(64) void k_fin(const float* __restrict__ lossb,
    const float* __restrict__ rel, float* __restrict__ out) {
  float v = lossb[threadIdx.x];
#pragma unroll
  for (int o = 32; o > 0; o >>= 1) v += __shfl_down(v, o);
  if (threadIdx.x == 0) out[TOTOFF] = v * (1.f / NB) + rel[0];
}

extern "C" void kernel_launch(void* const* d_in, const int* in_sizes, int n_in,
                              void* d_out, int out_size, void* d_ws, size_t ws_size,
                              hipStream_t stream) {
  const float* seq = (const float*)d_in[0];
  const int* amask = (const int*)d_in[1];
  const int* nlab = (const int*)d_in[2];
  const int* est = (const int*)d_in[3];
  const int* elen = (const int*)d_in[4];
  const int* pe1 = (const int*)d_in[5];
  const int* pe2 = (const int*)d_in[6];
  const int* plab = (const int*)d_in[7];
  const unsigned char* adj = (const unsigned char*)d_in[8];
  const float* w_ner1 = (const float*)d_in[9];
  const float* b_ner1 = (const float*)d_in[10];
  const float* w_ner2 = (const float*)d_in[11];
  const float* b_ner2 = (const float*)d_in[12];
  const float* crf_start = (const float*)d_in[13];
  const float* crf_end = (const float*)d_in[14];
  const float* crf_trans = (const float*)d_in[15];
  const float* w_gat1 = (const float*)d_in[16];
  const float* a_src1 = (const float*)d_in[17];
  const float* a_dst1 = (const float*)d_in[18];
  const float* b_gat1 = (const float*)d_in[19];
  const float* w_gat2 = (const float*)d_in[20];
  const float* a_src2 = (const float*)d_in[21];
  const float* a_dst2 = (const float*)d_in[22];
  const float* b_gat2 = (const float*)d_in[23];
  const float* w_fe = (const float*)d_in[24];
  const float* b_fe = (const float*)d_in[25];
  const float* g_fe = (const float*)d_in[26];
  const float* be_fe = (const float*)d_in[27];
  const float* w_rc1 = (const float*)d_in[28];
  const float* b_rc1 = (const float*)d_in[29];
  const float* g_rc = (const float*)d_in[30];
  const float* be_rc = (const float*)d_in[31];
  const float* w_rc2 = (const float*)d_in[32];
  const float* b_rc2 = (const float*)d_in[33];

  float* out = (float*)d_out;
  float* ws = (float*)d_ws;
  float* ent = ws + WS_ENT;
  float* hg1 = ws + WS_HG1;
  float* x1 = ws + WS_X1;
  float* h2 = ws + WS_H2;
  float* x2 = ws + WS_X2;
  float* s1 = ws + WS_S1;
  float* d1 = ws + WS_D1;
  float* s2 = ws + WS_S2;
  float* d2 = ws + WS_D2;
  float* ctx = ws + WS_CTX;
  float* pf = ws + WS_PF;
  float* crfb = ws + WS_CRF;
  float* rel = ws + WS_REL;
  unsigned short* w1s = (unsigned short*)(ws + WS_W1T);
  unsigned short* feb = (unsigned short*)(ws + WS_FE);
  unsigned short* wrt = (unsigned short*)(ws + WS_WRT);    // dead ENT region
  unsigned short* wfet = (unsigned short*)(ws + WS_WFET);  // dead ENT region
  float* segm = ws + WS_SEG;                               // dead ENT region

  hipMemsetAsync(rel, 0, sizeof(float), stream);

  k_w1s<<<96, 256, 0, stream>>>(w_ner1, w1s);
  k_ner<<<1024, 64, 0, stream>>>(seq, w1s, b_ner1, w_ner2, b_ner2, out);
  k_ent<<<NB * NE, 256, 0, stream>>>(seq, est, elen, ent);
  k_g1<<<NB * 4, 256, 0, stream>>>(ent, w_gat1, hg1);
  // ent is dead after k_g1 -> its region now hosts wrt/wfet/segm
  k_wrt<<<NR * 8, 256, 0, stream>>>(w_rc1, wrt);
  k_wfet<<<10, 256, 0, stream>>>(w_fe, wfet);
  k_crf_seg<<<NB * SEGS, 128, 0, stream>>>(out, amask, crf_trans, segm);
  k_crf_fin<<<NB, 64, 0, stream>>>(out, nlab, amask, crf_start, crf_end, crf_trans,
                                   segm, crfb);
  k_sd1<<<NB * NE, 128, 0, stream>>>(hg1, a_src1, a_dst1, s1, d1);
  k_att1<<<NB * NHEADS * NE, 128, 0, stream>>>(hg1, s1, d1, adj, b_gat1, x1);
  k_g2<<<NB, 256, 0, stream>>>(x1, w_gat2, a_src2, a_dst2, h2, s2, d2);
  k_att2<<<NB * NE, 64, 0, stream>>>(h2, s2, d2, adj, b_gat2, x2);
  k_ctx<<<NB, 64, 0, stream>>>(x2, ctx);
  k_pf<<<NB * NP, 64, 0, stream>>>(x2, ctx, pe1, pe2, pf);
  k_fe<<<NB, 256, 0, stream>>>(pf, wfet, b_fe, g_fe, be_fe, feb);
  k_rc<<<NR * NB, 256, 0, stream>>>(feb, wrt, b_rc1, g_rc, be_rc, w_rc2, b_rc2,
                                    plab, out + ZOFF, rel);
  k_fin<<<1, 64, 0, stream>>>(crfb, rel, out);
}

// Round 5
// 472.395 us; speedup vs baseline: 1.1085x; 1.1085x over previous
//
#include <hip/hip_runtime.h>
#include <math.h>

// Problem: NERRelationModel_84963043050124
// B=64 S=512 H=768 E=32 P=16 K=9 R=6 HEADS=4 C1=128 C2=64 FEAT=257
// Outputs: ner_logits [B,S,K]=294912, z [R,B,P]=6144, total [1] -> 301057 f32

#define NB 64
#define NS 512
#define NH 768
#define NE 32
#define NP 16
#define NK 9
#define NR 6
#define NHEADS 4
#define NC1 128
#define NC2 64
#define SEGS 16
#define SEGLEN 32

#define ZOFF 294912
#define TOTOFF 301056

// ---- workspace layout (float offsets) ----
#define WS_ENT   0u           // [B,E,768]  (reused: WRT/WFET/SEG after k_g1f)
#define WS_X1    2621440u     // [B,E,512]
#define WS_X2    3801088u     // [B,E,64]
#define WS_PF    3956736u     // [B*P, 260] padded pitch
#define WS_FE    4222976u     // bf16 [B,P,512]
#define WS_CRF   4747264u     // [64]
#define WS_REL   4747328u     // [1]
#define WS_W1T   4747392u     // bf16 [256][768] = 98304 floats
// overlapped into dead ENT region (valid after k_g1f consumed ent):
#define WS_WRT   0u           // bf16 [R*256][512] = 393216 floats
#define WS_WFET  393216u      // bf16 [512][320]   = 81920 floats
#define WS_SEG   475136u      // f32 [B][SEGS][81] = 82944 floats

typedef __attribute__((ext_vector_type(8))) short bf16x8;
typedef __attribute__((ext_vector_type(4))) float f32x4;

__device__ __forceinline__ unsigned short f2bf(float x) {
  union { float f; unsigned u; } v; v.f = x;
  unsigned r = v.u + 0x7FFFu + ((v.u >> 16) & 1u);
  return (unsigned short)(r >> 16);
}

__device__ __forceinline__ float logsigf(float x) {
  if (x >= 0.f) return -log1pf(__expf(-x));
  return x - log1pf(__expf(x));
}

// ---------------- w1 -> bf16 transposed [col][k], LDS-tiled coalesced ----------------
// 8 blocks x 32 cols. Reads float4-coalesced; writes 16B chunks.
// NOTE R4 bug fixed: uint4 = 8 shorts, so write stride must be 8 (12 iters), not 16.
__global__ __launch_bounds__(256) void k_w1t(const float* __restrict__ w1,
    unsigned short* __restrict__ w1t) {
  __shared__ unsigned short tr[32 * 776];  // [col-in-tile][k], pitch 776 (16B-aligned rows)
  const int c0 = blockIdx.x * 32;
  const int t = threadIdx.x;
#pragma unroll
  for (int p = 0; p < 24; p++) {
    const int k = p * 32 + (t >> 3), c4 = t & 7;
    const float4 f = *reinterpret_cast<const float4*>(&w1[(size_t)k * 256 + c0 + c4 * 4]);
    tr[(c4 * 4 + 0) * 776 + k] = f2bf(f.x);
    tr[(c4 * 4 + 1) * 776 + k] = f2bf(f.y);
    tr[(c4 * 4 + 2) * 776 + k] = f2bf(f.z);
    tr[(c4 * 4 + 3) * 776 + k] = f2bf(f.w);
  }
  __syncthreads();
  const int c = t >> 3, q = t & 7;  // thread: col c, 96-k chunk q
#pragma unroll
  for (int i = 0; i < 12; i++) {
    *reinterpret_cast<uint4*>(&w1t[(size_t)(c0 + c) * NH + q * 96 + i * 8]) =
        *reinterpret_cast<const uint4*>(&tr[c * 776 + q * 96 + i * 8]);
  }
}

// ---------------- fused weight converts: w_rc1 + w_fe ----------------
// blocks 0..47: w_rc1 [r][k(512)][col(256)] -> bf16 [r*256+col][512]
// blocks 48..57: w_fe [k(257)][col(512)] -> bf16 [col][320]
__global__ __launch_bounds__(256) void k_wconv(const float* __restrict__ wrc,
    const float* __restrict__ wfe, unsigned short* __restrict__ wrt,
    unsigned short* __restrict__ wfet) {
  __shared__ unsigned short tr[256 * 72];
  const int t = threadIdx.x;
  if (blockIdx.x < 48) {
    const int r = blockIdx.x >> 3, kt = blockIdx.x & 7;
    const int k0 = kt * 64;
#pragma unroll
    for (int i = 0; i < 16; i++) {
      const int slot = t + 256 * i;
      const int row = slot >> 6, c4 = slot & 63;
      const float4 f = *reinterpret_cast<const float4*>(
          &wrc[((size_t)(r * 512) + k0 + row) * 256 + c4 * 4]);
      tr[(c4 * 4 + 0) * 72 + row] = f2bf(f.x);
      tr[(c4 * 4 + 1) * 72 + row] = f2bf(f.y);
      tr[(c4 * 4 + 2) * 72 + row] = f2bf(f.z);
      tr[(c4 * 4 + 3) * 72 + row] = f2bf(f.w);
    }
    __syncthreads();
#pragma unroll
    for (int i = 0; i < 8; i++) {
      const int slot = t + 256 * i;
      const int col = slot >> 3, q = slot & 7;
      *reinterpret_cast<uint4*>(&wrt[((size_t)(r * 256 + col)) * 512 + k0 + q * 8]) =
          *reinterpret_cast<const uint4*>(&tr[col * 72 + q * 8]);
    }
  } else {
    const int bid = blockIdx.x - 48;
    const int kt = bid % 5, cb = bid / 5;
    const int k0 = kt * 64, c0 = cb * 256;
#pragma unroll
    for (int i = 0; i < 16; i++) {
      const int slot = t + 256 * i;
      const int row = slot >> 6, c4 = slot & 63;
      const int k = k0 + row;
      float4 f = {0.f, 0.f, 0.f, 0.f};
      if (k < 257)
        f = *reinterpret_cast<const float4*>(&wfe[(size_t)k * 512 + c0 + c4 * 4]);
      tr[(c4 * 4 + 0) * 72 + row] = f2bf(f.x);
      tr[(c4 * 4 + 1) * 72 + row] = f2bf(f.y);
      tr[(c4 * 4 + 2) * 72 + row] = f2bf(f.z);
      tr[(c4 * 4 + 3) * 72 + row] = f2bf(f.w);
    }
    __syncthreads();
#pragma unroll
    for (int i = 0; i < 8; i++) {
      const int slot = t + 256 * i;
      const int col = slot >> 3, q = slot & 7;
      *reinterpret_cast<uint4*>(&wfet[((size_t)(c0 + col)) * 320 + k0 + q * 8]) =
          *reinterpret_cast<const uint4*>(&tr[col * 72 + q * 8]);
    }
  }
}

// ---------------- NER head: MFMA bf16 (R0 structure -- proven best) ----------------
__global__ __launch_bounds__(256) void k_ner(const float* __restrict__ seq,
    const unsigned short* __restrict__ w1t, const float* __restrict__ b1,
    const float* __restrict__ w2, const float* __restrict__ b2,
    float* __restrict__ out) {
  __shared__ unsigned short AsS[64 * 40];
  __shared__ unsigned short BsS[256 * 40];
  __shared__ float zs[64 * 4 * 12];
  const int t = threadIdx.x;
  const int tok0 = blockIdx.x * 64;
  const int w = t >> 6, lane = t & 63, quad = lane >> 4, l15 = lane & 15;

  f32x4 acc[4][4];
#pragma unroll
  for (int r = 0; r < 4; r++)
#pragma unroll
    for (int c = 0; c < 4; c++) acc[r][c] = (f32x4){0.f, 0.f, 0.f, 0.f};

  const int tokA = t >> 2, koffA = (t & 3) * 8;
  const float* aptr = seq + (size_t)(tok0 + tokA) * NH + koffA;

  for (int kt = 0; kt < NH; kt += 32) {
    __syncthreads();
    {
      const float4 f0 = *reinterpret_cast<const float4*>(aptr + kt);
      const float4 f1 = *reinterpret_cast<const float4*>(aptr + kt + 4);
      bf16x8 av;
      av[0] = (short)f2bf(f0.x); av[1] = (short)f2bf(f0.y);
      av[2] = (short)f2bf(f0.z); av[3] = (short)f2bf(f0.w);
      av[4] = (short)f2bf(f1.x); av[5] = (short)f2bf(f1.y);
      av[6] = (short)f2bf(f1.z); av[7] = (short)f2bf(f1.w);
      *reinterpret_cast<bf16x8*>(&AsS[tokA * 40 + koffA]) = av;
    }
#pragma unroll
    for (int i = 0; i < 4; i++) {
      const int q = t + 256 * i;
      const int col = q >> 2, koff = (q & 3) * 8;
      *reinterpret_cast<uint4*>(&BsS[col * 40 + koff]) =
          *reinterpret_cast<const uint4*>(&w1t[(size_t)col * NH + kt + koff]);
    }
    __syncthreads();
    bf16x8 a[4], b[4];
#pragma unroll
    for (int r = 0; r < 4; r++)
      a[r] = *reinterpret_cast<const bf16x8*>(&AsS[(r * 16 + l15) * 40 + quad * 8]);
#pragma unroll
    for (int c = 0; c < 4; c++)
      b[c] = *reinterpret_cast<const bf16x8*>(&BsS[(w * 64 + c * 16 + l15) * 40 + quad * 8]);
#pragma unroll
    for (int r = 0; r < 4; r++)
#pragma unroll
      for (int c = 0; c < 4; c++)
        acc[r][c] = __builtin_amdgcn_mfma_f32_16x16x32_bf16(a[r], b[c], acc[r][c], 0, 0, 0);
  }

  float b1v[4], w2v[4][NK];
#pragma unroll
  for (int c = 0; c < 4; c++) {
    const int col = w * 64 + c * 16 + l15;
    b1v[c] = b1[col];
#pragma unroll
    for (int cc = 0; cc < NK; cc++) w2v[c][cc] = w2[col * NK + cc];
  }
#pragma unroll
  for (int r = 0; r < 4; r++) {
#pragma unroll
    for (int reg = 0; reg < 4; reg++) {
      float p[NK];
#pragma unroll
      for (int cc = 0; cc < NK; cc++) p[cc] = 0.f;
#pragma unroll
      for (int c = 0; c < 4; c++) {
        const float h = fmaxf(acc[r][c][reg] + b1v[c], 0.f);
#pragma unroll
        for (int cc = 0; cc < NK; cc++) p[cc] = fmaf(h, w2v[c][cc], p[cc]);
      }
#pragma unroll
      for (int o = 1; o < 16; o <<= 1)
#pragma unroll
        for (int cc = 0; cc < NK; cc++) p[cc] += __shfl_xor(p[cc], o);
      if (l15 == 0) {
        const int tokr = r * 16 + quad * 4 + reg;
#pragma unroll
        for (int cc = 0; cc < NK; cc++) zs[(tokr * 4 + w) * 12 + cc] = p[cc];
      }
    }
  }
  __syncthreads();
  if (t < 64) {
#pragma unroll
    for (int cc = 0; cc < NK; cc++) {
      const float z = zs[(t * 4 + 0) * 12 + cc] + zs[(t * 4 + 1) * 12 + cc] +
                      zs[(t * 4 + 2) * 12 + cc] + zs[(t * 4 + 3) * 12 + cc] + b2[cc];
      out[(size_t)(tok0 + t) * NK + cc] = z;
    }
  }
}

// ---------------- CRF segment reduce ----------------
__global__ __launch_bounds__(128) void k_crf_seg(const float* __restrict__ em,
    const int* __restrict__ mask, const float* __restrict__ trans,
    float* __restrict__ segm) {
  __shared__ float bufA[16 * 81];
  __shared__ float bufB[8 * 81];
  __shared__ float ems[SEGLEN * 9];
  __shared__ int mks[SEGLEN];
  __shared__ float trs[81];
  const int blk = blockIdx.x;
  const int b = blk >> 4, seg = blk & 15;
  const int t = threadIdx.x;
  const int s0 = 1 + seg * SEGLEN;
  const float* emb = em + (size_t)b * NS * NK;
  const int* mk = mask + b * NS;
  if (t < 81) trs[t] = trans[t];
  for (int i = t; i < SEGLEN * 9; i += 128) {
    const int g = s0 * 9 + i;
    ems[i] = (g < NS * 9) ? emb[g] : 0.f;
  }
  if (t < SEGLEN) {
    const int s = s0 + t;
    mks[t] = (s < NS) ? mk[s] : 0;
  }
  __syncthreads();
  for (int idx = t; idx < 16 * 81; idx += 128) {
    const int p = idx / 81, e = idx % 81, i = e / 9, j = e % 9;
    const int la = 2 * p, lb = la + 1;
    const bool ma = mks[la] > 0, mb = mks[lb] > 0;
    float r;
    if (ma && mb) {
      float v[9], mx = -1e30f;
#pragma unroll
      for (int m = 0; m < 9; m++) {
        v[m] = trs[i * 9 + m] + ems[la * 9 + m] + trs[m * 9 + j];
        mx = fmaxf(mx, v[m]);
      }
      float sum = 0.f;
#pragma unroll
      for (int m = 0; m < 9; m++) sum += __expf(v[m] - mx);
      r = mx + __logf(sum) + ems[lb * 9 + j];
    } else if (ma) {
      r = trs[e] + ems[la * 9 + j];
    } else if (mb) {
      r = trs[e] + ems[lb * 9 + j];
    } else {
      r = (i == j) ? 0.f : -1e30f;
    }
    bufA[p * 81 + e] = r;
  }
  float* src = bufA;
  float* dst = bufB;
  for (int n = 16; n > 1; n >>= 1) {
    __syncthreads();
    const int half = n >> 1;
    for (int idx = t; idx < half * 81; idx += 128) {
      const int q = idx / 81, e = idx % 81, i = e / 9, j = e % 9;
      const float* A = src + (size_t)(2 * q) * 81;
      const float* Bm = src + (size_t)(2 * q + 1) * 81;
      float v[9], mx = -1e30f;
#pragma unroll
      for (int m = 0; m < 9; m++) {
        v[m] = A[i * 9 + m] + Bm[m * 9 + j];
        mx = fmaxf(mx, v[m]);
      }
      float sum = 0.f;
#pragma unroll
      for (int m = 0; m < 9; m++) sum += __expf(v[m] - mx);
      dst[q * 81 + e] = mx + __logf(sum);
    }
    float* tmp = src; src = dst; dst = tmp;
  }
  __syncthreads();
  if (t < 81) segm[((size_t)b * SEGS + seg) * 81 + t] = src[t];
}

// ---------------- CRF finalize ----------------
__global__ __launch_bounds__(64) void k_crf_fin(const float* __restrict__ em,
    const int* __restrict__ tags, const int* __restrict__ mask,
    const float* __restrict__ startv, const float* __restrict__ endv,
    const float* __restrict__ trans, const float* __restrict__ segm,
    float* __restrict__ lossb) {
  __shared__ float sm[SEGS * 81];
  __shared__ float av[16];
  __shared__ float red[2];
  const int b = blockIdx.x, t = threadIdx.x;
  const float* emb = em + (size_t)b * NS * NK;
  const int* mk = mask + b * NS;
  const int* tg = tags + b * NS;
  for (int i = t; i < SEGS * 81; i += 64) sm[i] = segm[(size_t)b * SEGS * 81 + i];
  {
    float num = 0.f;
    int lastS = 0;
#pragma unroll
    for (int o = 0; o < 8; o++) {
      const int s = t * 8 + o;
      if (s >= 1 && mk[s] > 0) {
        const int cur = tg[s], prv = tg[s - 1];
        num += trans[prv * NK + cur] + emb[s * NK + cur];
        lastS = s;
      }
    }
#pragma unroll
    for (int o = 32; o > 0; o >>= 1) {
      num += __shfl_xor(num, o);
      lastS = max(lastS, __shfl_xor(lastS, o));
    }
    if (t == 0) {
      const int t0 = tg[0];
      red[0] = startv[t0] + emb[t0] + num + endv[tg[lastS]];
    }
  }
  __syncthreads();
  if (t < 9) av[t] = startv[t] + emb[t];
  __syncthreads();
  for (int h = 0; h < SEGS; h++) {
    float nv = 0.f;
    if (t < 9) {
      float v[9], mx = -1e30f;
#pragma unroll
      for (int i2 = 0; i2 < 9; i2++) {
        v[i2] = av[i2] + sm[h * 81 + i2 * 9 + t];
        mx = fmaxf(mx, v[i2]);
      }
      float sum = 0.f;
#pragma unroll
      for (int i2 = 0; i2 < 9; i2++) sum += __expf(v[i2] - mx);
      nv = mx + __logf(sum);
    }
    __syncthreads();
    if (t < 9) av[t] = nv;
    __syncthreads();
  }
  if (t == 0) {
    float mx = -1e30f;
#pragma unroll
    for (int j = 0; j < 9; j++) mx = fmaxf(mx, av[j] + endv[j]);
    float sum = 0.f;
#pragma unroll
    for (int j = 0; j < 9; j++) sum += __expf(av[j] + endv[j] - mx);
    lossb[b] = (mx + __logf(sum)) - red[0];
  }
}

// ---------------- entity span mean pool ----------------
__global__ __launch_bounds__(256) void k_ent(const float* __restrict__ seq,
    const int* __restrict__ est, const int* __restrict__ elen, float* __restrict__ ent) {
  const int be = blockIdx.x;
  const int b = be >> 5, e = be & 31;
  const int st = est[b * NE + e];
  int en = st + elen[b * NE + e];
  en = min(max(en, 0), NS - 1);
  const float inv = 1.f / (float)(en - st + 1);
  for (int c = threadIdx.x; c < NH; c += 256) {
    float s = 0.f;
    for (int r = st; r <= en; r++) s += seq[((size_t)b * NS + r) * NH + c];
    ent[((size_t)b * NE + e) * NH + c] = s * inv;
  }
}

// ---------------- fused GAT1: GEMM + attn dots + softmax + aggregate + relu ----------------
// block (b, head). h-tile (32e x 128c) lives entirely in-block -> no hg1/s1/d1
// round-trips, k_sd1 + k_att1 eliminated.
__global__ __launch_bounds__(256) void k_g1f(const float* __restrict__ ent,
    const float* __restrict__ w, const float* __restrict__ as,
    const float* __restrict__ ad, const unsigned char* __restrict__ adj,
    const float* __restrict__ bias, float* __restrict__ x1) {
  __shared__ float As[32 * 36];
  __shared__ float Bs[32 * 128];
  __shared__ float Hs[32 * 132];
  __shared__ float Att[32 * 32];   // [j][i]
  __shared__ float Sv[32], Dv[32];
  const int b = blockIdx.x >> 2, hd = blockIdx.x & 3;
  const int t = threadIdx.x;
  const int tc = t & 31, tr = t >> 5;
  float acc[4][4];
#pragma unroll
  for (int i = 0; i < 4; i++)
#pragma unroll
    for (int j = 0; j < 4; j++) acc[i][j] = 0.f;
  for (int kt = 0; kt < NH; kt += 32) {
    __syncthreads();
    {
      const int e = t >> 3, k4 = t & 7;
      *reinterpret_cast<float4*>(&As[e * 36 + k4 * 4]) =
          *reinterpret_cast<const float4*>(&ent[((size_t)b * NE + e) * NH + kt + k4 * 4]);
    }
#pragma unroll
    for (int i = 0; i < 4; i++) {
      const int slot = t + 256 * i;
      const int row = slot >> 5, cg = slot & 31;
      *reinterpret_cast<float4*>(&Bs[row * 128 + cg * 4]) =
          *reinterpret_cast<const float4*>(&w[(size_t)(kt + row) * 512 + hd * 128 + cg * 4]);
    }
    __syncthreads();
#pragma unroll
    for (int kg = 0; kg < 8; kg++) {
      float4 a[4];
#pragma unroll
      for (int i = 0; i < 4; i++)
        a[i] = *reinterpret_cast<const float4*>(&As[(tr * 4 + i) * 36 + kg * 4]);
#pragma unroll
      for (int k2 = 0; k2 < 4; k2++) {
        const float4 bv = *reinterpret_cast<const float4*>(&Bs[(kg * 4 + k2) * 128 + tc * 4]);
#pragma unroll
        for (int i = 0; i < 4; i++) {
          const float av = reinterpret_cast<const float*>(&a[i])[k2];
          acc[i][0] = fmaf(av, bv.x, acc[i][0]);
          acc[i][1] = fmaf(av, bv.y, acc[i][1]);
          acc[i][2] = fmaf(av, bv.z, acc[i][2]);
          acc[i][3] = fmaf(av, bv.w, acc[i][3]);
        }
      }
    }
  }
  // stage h tile
#pragma unroll
  for (int i = 0; i < 4; i++)
#pragma unroll
    for (int j = 0; j < 4; j++)
      Hs[(tr * 4 + i) * 132 + tc * 4 + j] = acc[i][j];
  __syncthreads();
  // s/d dots: 8 threads per entity, 16 cols each
  {
    const int e = t >> 3, cg = t & 7;
    float sv = 0.f, dv = 0.f;
#pragma unroll
    for (int c = 0; c < 16; c++) {
      const float h = Hs[e * 132 + cg * 16 + c];
      sv += h * as[hd * NC1 + cg * 16 + c];
      dv += h * ad[hd * NC1 + cg * 16 + c];
    }
#pragma unroll
    for (int o = 1; o < 8; o <<= 1) { sv += __shfl_xor(sv, o); dv += __shfl_xor(dv, o); }
    if (cg == 0) { Sv[e] = sv; Dv[e] = dv; }
  }
  __syncthreads();
  if (t < 32) {
    const int i = t;
    const float di = Dv[i];
    float lg[32];
    float m = -1e30f;
#pragma unroll
    for (int j = 0; j < 32; j++) {
      float v = di + Sv[j];
      v = v >= 0.f ? v : 0.2f * v;
      if (!adj[((size_t)b * NE + i) * NE + j]) v = -1e9f;
      lg[j] = v; m = fmaxf(m, v);
    }
    float sum = 0.f;
#pragma unroll
    for (int j = 0; j < 32; j++) { lg[j] = __expf(lg[j] - m); sum += lg[j]; }
    const float inv = 1.f / sum;
#pragma unroll
    for (int j = 0; j < 32; j++) Att[j * 32 + i] = lg[j] * inv;
  }
  __syncthreads();
#pragma unroll
  for (int i = 0; i < 4; i++) {
    const int row = tr * 4 + i;
    float o0 = bias[hd * NC1 + tc * 4 + 0];
    float o1 = bias[hd * NC1 + tc * 4 + 1];
    float o2 = bias[hd * NC1 + tc * 4 + 2];
    float o3 = bias[hd * NC1 + tc * 4 + 3];
#pragma unroll
    for (int j = 0; j < 32; j++) {
      const float a = Att[j * 32 + row];
      o0 = fmaf(a, Hs[j * 132 + tc * 4 + 0], o0);
      o1 = fmaf(a, Hs[j * 132 + tc * 4 + 1], o1);
      o2 = fmaf(a, Hs[j * 132 + tc * 4 + 2], o2);
      o3 = fmaf(a, Hs[j * 132 + tc * 4 + 3], o3);
    }
    float4 v;
    v.x = fmaxf(o0, 0.f); v.y = fmaxf(o1, 0.f);
    v.z = fmaxf(o2, 0.f); v.w = fmaxf(o3, 0.f);
    *reinterpret_cast<float4*>(&x1[((size_t)b * NE + row) * 512 + hd * 128 + tc * 4]) = v;
  }
}

// ---------------- fused GAT2: GEMM + dots + softmax + aggregate ----------------
// block b owns the entire 32e x 64c h2 tile -> k_att2 and h2/s2/d2 eliminated.
__global__ __launch_bounds__(256) void k_g2f(const float* __restrict__ x1,
    const float* __restrict__ w, const float* __restrict__ as,
    const float* __restrict__ ad, const unsigned char* __restrict__ adj,
    const float* __restrict__ bias, float* __restrict__ x2) {
  __shared__ float As[32 * 36];
  __shared__ float Bs[32 * 64];
  __shared__ float H2[32 * 68];
  __shared__ float Att[32 * 32];   // [j][i]
  __shared__ float Sv[32], Dv[32];
  const int b = blockIdx.x;
  const int t = threadIdx.x;
  const int tc = t & 15, tr = t >> 4;
  float acc[2][4];
#pragma unroll
  for (int i = 0; i < 2; i++)
#pragma unroll
    for (int j = 0; j < 4; j++) acc[i][j] = 0.f;
  for (int kt = 0; kt < 512; kt += 32) {
    __syncthreads();
    {
      const int e = t >> 3, k4 = t & 7;
      *reinterpret_cast<float4*>(&As[e * 36 + k4 * 4]) =
          *reinterpret_cast<const float4*>(&x1[((size_t)b * NE + e) * 512 + kt + k4 * 4]);
    }
#pragma unroll
    for (int i = 0; i < 2; i++) {
      const int slot = t + 256 * i;
      const int row = slot >> 4, cg = slot & 15;
      *reinterpret_cast<float4*>(&Bs[row * 64 + cg * 4]) =
          *reinterpret_cast<const float4*>(&w[(size_t)(kt + row) * NC2 + cg * 4]);
    }
    __syncthreads();
#pragma unroll
    for (int kg = 0; kg < 8; kg++) {
      float4 a[2];
#pragma unroll
      for (int i = 0; i < 2; i++)
        a[i] = *reinterpret_cast<const float4*>(&As[(tr * 2 + i) * 36 + kg * 4]);
#pragma unroll
      for (int k2 = 0; k2 < 4; k2++) {
        const float4 bv = *reinterpret_cast<const float4*>(&Bs[(kg * 4 + k2) * 64 + tc * 4]);
#pragma unroll
        for (int i = 0; i < 2; i++) {
          const float av = reinterpret_cast<const float*>(&a[i])[k2];
          acc[i][0] = fmaf(av, bv.x, acc[i][0]);
          acc[i][1] = fmaf(av, bv.y, acc[i][1]);
          acc[i][2] = fmaf(av, bv.z, acc[i][2]);
          acc[i][3] = fmaf(av, bv.w, acc[i][3]);
        }
      }
    }
  }
  const float4 a4s = *reinterpret_cast<const float4*>(&as[tc * 4]);
  const float4 a4d = *reinterpret_cast<const float4*>(&ad[tc * 4]);
#pragma unroll
  for (int i = 0; i < 2; i++) {
    const int e = tr * 2 + i;
    float4 v;
    v.x = acc[i][0]; v.y = acc[i][1]; v.z = acc[i][2]; v.w = acc[i][3];
    *reinterpret_cast<float4*>(&H2[e * 68 + tc * 4]) = v;
    float sv = v.x * a4s.x + v.y * a4s.y + v.z * a4s.z + v.w * a4s.w;
    float dv = v.x * a4d.x + v.y * a4d.y + v.z * a4d.z + v.w * a4d.w;
#pragma unroll
    for (int o = 8; o > 0; o >>= 1) { sv += __shfl_xor(sv, o); dv += __shfl_xor(dv, o); }
    if (tc == 0) { Sv[e] = sv; Dv[e] = dv; }
  }
  __syncthreads();
  if (t < 32) {
    const int i = t;
    const float di = Dv[i];
    float lg[32];
    float m = -1e30f;
#pragma unroll
    for (int j = 0; j < 32; j++) {
      float v = di + Sv[j];
      v = v >= 0.f ? v : 0.2f * v;
      if (!adj[((size_t)b * NE + i) * NE + j]) v = -1e9f;
      lg[j] = v; m = fmaxf(m, v);
    }
    float sum = 0.f;
#pragma unroll
    for (int j = 0; j < 32; j++) { lg[j] = __expf(lg[j] - m); sum += lg[j]; }
    const float inv = 1.f / sum;
#pragma unroll
    for (int j = 0; j < 32; j++) Att[j * 32 + i] = lg[j] * inv;
  }
  __syncthreads();
#pragma unroll
  for (int i = 0; i < 2; i++) {
    const int row = tr * 2 + i;
    float o0 = bias[tc * 4 + 0];
    float o1 = bias[tc * 4 + 1];
    float o2 = bias[tc * 4 + 2];
    float o3 = bias[tc * 4 + 3];
#pragma unroll
    for (int j = 0; j < 32; j++) {
      const float a = Att[j * 32 + row];
      o0 = fmaf(a, H2[j * 68 + tc * 4 + 0], o0);
      o1 = fmaf(a, H2[j * 68 + tc * 4 + 1], o1);
      o2 = fmaf(a, H2[j * 68 + tc * 4 + 2], o2);
      o3 = fmaf(a, H2[j * 68 + tc * 4 + 3], o3);
    }
    float4 v;
    v.x = o0; v.y = o1; v.z = o2; v.w = o3;
    *reinterpret_cast<float4*>(&x2[((size_t)b * NE + row) * NC2 + tc * 4]) = v;
  }
}

// ---------------- pair feature build (pitch 260), ctx inlined ----------------
__global__ __launch_bounds__(64) void k_pf(const float* __restrict__ x2,
    const int* __restrict__ pe1, const int* __restrict__ pe2,
    float* __restrict__ pf) {
  const int bp = blockIdx.x;
  const int b = bp >> 4, p = bp & 15;
  const int t = threadIdx.x;
  const int e1 = pe1[b * NP + p], e2 = pe2[b * NP + p];
  const float v1 = x2[((size_t)b * NE + e1) * NC2 + t];
  const float v2 = x2[((size_t)b * NE + e2) * NC2 + t];
  float cs = 0.f;
  for (int e = 0; e < NE; e++) cs += x2[((size_t)b * NE + e) * NC2 + t];
  float* row = pf + (size_t)bp * 260;
  row[t] = v1;
  row[64 + t] = v2;
  row[128 + t] = v1 * v2;
  row[192 + t] = cs * (1.f / NE);
  if (t == 0) row[256] = logf(fabsf((float)(e1 - e2)) + 1.f);
  if (t < 3) row[257 + t] = 0.f;
}

// ---------------- fe = leaky(LN(pf @ w_fe + b_fe)) -- MFMA bf16, bf16 out ----------------
__global__ __launch_bounds__(256) void k_fe(const float* __restrict__ pf,
    const unsigned short* __restrict__ wt, const float* __restrict__ bfe,
    const float* __restrict__ g, const float* __restrict__ be,
    unsigned short* __restrict__ feb) {
  __shared__ unsigned short Af[16 * 320];
  __shared__ float Cs[16 * 520];
  const int b = blockIdx.x, t = threadIdx.x;
  const int w = t >> 6, lane = t & 63, quad = lane >> 4, l15 = lane & 15;
  for (int i = t; i < 16 * 320; i += 256) {
    const int p = i / 320, k = i - p * 320;
    Af[i] = (k < 260) ? f2bf(pf[(size_t)(b * NP + p) * 260 + k]) : (unsigned short)0;
  }
  __syncthreads();
  f32x4 acc[8];
#pragma unroll
  for (int c = 0; c < 8; c++) acc[c] = (f32x4){0.f, 0.f, 0.f, 0.f};
#pragma unroll
  for (int kt = 0; kt < 10; kt++) {
    const bf16x8 a = *reinterpret_cast<const bf16x8*>(&Af[l15 * 320 + kt * 32 + quad * 8]);
#pragma unroll
    for (int c = 0; c < 8; c++) {
      const int col = w * 128 + c * 16 + l15;
      const bf16x8 bv = *reinterpret_cast<const bf16x8*>(&wt[(size_t)col * 320 + kt * 32 + quad * 8]);
      acc[c] = __builtin_amdgcn_mfma_f32_16x16x32_bf16(a, bv, acc[c], 0, 0, 0);
    }
  }
#pragma unroll
  for (int c = 0; c < 8; c++)
#pragma unroll
    for (int reg = 0; reg < 4; reg++)
      Cs[(quad * 4 + reg) * 520 + w * 128 + c * 16 + l15] = acc[c][reg];
  __syncthreads();
  float bfev[8], gv[8], bev[8];
#pragma unroll
  for (int ch = 0; ch < 8; ch++) {
    const int col = ch * 64 + lane;
    bfev[ch] = bfe[col]; gv[ch] = g[col]; bev[ch] = be[col];
  }
#pragma unroll
  for (int pp = 0; pp < 4; pp++) {
    const int p = w * 4 + pp;
    float v[8], s = 0.f, sq = 0.f;
#pragma unroll
    for (int ch = 0; ch < 8; ch++) {
      v[ch] = Cs[p * 520 + ch * 64 + lane] + bfev[ch];
      s += v[ch]; sq += v[ch] * v[ch];
    }
#pragma unroll
    for (int o = 32; o > 0; o >>= 1) { s += __shfl_xor(s, o); sq += __shfl_xor(sq, o); }
    const float mean = s * (1.f / 512.f);
    const float var = sq * (1.f / 512.f) - mean * mean;
    const float rr = rsqrtf(var + 1e-5f);
#pragma unroll
    for (int ch = 0; ch < 8; ch++) {
      float n = (v[ch] - mean) * rr * gv[ch] + bev[ch];
      n = n >= 0.f ? n : 0.01f * n;
      feb[(size_t)(b * NP + p) * 512 + ch * 64 + lane] = f2bf(n);
    }
  }
}

// ---------------- relation heads: MFMA bf16 GEMM + LN + leaky + dot + BCE ----------------
__global__ __launch_bounds__(256) void k_rc(const unsigned short* __restrict__ feb,
    const unsigned short* __restrict__ wrt, const float* __restrict__ b1,
    const float* __restrict__ g, const float* __restrict__ be,
    const float* __restrict__ w2, const float* __restrict__ b2,
    const int* __restrict__ ylab, float* __restrict__ zout, float* __restrict__ relacc) {
  __shared__ unsigned short Af[16 * 520];
  __shared__ float Cs[16 * 264];
  const int blk = blockIdx.x;
  const int r = blk >> 6, b = blk & 63;
  const int t = threadIdx.x;
  const int w = t >> 6, lane = t & 63, quad = lane >> 4, l15 = lane & 15;
#pragma unroll
  for (int i = 0; i < 4; i++) {
    const int slot = t + 256 * i;
    const int p = slot >> 6, q = slot & 63;
    *reinterpret_cast<uint4*>(&Af[p * 520 + q * 8]) =
        *reinterpret_cast<const uint4*>(&feb[(size_t)(b * NP + p) * 512 + q * 8]);
  }
  __syncthreads();
  f32x4 acc[4];
#pragma unroll
  for (int c = 0; c < 4; c++) acc[c] = (f32x4){0.f, 0.f, 0.f, 0.f};
#pragma unroll
  for (int kt = 0; kt < 16; kt++) {
    const bf16x8 a = *reinterpret_cast<const bf16x8*>(&Af[l15 * 520 + kt * 32 + quad * 8]);
#pragma unroll
    for (int c = 0; c < 4; c++) {
      const int col = w * 64 + c * 16 + l15;
      const bf16x8 bv = *reinterpret_cast<const bf16x8*>(
          &wrt[(size_t)(r * 256 + col) * 512 + kt * 32 + quad * 8]);
      acc[c] = __builtin_amdgcn_mfma_f32_16x16x32_bf16(a, bv, acc[c], 0, 0, 0);
    }
  }
#pragma unroll
  for (int c = 0; c < 4; c++)
#pragma unroll
    for (int reg = 0; reg < 4; reg++)
      Cs[(quad * 4 + reg) * 264 + w * 64 + c * 16 + l15] = acc[c][reg];
  __syncthreads();
  float b1v[4], gv[4], bev[4], w2v[4];
#pragma unroll
  for (int ch = 0; ch < 4; ch++) {
    const int col = r * 256 + ch * 64 + lane;
    b1v[ch] = b1[col]; gv[ch] = g[col]; bev[ch] = be[col]; w2v[ch] = w2[col];
  }
  const float b2v = b2[r];
  float local = 0.f;
#pragma unroll
  for (int pp = 0; pp < 4; pp++) {
    const int p = w * 4 + pp;
    float v[4], s = 0.f, sq = 0.f;
#pragma unroll
    for (int ch = 0; ch < 4; ch++) {
      v[ch] = Cs[p * 264 + ch * 64 + lane] + b1v[ch];
      s += v[ch]; sq += v[ch] * v[ch];
    }
#pragma unroll
    for (int o = 32; o > 0; o >>= 1) { s += __shfl_xor(s, o); sq += __shfl_xor(sq, o); }
    const float mean = s * (1.f / 256.f);
    const float var = sq * (1.f / 256.f) - mean * mean;
    const float rr = rsqrtf(var + 1e-5f);
    float zdot = 0.f;
#pragma unroll
    for (int ch = 0; ch < 4; ch++) {
      float n = (v[ch] - mean) * rr * gv[ch] + bev[ch];
      n = n >= 0.f ? n : 0.01f * n;
      zdot = fmaf(n, w2v[ch], zdot);
    }
#pragma unroll
    for (int o = 32; o > 0; o >>= 1) zdot += __shfl_xor(zdot, o);
    if (lane == 0) {
      const float zp = zdot + b2v;
      zout[(size_t)(r * NB + b) * NP + p] = zp;
      const float y = (float)ylab[b * NP + p];
      local += -(2.f * y * logsigf(zp) + (1.f - y) * logsigf(-zp));
    }
  }
  if (lane == 0) atomicAdd(relacc, local * (1.f / (NB * NP)));
}

// ---------------- finalize total loss ----------------
__global__ __launch_bounds__(64) void k_fin(const float* __restrict__ lossb,
    const float* __restrict__ rel, float* __restrict__ out) {
  float v = lossb[threadIdx.x];
#pragma unroll
  for (int o = 32; o > 0; o >>= 1) v += __shfl_down(v, o);
  if (threadIdx.x == 0) out[TOTOFF] = v * (1.f / NB) + rel[0];
}

extern "C" void kernel_launch(void* const* d_in, const int* in_sizes, int n_in,
                              void* d_out, int out_size, void* d_ws, size_t ws_size,
                              hipStream_t stream) {
  const float* seq = (const float*)d_in[0];
  const int* amask = (const int*)d_in[1];
  const int* nlab = (const int*)d_in[2];
  const int* est = (const int*)d_in[3];
  const int* elen = (const int*)d_in[4];
  const int* pe1 = (const int*)d_in[5];
  const int* pe2 = (const int*)d_in[6];
  const int* plab = (const int*)d_in[7];
  const unsigned char* adj = (const unsigned char*)d_in[8];
  const float* w_ner1 = (const float*)d_in[9];
  const float* b_ner1 = (const float*)d_in[10];
  const float* w_ner2 = (const float*)d_in[11];
  const float* b_ner2 = (const float*)d_in[12];
  const float* crf_start = (const float*)d_in[13];
  const float* crf_end = (const float*)d_in[14];
  const float* crf_trans = (const float*)d_in[15];
  const float* w_gat1 = (const float*)d_in[16];
  const float* a_src1 = (const float*)d_in[17];
  const float* a_dst1 = (const float*)d_in[18];
  const float* b_gat1 = (const float*)d_in[19];
  const float* w_gat2 = (const float*)d_in[20];
  const float* a_src2 = (const float*)d_in[21];
  const float* a_dst2 = (const float*)d_in[22];
  const float* b_gat2 = (const float*)d_in[23];
  const float* w_fe = (const float*)d_in[24];
  const float* b_fe = (const float*)d_in[25];
  const float* g_fe = (const float*)d_in[26];
  const float* be_fe = (const float*)d_in[27];
  const float* w_rc1 = (const float*)d_in[28];
  const float* b_rc1 = (const float*)d_in[29];
  const float* g_rc = (const float*)d_in[30];
  const float* be_rc = (const float*)d_in[31];
  const float* w_rc2 = (const float*)d_in[32];
  const float* b_rc2 = (const float*)d_in[33];

  float* out = (float*)d_out;
  float* ws = (float*)d_ws;
  float* ent = ws + WS_ENT;
  float* x1 = ws + WS_X1;
  float* x2 = ws + WS_X2;
  float* pf = ws + WS_PF;
  float* crfb = ws + WS_CRF;
  float* rel = ws + WS_REL;
  unsigned short* w1t = (unsigned short*)(ws + WS_W1T);
  unsigned short* feb = (unsigned short*)(ws + WS_FE);
  unsigned short* wrt = (unsigned short*)(ws + WS_WRT);    // dead ENT region
  unsigned short* wfet = (unsigned short*)(ws + WS_WFET);  // dead ENT region
  float* segm = ws + WS_SEG;                               // dead ENT region

  hipMemsetAsync(rel, 0, sizeof(float), stream);

  k_w1t<<<8, 256, 0, stream>>>(w_ner1, w1t);
  k_ner<<<512, 256, 0, stream>>>(seq, w1t, b_ner1, w_ner2, b_ner2, out);
  k_ent<<<NB * NE, 256, 0, stream>>>(seq, est, elen, ent);
  k_g1f<<<NB * NHEADS, 256, 0, stream>>>(ent, w_gat1, a_src1, a_dst1, adj, b_gat1, x1);
  // ent is dead after k_g1f -> its region now hosts wrt/wfet/segm
  k_wconv<<<58, 256, 0, stream>>>(w_rc1, w_fe, wrt, wfet);
  k_crf_seg<<<NB * SEGS, 128, 0, stream>>>(out, amask, crf_trans, segm);
  k_crf_fin<<<NB, 64, 0, stream>>>(out, nlab, amask, crf_start, crf_end, crf_trans,
                                   segm, crfb);
  k_g2f<<<NB, 256, 0, stream>>>(x1, w_gat2, a_src2, a_dst2, adj, b_gat2, x2);
  k_pf<<<NB * NP, 64, 0, stream>>>(x2, pe1, pe2, pf);
  k_fe<<<NB, 256, 0, stream>>>(pf, wfet, b_fe, g_fe, be_fe, feb);
  k_rc<<<NR * NB, 256, 0, stream>>>(feb, wrt, b_rc1, g_rc, be_rc, w_rc2, b_rc2,
                                    plab, out + ZOFF, rel);
  k_fin<<<1, 64, 0, stream>>>(crfb, rel, out);
}

// Round 6
// 452.020 us; speedup vs baseline: 1.1585x; 1.0451x over previous
//
#include <hip/hip_runtime.h>
#include <math.h>

// Problem: NERRelationModel_84963043050124
// B=64 S=512 H=768 E=32 P=16 K=9 R=6 HEADS=4 C1=128 C2=64 FEAT=257
// Outputs: ner_logits [B,S,K]=294912, z [R,B,P]=6144, total [1] -> 301057 f32

#define NB 64
#define NS 512
#define NH 768
#define NE 32
#define NP 16
#define NK 9
#define NR 6
#define NHEADS 4
#define NC1 128
#define NC2 64
#define SEGS 16
#define SEGLEN 32

#define ZOFF 294912
#define TOTOFF 301056

// ---- workspace layout (float offsets) ----
#define WS_ENT   0u           // bf16 entb [B,E,768] = 786432 fl  (reused: WRT/WFET/SEG after k_g1f)
#define WS_WG1T  1572864u     // bf16 wg1t [512][768] = 196608 fl
#define WS_X1    2621440u     // [B,E,512]
#define WS_X2    3801088u     // [B,E,64]
#define WS_PF    3956736u     // [B*P, 260] padded pitch
#define WS_FE    4222976u     // bf16 [B,P,512]
#define WS_CRF   4747264u     // [64]
#define WS_REL   4747328u     // [1]
#define WS_W1T   4747392u     // bf16 [256][768] = 98304 floats
// overlapped into dead ENT region (valid after k_g1f consumed entb):
#define WS_WRT   0u           // bf16 [R*256][512] = 393216 floats
#define WS_WFET  393216u      // bf16 [512][320]   = 81920 floats
#define WS_SEG   475136u      // f32 [B][SEGS][81] = 82944 floats

typedef __attribute__((ext_vector_type(8))) short bf16x8;
typedef __attribute__((ext_vector_type(4))) float f32x4;

__device__ __forceinline__ unsigned short f2bf(float x) {
  union { float f; unsigned u; } v; v.f = x;
  unsigned r = v.u + 0x7FFFu + ((v.u >> 16) & 1u);
  return (unsigned short)(r >> 16);
}

__device__ __forceinline__ float logsigf(float x) {
  if (x >= 0.f) return -log1pf(__expf(-x));
  return x - log1pf(__expf(x));
}

// ---------------- weight transpose->bf16: w_ner1 (256 cols) + w_gat1 (512 cols) ----------------
// blocks 0..7: w_ner1 [768][256] -> w1t [col][768]; blocks 8..23: w_gat1 [768][512] -> wg1t.
__global__ __launch_bounds__(256) void k_wt(const float* __restrict__ w1,
    const float* __restrict__ wg1, unsigned short* __restrict__ w1t,
    unsigned short* __restrict__ wg1t) {
  __shared__ unsigned short tr[32 * 776];  // [col-in-tile][k], pitch 776
  const int t = threadIdx.x;
  const float* src;
  unsigned short* dst;
  int c0, ncol;
  if (blockIdx.x < 8) { src = w1; dst = w1t; ncol = 256; c0 = blockIdx.x * 32; }
  else { src = wg1; dst = wg1t; ncol = 512; c0 = (blockIdx.x - 8) * 32; }
#pragma unroll
  for (int p = 0; p < 24; p++) {
    const int k = p * 32 + (t >> 3), c4 = t & 7;
    const float4 f = *reinterpret_cast<const float4*>(&src[(size_t)k * ncol + c0 + c4 * 4]);
    tr[(c4 * 4 + 0) * 776 + k] = f2bf(f.x);
    tr[(c4 * 4 + 1) * 776 + k] = f2bf(f.y);
    tr[(c4 * 4 + 2) * 776 + k] = f2bf(f.z);
    tr[(c4 * 4 + 3) * 776 + k] = f2bf(f.w);
  }
  __syncthreads();
  const int c = t >> 3, q = t & 7;  // thread: col c, 96-k chunk q
#pragma unroll
  for (int i = 0; i < 12; i++) {
    *reinterpret_cast<uint4*>(&dst[(size_t)(c0 + c) * NH + q * 96 + i * 8]) =
        *reinterpret_cast<const uint4*>(&tr[c * 776 + q * 96 + i * 8]);
  }
}

// ---------------- fused weight converts: w_rc1 + w_fe ----------------
__global__ __launch_bounds__(256) void k_wconv(const float* __restrict__ wrc,
    const float* __restrict__ wfe, unsigned short* __restrict__ wrt,
    unsigned short* __restrict__ wfet) {
  __shared__ unsigned short tr[256 * 72];
  const int t = threadIdx.x;
  if (blockIdx.x < 48) {
    const int r = blockIdx.x >> 3, kt = blockIdx.x & 7;
    const int k0 = kt * 64;
#pragma unroll
    for (int i = 0; i < 16; i++) {
      const int slot = t + 256 * i;
      const int row = slot >> 6, c4 = slot & 63;
      const float4 f = *reinterpret_cast<const float4*>(
          &wrc[((size_t)(r * 512) + k0 + row) * 256 + c4 * 4]);
      tr[(c4 * 4 + 0) * 72 + row] = f2bf(f.x);
      tr[(c4 * 4 + 1) * 72 + row] = f2bf(f.y);
      tr[(c4 * 4 + 2) * 72 + row] = f2bf(f.z);
      tr[(c4 * 4 + 3) * 72 + row] = f2bf(f.w);
    }
    __syncthreads();
#pragma unroll
    for (int i = 0; i < 8; i++) {
      const int slot = t + 256 * i;
      const int col = slot >> 3, q = slot & 7;
      *reinterpret_cast<uint4*>(&wrt[((size_t)(r * 256 + col)) * 512 + k0 + q * 8]) =
          *reinterpret_cast<const uint4*>(&tr[col * 72 + q * 8]);
    }
  } else {
    const int bid = blockIdx.x - 48;
    const int kt = bid % 5, cb = bid / 5;
    const int k0 = kt * 64, c0 = cb * 256;
#pragma unroll
    for (int i = 0; i < 16; i++) {
      const int slot = t + 256 * i;
      const int row = slot >> 6, c4 = slot & 63;
      const int k = k0 + row;
      float4 f = {0.f, 0.f, 0.f, 0.f};
      if (k < 257)
        f = *reinterpret_cast<const float4*>(&wfe[(size_t)k * 512 + c0 + c4 * 4]);
      tr[(c4 * 4 + 0) * 72 + row] = f2bf(f.x);
      tr[(c4 * 4 + 1) * 72 + row] = f2bf(f.y);
      tr[(c4 * 4 + 2) * 72 + row] = f2bf(f.z);
      tr[(c4 * 4 + 3) * 72 + row] = f2bf(f.w);
    }
    __syncthreads();
#pragma unroll
    for (int i = 0; i < 8; i++) {
      const int slot = t + 256 * i;
      const int col = slot >> 3, q = slot & 7;
      *reinterpret_cast<uint4*>(&wfet[((size_t)(c0 + col)) * 320 + k0 + q * 8]) =
          *reinterpret_cast<const uint4*>(&tr[col * 72 + q * 8]);
    }
  }
}

// ---------------- NER head: MFMA bf16 (R0 structure -- proven best) ----------------
__global__ __launch_bounds__(256) void k_ner(const float* __restrict__ seq,
    const unsigned short* __restrict__ w1t, const float* __restrict__ b1,
    const float* __restrict__ w2, const float* __restrict__ b2,
    float* __restrict__ out) {
  __shared__ unsigned short AsS[64 * 40];
  __shared__ unsigned short BsS[256 * 40];
  __shared__ float zs[64 * 4 * 12];
  const int t = threadIdx.x;
  const int tok0 = blockIdx.x * 64;
  const int w = t >> 6, lane = t & 63, quad = lane >> 4, l15 = lane & 15;

  f32x4 acc[4][4];
#pragma unroll
  for (int r = 0; r < 4; r++)
#pragma unroll
    for (int c = 0; c < 4; c++) acc[r][c] = (f32x4){0.f, 0.f, 0.f, 0.f};

  const int tokA = t >> 2, koffA = (t & 3) * 8;
  const float* aptr = seq + (size_t)(tok0 + tokA) * NH + koffA;

  for (int kt = 0; kt < NH; kt += 32) {
    __syncthreads();
    {
      const float4 f0 = *reinterpret_cast<const float4*>(aptr + kt);
      const float4 f1 = *reinterpret_cast<const float4*>(aptr + kt + 4);
      bf16x8 av;
      av[0] = (short)f2bf(f0.x); av[1] = (short)f2bf(f0.y);
      av[2] = (short)f2bf(f0.z); av[3] = (short)f2bf(f0.w);
      av[4] = (short)f2bf(f1.x); av[5] = (short)f2bf(f1.y);
      av[6] = (short)f2bf(f1.z); av[7] = (short)f2bf(f1.w);
      *reinterpret_cast<bf16x8*>(&AsS[tokA * 40 + koffA]) = av;
    }
#pragma unroll
    for (int i = 0; i < 4; i++) {
      const int q = t + 256 * i;
      const int col = q >> 2, koff = (q & 3) * 8;
      *reinterpret_cast<uint4*>(&BsS[col * 40 + koff]) =
          *reinterpret_cast<const uint4*>(&w1t[(size_t)col * NH + kt + koff]);
    }
    __syncthreads();
    bf16x8 a[4], b[4];
#pragma unroll
    for (int r = 0; r < 4; r++)
      a[r] = *reinterpret_cast<const bf16x8*>(&AsS[(r * 16 + l15) * 40 + quad * 8]);
#pragma unroll
    for (int c = 0; c < 4; c++)
      b[c] = *reinterpret_cast<const bf16x8*>(&BsS[(w * 64 + c * 16 + l15) * 40 + quad * 8]);
#pragma unroll
    for (int r = 0; r < 4; r++)
#pragma unroll
      for (int c = 0; c < 4; c++)
        acc[r][c] = __builtin_amdgcn_mfma_f32_16x16x32_bf16(a[r], b[c], acc[r][c], 0, 0, 0);
  }

  float b1v[4], w2v[4][NK];
#pragma unroll
  for (int c = 0; c < 4; c++) {
    const int col = w * 64 + c * 16 + l15;
    b1v[c] = b1[col];
#pragma unroll
    for (int cc = 0; cc < NK; cc++) w2v[c][cc] = w2[col * NK + cc];
  }
#pragma unroll
  for (int r = 0; r < 4; r++) {
#pragma unroll
    for (int reg = 0; reg < 4; reg++) {
      float p[NK];
#pragma unroll
      for (int cc = 0; cc < NK; cc++) p[cc] = 0.f;
#pragma unroll
      for (int c = 0; c < 4; c++) {
        const float h = fmaxf(acc[r][c][reg] + b1v[c], 0.f);
#pragma unroll
        for (int cc = 0; cc < NK; cc++) p[cc] = fmaf(h, w2v[c][cc], p[cc]);
      }
#pragma unroll
      for (int o = 1; o < 16; o <<= 1)
#pragma unroll
        for (int cc = 0; cc < NK; cc++) p[cc] += __shfl_xor(p[cc], o);
      if (l15 == 0) {
        const int tokr = r * 16 + quad * 4 + reg;
#pragma unroll
        for (int cc = 0; cc < NK; cc++) zs[(tokr * 4 + w) * 12 + cc] = p[cc];
      }
    }
  }
  __syncthreads();
  if (t < 64) {
#pragma unroll
    for (int cc = 0; cc < NK; cc++) {
      const float z = zs[(t * 4 + 0) * 12 + cc] + zs[(t * 4 + 1) * 12 + cc] +
                      zs[(t * 4 + 2) * 12 + cc] + zs[(t * 4 + 3) * 12 + cc] + b2[cc];
      out[(size_t)(tok0 + t) * NK + cc] = z;
    }
  }
}

// ---------------- CRF segment reduce ----------------
__global__ __launch_bounds__(128) void k_crf_seg(const float* __restrict__ em,
    const int* __restrict__ mask, const float* __restrict__ trans,
    float* __restrict__ segm) {
  __shared__ float bufA[16 * 81];
  __shared__ float bufB[8 * 81];
  __shared__ float ems[SEGLEN * 9];
  __shared__ int mks[SEGLEN];
  __shared__ float trs[81];
  const int blk = blockIdx.x;
  const int b = blk >> 4, seg = blk & 15;
  const int t = threadIdx.x;
  const int s0 = 1 + seg * SEGLEN;
  const float* emb = em + (size_t)b * NS * NK;
  const int* mk = mask + b * NS;
  if (t < 81) trs[t] = trans[t];
  for (int i = t; i < SEGLEN * 9; i += 128) {
    const int g = s0 * 9 + i;
    ems[i] = (g < NS * 9) ? emb[g] : 0.f;
  }
  if (t < SEGLEN) {
    const int s = s0 + t;
    mks[t] = (s < NS) ? mk[s] : 0;
  }
  __syncthreads();
  for (int idx = t; idx < 16 * 81; idx += 128) {
    const int p = idx / 81, e = idx % 81, i = e / 9, j = e % 9;
    const int la = 2 * p, lb = la + 1;
    const bool ma = mks[la] > 0, mb = mks[lb] > 0;
    float r;
    if (ma && mb) {
      float v[9], mx = -1e30f;
#pragma unroll
      for (int m = 0; m < 9; m++) {
        v[m] = trs[i * 9 + m] + ems[la * 9 + m] + trs[m * 9 + j];
        mx = fmaxf(mx, v[m]);
      }
      float sum = 0.f;
#pragma unroll
      for (int m = 0; m < 9; m++) sum += __expf(v[m] - mx);
      r = mx + __logf(sum) + ems[lb * 9 + j];
    } else if (ma) {
      r = trs[e] + ems[la * 9 + j];
    } else if (mb) {
      r = trs[e] + ems[lb * 9 + j];
    } else {
      r = (i == j) ? 0.f : -1e30f;
    }
    bufA[p * 81 + e] = r;
  }
  float* src = bufA;
  float* dst = bufB;
  for (int n = 16; n > 1; n >>= 1) {
    __syncthreads();
    const int half = n >> 1;
    for (int idx = t; idx < half * 81; idx += 128) {
      const int q = idx / 81, e = idx % 81, i = e / 9, j = e % 9;
      const float* A = src + (size_t)(2 * q) * 81;
      const float* Bm = src + (size_t)(2 * q + 1) * 81;
      float v[9], mx = -1e30f;
#pragma unroll
      for (int m = 0; m < 9; m++) {
        v[m] = A[i * 9 + m] + Bm[m * 9 + j];
        mx = fmaxf(mx, v[m]);
      }
      float sum = 0.f;
#pragma unroll
      for (int m = 0; m < 9; m++) sum += __expf(v[m] - mx);
      dst[q * 81 + e] = mx + __logf(sum);
    }
    float* tmp = src; src = dst; dst = tmp;
  }
  __syncthreads();
  if (t < 81) segm[((size_t)b * SEGS + seg) * 81 + t] = src[t];
}

// ---------------- CRF finalize ----------------
__global__ __launch_bounds__(64) void k_crf_fin(const float* __restrict__ em,
    const int* __restrict__ tags, const int* __restrict__ mask,
    const float* __restrict__ startv, const float* __restrict__ endv,
    const float* __restrict__ trans, const float* __restrict__ segm,
    float* __restrict__ lossb) {
  __shared__ float sm[SEGS * 81];
  __shared__ float av[16];
  __shared__ float red[2];
  const int b = blockIdx.x, t = threadIdx.x;
  const float* emb = em + (size_t)b * NS * NK;
  const int* mk = mask + b * NS;
  const int* tg = tags + b * NS;
  for (int i = t; i < SEGS * 81; i += 64) sm[i] = segm[(size_t)b * SEGS * 81 + i];
  {
    float num = 0.f;
    int lastS = 0;
#pragma unroll
    for (int o = 0; o < 8; o++) {
      const int s = t * 8 + o;
      if (s >= 1 && mk[s] > 0) {
        const int cur = tg[s], prv = tg[s - 1];
        num += trans[prv * NK + cur] + emb[s * NK + cur];
        lastS = s;
      }
    }
#pragma unroll
    for (int o = 32; o > 0; o >>= 1) {
      num += __shfl_xor(num, o);
      lastS = max(lastS, __shfl_xor(lastS, o));
    }
    if (t == 0) {
      const int t0 = tg[0];
      red[0] = startv[t0] + emb[t0] + num + endv[tg[lastS]];
    }
  }
  __syncthreads();
  if (t < 9) av[t] = startv[t] + emb[t];
  __syncthreads();
  for (int h = 0; h < SEGS; h++) {
    float nv = 0.f;
    if (t < 9) {
      float v[9], mx = -1e30f;
#pragma unroll
      for (int i2 = 0; i2 < 9; i2++) {
        v[i2] = av[i2] + sm[h * 81 + i2 * 9 + t];
        mx = fmaxf(mx, v[i2]);
      }
      float sum = 0.f;
#pragma unroll
      for (int i2 = 0; i2 < 9; i2++) sum += __expf(v[i2] - mx);
      nv = mx + __logf(sum);
    }
    __syncthreads();
    if (t < 9) av[t] = nv;
    __syncthreads();
  }
  if (t == 0) {
    float mx = -1e30f;
#pragma unroll
    for (int j = 0; j < 9; j++) mx = fmaxf(mx, av[j] + endv[j]);
    float sum = 0.f;
#pragma unroll
    for (int j = 0; j < 9; j++) sum += __expf(av[j] + endv[j] - mx);
    lossb[b] = (mx + __logf(sum)) - red[0];
  }
}

// ---------------- entity span mean pool -> bf16 ----------------
__global__ __launch_bounds__(256) void k_ent(const float* __restrict__ seq,
    const int* __restrict__ est, const int* __restrict__ elen,
    unsigned short* __restrict__ entb) {
  const int be = blockIdx.x;
  const int b = be >> 5, e = be & 31;
  const int st = est[b * NE + e];
  int en = st + elen[b * NE + e];
  en = min(max(en, 0), NS - 1);
  const float inv = 1.f / (float)(en - st + 1);
  for (int c = threadIdx.x; c < NH; c += 256) {
    float s = 0.f;
    for (int r = st; r <= en; r++) s += seq[((size_t)b * NS + r) * NH + c];
    entb[((size_t)b * NE + e) * NH + c] = f2bf(s * inv);
  }
}

// ---------------- fused GAT1: MFMA bf16 GEMM + attn dots + softmax + aggregate + relu ----------------
// block (b, head). GEMM now on matrix cores (k_ner pattern): acc[2][2] per wave,
// wave w owns cols w*32..w*32+31. Attention phases unchanged (fp32).
__global__ __launch_bounds__(256) void k_g1f(const unsigned short* __restrict__ entb,
    const unsigned short* __restrict__ wg1t, const float* __restrict__ as,
    const float* __restrict__ ad, const unsigned char* __restrict__ adj,
    const float* __restrict__ bias, float* __restrict__ x1) {
  __shared__ unsigned short As[32 * 40];
  __shared__ unsigned short Bs[128 * 40];
  __shared__ float Hs[32 * 132];
  __shared__ float Att[32 * 32];   // [j][i]
  __shared__ float Sv[32], Dv[32];
  const int b = blockIdx.x >> 2, hd = blockIdx.x & 3;
  const int t = threadIdx.x;
  const int w = t >> 6, lane = t & 63, quad = lane >> 4, l15 = lane & 15;

  f32x4 acc[2][2];
#pragma unroll
  for (int r = 0; r < 2; r++)
#pragma unroll
    for (int c = 0; c < 2; c++) acc[r][c] = (f32x4){0.f, 0.f, 0.f, 0.f};

  const int rowA = t >> 2, koffA = (t & 3) * 8;  // t<128 stages A
  const unsigned short* aptr = entb + ((size_t)(b * NE) + rowA) * NH + koffA;

  for (int kt = 0; kt < NH; kt += 32) {
    __syncthreads();
    if (t < 128) {
      *reinterpret_cast<uint4*>(&As[rowA * 40 + koffA]) =
          *reinterpret_cast<const uint4*>(aptr + kt);
    }
#pragma unroll
    for (int i = 0; i < 2; i++) {
      const int q = t + 256 * i;
      const int col = q >> 2, koff = (q & 3) * 8;
      *reinterpret_cast<uint4*>(&Bs[col * 40 + koff]) =
          *reinterpret_cast<const uint4*>(&wg1t[(size_t)(hd * 128 + col) * NH + kt + koff]);
    }
    __syncthreads();
    bf16x8 a[2], bb[2];
#pragma unroll
    for (int r = 0; r < 2; r++)
      a[r] = *reinterpret_cast<const bf16x8*>(&As[(r * 16 + l15) * 40 + quad * 8]);
#pragma unroll
    for (int c = 0; c < 2; c++)
      bb[c] = *reinterpret_cast<const bf16x8*>(&Bs[(w * 32 + c * 16 + l15) * 40 + quad * 8]);
#pragma unroll
    for (int r = 0; r < 2; r++)
#pragma unroll
      for (int c = 0; c < 2; c++)
        acc[r][c] = __builtin_amdgcn_mfma_f32_16x16x32_bf16(a[r], bb[c], acc[r][c], 0, 0, 0);
  }
  // stage h tile: row = rf*16 + quad*4 + reg, col = w*32 + cf*16 + l15
#pragma unroll
  for (int r = 0; r < 2; r++)
#pragma unroll
    for (int c = 0; c < 2; c++)
#pragma unroll
      for (int reg = 0; reg < 4; reg++)
        Hs[(r * 16 + quad * 4 + reg) * 132 + w * 32 + c * 16 + l15] = acc[r][c][reg];
  __syncthreads();
  // s/d dots: 8 threads per entity, 16 cols each
  {
    const int e = t >> 3, cg = t & 7;
    float sv = 0.f, dv = 0.f;
#pragma unroll
    for (int c = 0; c < 16; c++) {
      const float h = Hs[e * 132 + cg * 16 + c];
      sv += h * as[hd * NC1 + cg * 16 + c];
      dv += h * ad[hd * NC1 + cg * 16 + c];
    }
#pragma unroll
    for (int o = 1; o < 8; o <<= 1) { sv += __shfl_xor(sv, o); dv += __shfl_xor(dv, o); }
    if (cg == 0) { Sv[e] = sv; Dv[e] = dv; }
  }
  __syncthreads();
  if (t < 32) {
    const int i = t;
    const float di = Dv[i];
    float lg[32];
    float m = -1e30f;
#pragma unroll
    for (int j = 0; j < 32; j++) {
      float v = di + Sv[j];
      v = v >= 0.f ? v : 0.2f * v;
      if (!adj[((size_t)b * NE + i) * NE + j]) v = -1e9f;
      lg[j] = v; m = fmaxf(m, v);
    }
    float sum = 0.f;
#pragma unroll
    for (int j = 0; j < 32; j++) { lg[j] = __expf(lg[j] - m); sum += lg[j]; }
    const float inv = 1.f / sum;
#pragma unroll
    for (int j = 0; j < 32; j++) Att[j * 32 + i] = lg[j] * inv;
  }
  __syncthreads();
  {
    const int tc = t & 31, tr = t >> 5;
#pragma unroll
    for (int i = 0; i < 4; i++) {
      const int row = tr * 4 + i;
      float o0 = bias[hd * NC1 + tc * 4 + 0];
      float o1 = bias[hd * NC1 + tc * 4 + 1];
      float o2 = bias[hd * NC1 + tc * 4 + 2];
      float o3 = bias[hd * NC1 + tc * 4 + 3];
#pragma unroll
      for (int j = 0; j < 32; j++) {
        const float a = Att[j * 32 + row];
        o0 = fmaf(a, Hs[j * 132 + tc * 4 + 0], o0);
        o1 = fmaf(a, Hs[j * 132 + tc * 4 + 1], o1);
        o2 = fmaf(a, Hs[j * 132 + tc * 4 + 2], o2);
        o3 = fmaf(a, Hs[j * 132 + tc * 4 + 3], o3);
      }
      float4 v;
      v.x = fmaxf(o0, 0.f); v.y = fmaxf(o1, 0.f);
      v.z = fmaxf(o2, 0.f); v.w = fmaxf(o3, 0.f);
      *reinterpret_cast<float4*>(&x1[((size_t)b * NE + row) * 512 + hd * 128 + tc * 4]) = v;
    }
  }
}

// ---------------- fused GAT2: GEMM + dots + softmax + aggregate ----------------
__global__ __launch_bounds__(256) void k_g2f(const float* __restrict__ x1,
    const float* __restrict__ w, const float* __restrict__ as,
    const float* __restrict__ ad, const unsigned char* __restrict__ adj,
    const float* __restrict__ bias, float* __restrict__ x2) {
  __shared__ float As[32 * 36];
  __shared__ float Bs[32 * 64];
  __shared__ float H2[32 * 68];
  __shared__ float Att[32 * 32];   // [j][i]
  __shared__ float Sv[32], Dv[32];
  const int b = blockIdx.x;
  const int t = threadIdx.x;
  const int tc = t & 15, tr = t >> 4;
  float acc[2][4];
#pragma unroll
  for (int i = 0; i < 2; i++)
#pragma unroll
    for (int j = 0; j < 4; j++) acc[i][j] = 0.f;
  for (int kt = 0; kt < 512; kt += 32) {
    __syncthreads();
    {
      const int e = t >> 3, k4 = t & 7;
      *reinterpret_cast<float4*>(&As[e * 36 + k4 * 4]) =
          *reinterpret_cast<const float4*>(&x1[((size_t)b * NE + e) * 512 + kt + k4 * 4]);
    }
#pragma unroll
    for (int i = 0; i < 2; i++) {
      const int slot = t + 256 * i;
      const int row = slot >> 4, cg = slot & 15;
      *reinterpret_cast<float4*>(&Bs[row * 64 + cg * 4]) =
          *reinterpret_cast<const float4*>(&w[(size_t)(kt + row) * NC2 + cg * 4]);
    }
    __syncthreads();
#pragma unroll
    for (int kg = 0; kg < 8; kg++) {
      float4 a[2];
#pragma unroll
      for (int i = 0; i < 2; i++)
        a[i] = *reinterpret_cast<const float4*>(&As[(tr * 2 + i) * 36 + kg * 4]);
#pragma unroll
      for (int k2 = 0; k2 < 4; k2++) {
        const float4 bv = *reinterpret_cast<const float4*>(&Bs[(kg * 4 + k2) * 64 + tc * 4]);
#pragma unroll
        for (int i = 0; i < 2; i++) {
          const float av = reinterpret_cast<const float*>(&a[i])[k2];
          acc[i][0] = fmaf(av, bv.x, acc[i][0]);
          acc[i][1] = fmaf(av, bv.y, acc[i][1]);
          acc[i][2] = fmaf(av, bv.z, acc[i][2]);
          acc[i][3] = fmaf(av, bv.w, acc[i][3]);
        }
      }
    }
  }
  const float4 a4s = *reinterpret_cast<const float4*>(&as[tc * 4]);
  const float4 a4d = *reinterpret_cast<const float4*>(&ad[tc * 4]);
#pragma unroll
  for (int i = 0; i < 2; i++) {
    const int e = tr * 2 + i;
    float4 v;
    v.x = acc[i][0]; v.y = acc[i][1]; v.z = acc[i][2]; v.w = acc[i][3];
    *reinterpret_cast<float4*>(&H2[e * 68 + tc * 4]) = v;
    float sv = v.x * a4s.x + v.y * a4s.y + v.z * a4s.z + v.w * a4s.w;
    float dv = v.x * a4d.x + v.y * a4d.y + v.z * a4d.z + v.w * a4d.w;
#pragma unroll
    for (int o = 8; o > 0; o >>= 1) { sv += __shfl_xor(sv, o); dv += __shfl_xor(dv, o); }
    if (tc == 0) { Sv[e] = sv; Dv[e] = dv; }
  }
  __syncthreads();
  if (t < 32) {
    const int i = t;
    const float di = Dv[i];
    float lg[32];
    float m = -1e30f;
#pragma unroll
    for (int j = 0; j < 32; j++) {
      float v = di + Sv[j];
      v = v >= 0.f ? v : 0.2f * v;
      if (!adj[((size_t)b * NE + i) * NE + j]) v = -1e9f;
      lg[j] = v; m = fmaxf(m, v);
    }
    float sum = 0.f;
#pragma unroll
    for (int j = 0; j < 32; j++) { lg[j] = __expf(lg[j] - m); sum += lg[j]; }
    const float inv = 1.f / sum;
#pragma unroll
    for (int j = 0; j < 32; j++) Att[j * 32 + i] = lg[j] * inv;
  }
  __syncthreads();
#pragma unroll
  for (int i = 0; i < 2; i++) {
    const int row = tr * 2 + i;
    float o0 = bias[tc * 4 + 0];
    float o1 = bias[tc * 4 + 1];
    float o2 = bias[tc * 4 + 2];
    float o3 = bias[tc * 4 + 3];
#pragma unroll
    for (int j = 0; j < 32; j++) {
      const float a = Att[j * 32 + row];
      o0 = fmaf(a, H2[j * 68 + tc * 4 + 0], o0);
      o1 = fmaf(a, H2[j * 68 + tc * 4 + 1], o1);
      o2 = fmaf(a, H2[j * 68 + tc * 4 + 2], o2);
      o3 = fmaf(a, H2[j * 68 + tc * 4 + 3], o3);
    }
    float4 v;
    v.x = o0; v.y = o1; v.z = o2; v.w = o3;
    *reinterpret_cast<float4*>(&x2[((size_t)b * NE + row) * NC2 + tc * 4]) = v;
  }
}

// ---------------- pair feature build (pitch 260), ctx inlined ----------------
__global__ __launch_bounds__(64) void k_pf(const float* __restrict__ x2,
    const int* __restrict__ pe1, const int* __restrict__ pe2,
    float* __restrict__ pf) {
  const int bp = blockIdx.x;
  const int b = bp >> 4, p = bp & 15;
  const int t = threadIdx.x;
  const int e1 = pe1[b * NP + p], e2 = pe2[b * NP + p];
  const float v1 = x2[((size_t)b * NE + e1) * NC2 + t];
  const float v2 = x2[((size_t)b * NE + e2) * NC2 + t];
  float cs = 0.f;
  for (int e = 0; e < NE; e++) cs += x2[((size_t)b * NE + e) * NC2 + t];
  float* row = pf + (size_t)bp * 260;
  row[t] = v1;
  row[64 + t] = v2;
  row[128 + t] = v1 * v2;
  row[192 + t] = cs * (1.f / NE);
  if (t == 0) row[256] = logf(fabsf((float)(e1 - e2)) + 1.f);
  if (t < 3) row[257 + t] = 0.f;
}

// ---------------- fe = leaky(LN(pf @ w_fe + b_fe)) -- MFMA bf16, bf16 out ----------------
__global__ __launch_bounds__(256) void k_fe(const float* __restrict__ pf,
    const unsigned short* __restrict__ wt, const float* __restrict__ bfe,
    const float* __restrict__ g, const float* __restrict__ be,
    unsigned short* __restrict__ feb) {
  __shared__ unsigned short Af[16 * 320];
  __shared__ float Cs[16 * 520];
  const int b = blockIdx.x, t = threadIdx.x;
  const int w = t >> 6, lane = t & 63, quad = lane >> 4, l15 = lane & 15;
  for (int i = t; i < 16 * 320; i += 256) {
    const int p = i / 320, k = i - p * 320;
    Af[i] = (k < 260) ? f2bf(pf[(size_t)(b * NP + p) * 260 + k]) : (unsigned short)0;
  }
  __syncthreads();
  f32x4 acc[8];
#pragma unroll
  for (int c = 0; c < 8; c++) acc[c] = (f32x4){0.f, 0.f, 0.f, 0.f};
#pragma unroll
  for (int kt = 0; kt < 10; kt++) {
    const bf16x8 a = *reinterpret_cast<const bf16x8*>(&Af[l15 * 320 + kt * 32 + quad * 8]);
#pragma unroll
    for (int c = 0; c < 8; c++) {
      const int col = w * 128 + c * 16 + l15;
      const bf16x8 bv = *reinterpret_cast<const bf16x8*>(&wt[(size_t)col * 320 + kt * 32 + quad * 8]);
      acc[c] = __builtin_amdgcn_mfma_f32_16x16x32_bf16(a, bv, acc[c], 0, 0, 0);
    }
  }
#pragma unroll
  for (int c = 0; c < 8; c++)
#pragma unroll
    for (int reg = 0; reg < 4; reg++)
      Cs[(quad * 4 + reg) * 520 + w * 128 + c * 16 + l15] = acc[c][reg];
  __syncthreads();
  float bfev[8], gv[8], bev[8];
#pragma unroll
  for (int ch = 0; ch < 8; ch++) {
    const int col = ch * 64 + lane;
    bfev[ch] = bfe[col]; gv[ch] = g[col]; bev[ch] = be[col];
  }
#pragma unroll
  for (int pp = 0; pp < 4; pp++) {
    const int p = w * 4 + pp;
    float v[8], s = 0.f, sq = 0.f;
#pragma unroll
    for (int ch = 0; ch < 8; ch++) {
      v[ch] = Cs[p * 520 + ch * 64 + lane] + bfev[ch];
      s += v[ch]; sq += v[ch] * v[ch];
    }
#pragma unroll
    for (int o = 32; o > 0; o >>= 1) { s += __shfl_xor(s, o); sq += __shfl_xor(sq, o); }
    const float mean = s * (1.f / 512.f);
    const float var = sq * (1.f / 512.f) - mean * mean;
    const float rr = rsqrtf(var + 1e-5f);
#pragma unroll
    for (int ch = 0; ch < 8; ch++) {
      float n = (v[ch] - mean) * rr * gv[ch] + bev[ch];
      n = n >= 0.f ? n : 0.01f * n;
      feb[(size_t)(b * NP + p) * 512 + ch * 64 + lane] = f2bf(n);
    }
  }
}

// ---------------- relation heads: MFMA bf16 GEMM + LN + leaky + dot + BCE ----------------
__global__ __launch_bounds__(256) void k_rc(const unsigned short* __restrict__ feb,
    const unsigned short* __restrict__ wrt, const float* __restrict__ b1,
    const float* __restrict__ g, const float* __restrict__ be,
    const float* __restrict__ w2, const float* __restrict__ b2,
    const int* __restrict__ ylab, float* __restrict__ zout, float* __restrict__ relacc) {
  __shared__ unsigned short Af[16 * 520];
  __shared__ float Cs[16 * 264];
  const int blk = blockIdx.x;
  const int r = blk >> 6, b = blk & 63;
  const int t = threadIdx.x;
  const int w = t >> 6, lane = t & 63, quad = lane >> 4, l15 = lane & 15;
#pragma unroll
  for (int i = 0; i < 4; i++) {
    const int slot = t + 256 * i;
    const int p = slot >> 6, q = slot & 63;
    *reinterpret_cast<uint4*>(&Af[p * 520 + q * 8]) =
        *reinterpret_cast<const uint4*>(&feb[(size_t)(b * NP + p) * 512 + q * 8]);
  }
  __syncthreads();
  f32x4 acc[4];
#pragma unroll
  for (int c = 0; c < 4; c++) acc[c] = (f32x4){0.f, 0.f, 0.f, 0.f};
#pragma unroll
  for (int kt = 0; kt < 16; kt++) {
    const bf16x8 a = *reinterpret_cast<const bf16x8*>(&Af[l15 * 520 + kt * 32 + quad * 8]);
#pragma unroll
    for (int c = 0; c < 4; c++) {
      const int col = w * 64 + c * 16 + l15;
      const bf16x8 bv = *reinterpret_cast<const bf16x8*>(
          &wrt[(size_t)(r * 256 + col) * 512 + kt * 32 + quad * 8]);
      acc[c] = __builtin_amdgcn_mfma_f32_16x16x32_bf16(a, bv, acc[c], 0, 0, 0);
    }
  }
#pragma unroll
  for (int c = 0; c < 4; c++)
#pragma unroll
    for (int reg = 0; reg < 4; reg++)
      Cs[(quad * 4 + reg) * 264 + w * 64 + c * 16 + l15] = acc[c][reg];
  __syncthreads();
  float b1v[4], gv[4], bev[4], w2v[4];
#pragma unroll
  for (int ch = 0; ch < 4; ch++) {
    const int col = r * 256 + ch * 64 + lane;
    b1v[ch] = b1[col]; gv[ch] = g[col]; bev[ch] = be[col]; w2v[ch] = w2[col];
  }
  const float b2v = b2[r];
  float local = 0.f;
#pragma unroll
  for (int pp = 0; pp < 4; pp++) {
    const int p = w * 4 + pp;
    float v[4], s = 0.f, sq = 0.f;
#pragma unroll
    for (int ch = 0; ch < 4; ch++) {
      v[ch] = Cs[p * 264 + ch * 64 + lane] + b1v[ch];
      s += v[ch]; sq += v[ch] * v[ch];
    }
#pragma unroll
    for (int o = 32; o > 0; o >>= 1) { s += __shfl_xor(s, o); sq += __shfl_xor(sq, o); }
    const float mean = s * (1.f / 256.f);
    const float var = sq * (1.f / 256.f) - mean * mean;
    const float rr = rsqrtf(var + 1e-5f);
    float zdot = 0.f;
#pragma unroll
    for (int ch = 0; ch < 4; ch++) {
      float n = (v[ch] - mean) * rr * gv[ch] + bev[ch];
      n = n >= 0.f ? n : 0.01f * n;
      zdot = fmaf(n, w2v[ch], zdot);
    }
#pragma unroll
    for (int o = 32; o > 0; o >>= 1) zdot += __shfl_xor(zdot, o);
    if (lane == 0) {
      const float zp = zdot + b2v;
      zout[(size_t)(r * NB + b) * NP + p] = zp;
      const float y = (float)ylab[b * NP + p];
      local += -(2.f * y * logsigf(zp) + (1.f - y) * logsigf(-zp));
    }
  }
  if (lane == 0) atomicAdd(relacc, local * (1.f / (NB * NP)));
}

// ---------------- finalize total loss ----------------
__global__ __launch_bounds__(64) void k_fin(const float* __restrict__ lossb,
    const float* __restrict__ rel, float* __restrict__ out) {
  float v = lossb[threadIdx.x];
#pragma unroll
  for (int o = 32; o > 0; o >>= 1) v += __shfl_down(v, o);
  if (threadIdx.x == 0) out[TOTOFF] = v * (1.f / NB) + rel[0];
}

extern "C" void kernel_launch(void* const* d_in, const int* in_sizes, int n_in,
                              void* d_out, int out_size, void* d_ws, size_t ws_size,
                              hipStream_t stream) {
  const float* seq = (const float*)d_in[0];
  const int* amask = (const int*)d_in[1];
  const int* nlab = (const int*)d_in[2];
  const int* est = (const int*)d_in[3];
  const int* elen = (const int*)d_in[4];
  const int* pe1 = (const int*)d_in[5];
  const int* pe2 = (const int*)d_in[6];
  const int* plab = (const int*)d_in[7];
  const unsigned char* adj = (const unsigned char*)d_in[8];
  const float* w_ner1 = (const float*)d_in[9];
  const float* b_ner1 = (const float*)d_in[10];
  const float* w_ner2 = (const float*)d_in[11];
  const float* b_ner2 = (const float*)d_in[12];
  const float* crf_start = (const float*)d_in[13];
  const float* crf_end = (const float*)d_in[14];
  const float* crf_trans = (const float*)d_in[15];
  const float* w_gat1 = (const float*)d_in[16];
  const float* a_src1 = (const float*)d_in[17];
  const float* a_dst1 = (const float*)d_in[18];
  const float* b_gat1 = (const float*)d_in[19];
  const float* w_gat2 = (const float*)d_in[20];
  const float* a_src2 = (const float*)d_in[21];
  const float* a_dst2 = (const float*)d_in[22];
  const float* b_gat2 = (const float*)d_in[23];
  const float* w_fe = (const float*)d_in[24];
  const float* b_fe = (const float*)d_in[25];
  const float* g_fe = (const float*)d_in[26];
  const float* be_fe = (const float*)d_in[27];
  const float* w_rc1 = (const float*)d_in[28];
  const float* b_rc1 = (const float*)d_in[29];
  const float* g_rc = (const float*)d_in[30];
  const float* be_rc = (const float*)d_in[31];
  const float* w_rc2 = (const float*)d_in[32];
  const float* b_rc2 = (const float*)d_in[33];

  float* out = (float*)d_out;
  float* ws = (float*)d_ws;
  float* x1 = ws + WS_X1;
  float* x2 = ws + WS_X2;
  float* pf = ws + WS_PF;
  float* crfb = ws + WS_CRF;
  float* rel = ws + WS_REL;
  unsigned short* entb = (unsigned short*)(ws + WS_ENT);
  unsigned short* wg1t = (unsigned short*)(ws + WS_WG1T);
  unsigned short* w1t = (unsigned short*)(ws + WS_W1T);
  unsigned short* feb = (unsigned short*)(ws + WS_FE);
  unsigned short* wrt = (unsigned short*)(ws + WS_WRT);    // dead ENT region
  unsigned short* wfet = (unsigned short*)(ws + WS_WFET);  // dead ENT region
  float* segm = ws + WS_SEG;                               // dead ENT region

  hipMemsetAsync(rel, 0, sizeof(float), stream);

  k_wt<<<24, 256, 0, stream>>>(w_ner1, w_gat1, w1t, wg1t);
  k_ner<<<512, 256, 0, stream>>>(seq, w1t, b_ner1, w_ner2, b_ner2, out);
  k_ent<<<NB * NE, 256, 0, stream>>>(seq, est, elen, entb);
  k_g1f<<<NB * NHEADS, 256, 0, stream>>>(entb, wg1t, a_src1, a_dst1, adj, b_gat1, x1);
  // entb is dead after k_g1f -> its region now hosts wrt/wfet/segm
  k_wconv<<<58, 256, 0, stream>>>(w_rc1, w_fe, wrt, wfet);
  k_crf_seg<<<NB * SEGS, 128, 0, stream>>>(out, amask, crf_trans, segm);
  k_crf_fin<<<NB, 64, 0, stream>>>(out, nlab, amask, crf_start, crf_end, crf_trans,
                                   segm, crfb);
  k_g2f<<<NB, 256, 0, stream>>>(x1, w_gat2, a_src2, a_dst2, adj, b_gat2, x2);
  k_pf<<<NB * NP, 64, 0, stream>>>(x2, pe1, pe2, pf);
  k_fe<<<NB, 256, 0, stream>>>(pf, wfet, b_fe, g_fe, be_fe, feb);
  k_rc<<<NR * NB, 256, 0, stream>>>(feb, wrt, b_rc1, g_rc, be_rc, w_rc2, b_rc2,
                                    plab, out + ZOFF, rel);
  k_fin<<<1, 64, 0, stream>>>(crfb, rel, out);
}

// Round 7
// 431.925 us; speedup vs baseline: 1.2124x; 1.0465x over previous
//
#include <hip/hip_runtime.h>
#include <math.h>

// Problem: NERRelationModel_84963043050124
// B=64 S=512 H=768 E=32 P=16 K=9 R=6 HEADS=4 C1=128 C2=64 FEAT=257
// Outputs: ner_logits [B,S,K]=294912, z [R,B,P]=6144, total [1] -> 301057 f32

#define NB 64
#define NS 512
#define NH 768
#define NE 32
#define NP 16
#define NK 9
#define NR 6
#define NHEADS 4
#define NC1 128
#define NC2 64
#define SEGS 16
#define SEGLEN 32

#define ZOFF 294912
#define TOTOFF 301056

// ---- workspace layout (float offsets) ----
#define WS_ENT   0u           // bf16 entb [B,E,768] (dead after k_main -> WRT/WFET/SEG)
#define WS_WG1T  1572864u     // bf16 wg1t [512][768]
#define WS_X1    2621440u     // bf16 x1b [B,E,512]
#define WS_X2    3801088u     // f32 [B,E,64]
#define WS_WG2T  3956736u     // bf16 wg2t [64][512] (reuses old PF region)
#define WS_FE    4222976u     // bf16 [B,P,512]
#define WS_CRF   4747264u     // [64]
#define WS_REL   4747328u     // [1]
#define WS_W1T   4747392u     // bf16 [256][768]
// overlapped into dead ENT region (valid after k_main consumed entb):
#define WS_WRT   0u           // bf16 [R*256][512]
#define WS_WFET  393216u      // bf16 [512][320]
#define WS_SEG   475136u      // f32 [B][SEGS][81]

typedef __attribute__((ext_vector_type(8))) short bf16x8;
typedef __attribute__((ext_vector_type(4))) float f32x4;

__device__ __forceinline__ unsigned short f2bf(float x) {
  union { float f; unsigned u; } v; v.f = x;
  unsigned r = v.u + 0x7FFFu + ((v.u >> 16) & 1u);
  return (unsigned short)(r >> 16);
}

__device__ __forceinline__ float logsigf(float x) {
  if (x >= 0.f) return -log1pf(__expf(-x));
  return x - log1pf(__expf(x));
}

// ---------------- k_prep: weight transposes (w_ner1/w_gat1/w_gat2) + entity pool ----------------
// blocks 0..7: w1t; 8..23: wg1t; 24..25: wg2t; 26..2073: k_ent -> entb bf16.
__global__ __launch_bounds__(256) void k_prep(
    const float* __restrict__ w1, const float* __restrict__ wg1,
    const float* __restrict__ wg2, const float* __restrict__ seq,
    const int* __restrict__ est, const int* __restrict__ elen,
    unsigned short* __restrict__ w1t, unsigned short* __restrict__ wg1t,
    unsigned short* __restrict__ wg2t, unsigned short* __restrict__ entb) {
  __shared__ unsigned short tr[32 * 776];  // [col-in-tile][k]
  const int bid = blockIdx.x, t = threadIdx.x;
  if (bid < 26) {
    const float* src;
    unsigned short* dst;
    int c0, ncol, nkt, kdim;
    if (bid < 8)       { src = w1;  dst = w1t;  ncol = 256; c0 = bid * 32;        nkt = 24; kdim = 768; }
    else if (bid < 24) { src = wg1; dst = wg1t; ncol = 512; c0 = (bid - 8) * 32;  nkt = 24; kdim = 768; }
    else               { src = wg2; dst = wg2t; ncol = 64;  c0 = (bid - 24) * 32; nkt = 16; kdim = 512; }
    for (int p = 0; p < nkt; p++) {
      const int k = p * 32 + (t >> 3), c4 = t & 7;
      const float4 f = *reinterpret_cast<const float4*>(&src[(size_t)k * ncol + c0 + c4 * 4]);
      tr[(c4 * 4 + 0) * 776 + k] = f2bf(f.x);
      tr[(c4 * 4 + 1) * 776 + k] = f2bf(f.y);
      tr[(c4 * 4 + 2) * 776 + k] = f2bf(f.z);
      tr[(c4 * 4 + 3) * 776 + k] = f2bf(f.w);
    }
    __syncthreads();
    const int c = t >> 3, q = t & 7;
    const int chunk = kdim >> 3;  // 96 or 64 k per q
    for (int i = 0; i < (chunk >> 3); i++) {
      *reinterpret_cast<uint4*>(&dst[(size_t)(c0 + c) * kdim + q * chunk + i * 8]) =
          *reinterpret_cast<const uint4*>(&tr[c * 776 + q * chunk + i * 8]);
    }
  } else {
    const int be = bid - 26;
    const int b = be >> 5, e = be & 31;
    const int st = est[b * NE + e];
    int en = st + elen[b * NE + e];
    en = min(max(en, 0), NS - 1);
    const float inv = 1.f / (float)(en - st + 1);
    for (int c = t; c < NH; c += 256) {
      float s = 0.f;
      for (int r = st; r <= en; r++) s += seq[((size_t)b * NS + r) * NH + c];
      entb[((size_t)b * NE + e) * NH + c] = f2bf(s * inv);
    }
  }
}

// ---------------- k_main: fused GAT1 (blocks 0..255) + NER head 32-tok tiles (256..1279) ----------------
__global__ __launch_bounds__(256) void k_main(
    const float* __restrict__ seq, const unsigned short* __restrict__ w1t,
    const float* __restrict__ b1, const float* __restrict__ w2,
    const float* __restrict__ b2, float* __restrict__ out,
    const unsigned short* __restrict__ entb, const unsigned short* __restrict__ wg1t,
    const float* __restrict__ as1, const float* __restrict__ ad1,
    const unsigned char* __restrict__ adj, const float* __restrict__ bias1,
    unsigned short* __restrict__ x1b) {
  __shared__ __align__(16) char smem[34048];
  const int bid = blockIdx.x, t = threadIdx.x;
  const int w = t >> 6, lane = t & 63, quad = lane >> 4, l15 = lane & 15;

  if (bid < 256) {
    // ======== fused GAT1: MFMA GEMM + dots + softmax + aggregate + relu, bf16 out ========
    unsigned short* As = (unsigned short*)smem;            // [32*40]
    unsigned short* Bs = (unsigned short*)(smem + 2560);   // [128*40]
    float* Hs  = (float*)(smem + 12800);                   // [32*132]
    float* Att = (float*)(smem + 29696);                   // [32*32] ([j][i])
    float* Sv  = (float*)(smem + 33792);                   // [32]
    float* Dv  = (float*)(smem + 33920);                   // [32]
    const int b = bid >> 2, hd = bid & 3;

    f32x4 acc[2][2];
#pragma unroll
    for (int r = 0; r < 2; r++)
#pragma unroll
      for (int c = 0; c < 2; c++) acc[r][c] = (f32x4){0.f, 0.f, 0.f, 0.f};

    const int rowA = t >> 2, koffA = (t & 3) * 8;  // t<128 stages A
    const unsigned short* aptr = entb + ((size_t)(b * NE) + rowA) * NH + koffA;

    for (int kt = 0; kt < NH; kt += 32) {
      __syncthreads();
      if (t < 128) {
        *reinterpret_cast<uint4*>(&As[rowA * 40 + koffA]) =
            *reinterpret_cast<const uint4*>(aptr + kt);
      }
#pragma unroll
      for (int i = 0; i < 2; i++) {
        const int q = t + 256 * i;
        const int col = q >> 2, koff = (q & 3) * 8;
        *reinterpret_cast<uint4*>(&Bs[col * 40 + koff]) =
            *reinterpret_cast<const uint4*>(&wg1t[(size_t)(hd * 128 + col) * NH + kt + koff]);
      }
      __syncthreads();
      bf16x8 a[2], bb[2];
#pragma unroll
      for (int r = 0; r < 2; r++)
        a[r] = *reinterpret_cast<const bf16x8*>(&As[(r * 16 + l15) * 40 + quad * 8]);
#pragma unroll
      for (int c = 0; c < 2; c++)
        bb[c] = *reinterpret_cast<const bf16x8*>(&Bs[(w * 32 + c * 16 + l15) * 40 + quad * 8]);
#pragma unroll
      for (int r = 0; r < 2; r++)
#pragma unroll
        for (int c = 0; c < 2; c++)
          acc[r][c] = __builtin_amdgcn_mfma_f32_16x16x32_bf16(a[r], bb[c], acc[r][c], 0, 0, 0);
    }
#pragma unroll
    for (int r = 0; r < 2; r++)
#pragma unroll
      for (int c = 0; c < 2; c++)
#pragma unroll
        for (int reg = 0; reg < 4; reg++)
          Hs[(r * 16 + quad * 4 + reg) * 132 + w * 32 + c * 16 + l15] = acc[r][c][reg];
    __syncthreads();
    {
      const int e = t >> 3, cg = t & 7;
      float sv = 0.f, dv = 0.f;
#pragma unroll
      for (int c = 0; c < 16; c++) {
        const float h = Hs[e * 132 + cg * 16 + c];
        sv += h * as1[hd * NC1 + cg * 16 + c];
        dv += h * ad1[hd * NC1 + cg * 16 + c];
      }
#pragma unroll
      for (int o = 1; o < 8; o <<= 1) { sv += __shfl_xor(sv, o); dv += __shfl_xor(dv, o); }
      if (cg == 0) { Sv[e] = sv; Dv[e] = dv; }
    }
    __syncthreads();
    if (t < 32) {
      const int i = t;
      const float di = Dv[i];
      float lg[32];
      float m = -1e30f;
#pragma unroll
      for (int j = 0; j < 32; j++) {
        float v = di + Sv[j];
        v = v >= 0.f ? v : 0.2f * v;
        if (!adj[((size_t)b * NE + i) * NE + j]) v = -1e9f;
        lg[j] = v; m = fmaxf(m, v);
      }
      float sum = 0.f;
#pragma unroll
      for (int j = 0; j < 32; j++) { lg[j] = __expf(lg[j] - m); sum += lg[j]; }
      const float inv = 1.f / sum;
#pragma unroll
      for (int j = 0; j < 32; j++) Att[j * 32 + i] = lg[j] * inv;
    }
    __syncthreads();
    {
      const int tc = t & 31, tr2 = t >> 5;
#pragma unroll
      for (int i = 0; i < 4; i++) {
        const int row = tr2 * 4 + i;
        float o0 = bias1[hd * NC1 + tc * 4 + 0];
        float o1 = bias1[hd * NC1 + tc * 4 + 1];
        float o2 = bias1[hd * NC1 + tc * 4 + 2];
        float o3 = bias1[hd * NC1 + tc * 4 + 3];
#pragma unroll
        for (int j = 0; j < 32; j++) {
          const float a = Att[j * 32 + row];
          o0 = fmaf(a, Hs[j * 132 + tc * 4 + 0], o0);
          o1 = fmaf(a, Hs[j * 132 + tc * 4 + 1], o1);
          o2 = fmaf(a, Hs[j * 132 + tc * 4 + 2], o2);
          o3 = fmaf(a, Hs[j * 132 + tc * 4 + 3], o3);
        }
        uint2 v;
        v.x = (unsigned)f2bf(fmaxf(o0, 0.f)) | ((unsigned)f2bf(fmaxf(o1, 0.f)) << 16);
        v.y = (unsigned)f2bf(fmaxf(o2, 0.f)) | ((unsigned)f2bf(fmaxf(o3, 0.f)) << 16);
        *reinterpret_cast<uint2*>(&x1b[((size_t)b * NE + row) * 512 + hd * 128 + tc * 4]) = v;
      }
    }
  } else {
    // ======== NER head: MFMA bf16, 32-token x 256-col tiles (R0 2-barrier structure) ========
    unsigned short* AsS = (unsigned short*)smem;           // [32*40]
    unsigned short* BsS = (unsigned short*)(smem + 2560);  // [256*40]
    float* zs = (float*)(smem + 23040);                    // [32*4*12]
    const int tok0 = (bid - 256) * 32;

    f32x4 acc[2][4];
#pragma unroll
    for (int r = 0; r < 2; r++)
#pragma unroll
      for (int c = 0; c < 4; c++) acc[r][c] = (f32x4){0.f, 0.f, 0.f, 0.f};

    const int tokA = t >> 3, koffA = (t & 7) * 4;  // 4 floats per thread
    const float* aptr = seq + (size_t)(tok0 + tokA) * NH + koffA;

    for (int kt = 0; kt < NH; kt += 32) {
      __syncthreads();
      {
        const float4 f0 = *reinterpret_cast<const float4*>(aptr + kt);
        uint2 v;
        v.x = (unsigned)f2bf(f0.x) | ((unsigned)f2bf(f0.y) << 16);
        v.y = (unsigned)f2bf(f0.z) | ((unsigned)f2bf(f0.w) << 16);
        *reinterpret_cast<uint2*>(&AsS[tokA * 40 + koffA]) = v;
      }
#pragma unroll
      for (int i = 0; i < 4; i++) {
        const int q = t + 256 * i;
        const int col = q >> 2, koff = (q & 3) * 8;
        *reinterpret_cast<uint4*>(&BsS[col * 40 + koff]) =
            *reinterpret_cast<const uint4*>(&w1t[(size_t)col * NH + kt + koff]);
      }
      __syncthreads();
      bf16x8 a[2], b[4];
#pragma unroll
      for (int r = 0; r < 2; r++)
        a[r] = *reinterpret_cast<const bf16x8*>(&AsS[(r * 16 + l15) * 40 + quad * 8]);
#pragma unroll
      for (int c = 0; c < 4; c++)
        b[c] = *reinterpret_cast<const bf16x8*>(&BsS[(w * 64 + c * 16 + l15) * 40 + quad * 8]);
#pragma unroll
      for (int r = 0; r < 2; r++)
#pragma unroll
        for (int c = 0; c < 4; c++)
          acc[r][c] = __builtin_amdgcn_mfma_f32_16x16x32_bf16(a[r], b[c], acc[r][c], 0, 0, 0);
    }

    float b1v[4], w2v[4][NK];
#pragma unroll
    for (int c = 0; c < 4; c++) {
      const int col = w * 64 + c * 16 + l15;
      b1v[c] = b1[col];
#pragma unroll
      for (int cc = 0; cc < NK; cc++) w2v[c][cc] = w2[col * NK + cc];
    }
#pragma unroll
    for (int r = 0; r < 2; r++) {
#pragma unroll
      for (int reg = 0; reg < 4; reg++) {
        float p[NK];
#pragma unroll
        for (int cc = 0; cc < NK; cc++) p[cc] = 0.f;
#pragma unroll
        for (int c = 0; c < 4; c++) {
          const float h = fmaxf(acc[r][c][reg] + b1v[c], 0.f);
#pragma unroll
          for (int cc = 0; cc < NK; cc++) p[cc] = fmaf(h, w2v[c][cc], p[cc]);
        }
#pragma unroll
        for (int o = 1; o < 16; o <<= 1)
#pragma unroll
          for (int cc = 0; cc < NK; cc++) p[cc] += __shfl_xor(p[cc], o);
        if (l15 == 0) {
          const int tokr = r * 16 + quad * 4 + reg;
#pragma unroll
          for (int cc = 0; cc < NK; cc++) zs[(tokr * 4 + w) * 12 + cc] = p[cc];
        }
      }
    }
    __syncthreads();
    if (t < 32) {
#pragma unroll
      for (int cc = 0; cc < NK; cc++) {
        const float z = zs[(t * 4 + 0) * 12 + cc] + zs[(t * 4 + 1) * 12 + cc] +
                        zs[(t * 4 + 2) * 12 + cc] + zs[(t * 4 + 3) * 12 + cc] + b2[cc];
        out[(size_t)(tok0 + t) * NK + cc] = z;
      }
    }
  }
}

// ---------------- k_mid: weight converts (blocks 0..57) + CRF segment reduce (58..1081) ----------------
__global__ __launch_bounds__(256) void k_mid(
    const float* __restrict__ wrc, const float* __restrict__ wfe,
    unsigned short* __restrict__ wrt, unsigned short* __restrict__ wfet,
    const float* __restrict__ em, const int* __restrict__ mask,
    const float* __restrict__ trans, float* __restrict__ segm) {
  __shared__ __align__(16) char smem[36864];
  const int bid = blockIdx.x, t = threadIdx.x;
  if (bid < 58) {
    unsigned short* tr = (unsigned short*)smem;  // [256*72]
    if (bid < 48) {
      const int r = bid >> 3, kt = bid & 7;
      const int k0 = kt * 64;
#pragma unroll
      for (int i = 0; i < 16; i++) {
        const int slot = t + 256 * i;
        const int row = slot >> 6, c4 = slot & 63;
        const float4 f = *reinterpret_cast<const float4*>(
            &wrc[((size_t)(r * 512) + k0 + row) * 256 + c4 * 4]);
        tr[(c4 * 4 + 0) * 72 + row] = f2bf(f.x);
        tr[(c4 * 4 + 1) * 72 + row] = f2bf(f.y);
        tr[(c4 * 4 + 2) * 72 + row] = f2bf(f.z);
        tr[(c4 * 4 + 3) * 72 + row] = f2bf(f.w);
      }
      __syncthreads();
#pragma unroll
      for (int i = 0; i < 8; i++) {
        const int slot = t + 256 * i;
        const int col = slot >> 3, q = slot & 7;
        *reinterpret_cast<uint4*>(&wrt[((size_t)(r * 256 + col)) * 512 + k0 + q * 8]) =
            *reinterpret_cast<const uint4*>(&tr[col * 72 + q * 8]);
      }
    } else {
      const int b2 = bid - 48;
      const int kt = b2 % 5, cb = b2 / 5;
      const int k0 = kt * 64, c0 = cb * 256;
#pragma unroll
      for (int i = 0; i < 16; i++) {
        const int slot = t + 256 * i;
        const int row = slot >> 6, c4 = slot & 63;
        const int k = k0 + row;
        float4 f = {0.f, 0.f, 0.f, 0.f};
        if (k < 257)
          f = *reinterpret_cast<const float4*>(&wfe[(size_t)k * 512 + c0 + c4 * 4]);
        tr[(c4 * 4 + 0) * 72 + row] = f2bf(f.x);
        tr[(c4 * 4 + 1) * 72 + row] = f2bf(f.y);
        tr[(c4 * 4 + 2) * 72 + row] = f2bf(f.z);
        tr[(c4 * 4 + 3) * 72 + row] = f2bf(f.w);
      }
      __syncthreads();
#pragma unroll
      for (int i = 0; i < 8; i++) {
        const int slot = t + 256 * i;
        const int col = slot >> 3, q = slot & 7;
        *reinterpret_cast<uint4*>(&wfet[((size_t)(c0 + col)) * 320 + k0 + q * 8]) =
            *reinterpret_cast<const uint4*>(&tr[col * 72 + q * 8]);
      }
    }
  } else {
    float* bufA = (float*)smem;             // [16*81]
    float* bufB = (float*)(smem + 5184);    // [8*81]
    float* ems  = (float*)(smem + 7776);    // [SEGLEN*9]
    int*   mks  = (int*)(smem + 8928);      // [SEGLEN]
    float* trs  = (float*)(smem + 9056);    // [81]
    const int blk = bid - 58;
    const int b = blk >> 4, seg = blk & 15;
    const int s0 = 1 + seg * SEGLEN;
    const float* emb = em + (size_t)b * NS * NK;
    const int* mk = mask + b * NS;
    if (t < 81) trs[t] = trans[t];
    for (int i = t; i < SEGLEN * 9; i += 256) {
      const int g = s0 * 9 + i;
      ems[i] = (g < NS * 9) ? emb[g] : 0.f;
    }
    if (t < SEGLEN) {
      const int s = s0 + t;
      mks[t] = (s < NS) ? mk[s] : 0;
    }
    __syncthreads();
    for (int idx = t; idx < 16 * 81; idx += 256) {
      const int p = idx / 81, e = idx % 81, i = e / 9, j = e % 9;
      const int la = 2 * p, lb = la + 1;
      const bool ma = mks[la] > 0, mb = mks[lb] > 0;
      float r;
      if (ma && mb) {
        float v[9], mx = -1e30f;
#pragma unroll
        for (int m = 0; m < 9; m++) {
          v[m] = trs[i * 9 + m] + ems[la * 9 + m] + trs[m * 9 + j];
          mx = fmaxf(mx, v[m]);
        }
        float sum = 0.f;
#pragma unroll
        for (int m = 0; m < 9; m++) sum += __expf(v[m] - mx);
        r = mx + __logf(sum) + ems[lb * 9 + j];
      } else if (ma) {
        r = trs[e] + ems[la * 9 + j];
      } else if (mb) {
        r = trs[e] + ems[lb * 9 + j];
      } else {
        r = (i == j) ? 0.f : -1e30f;
      }
      bufA[p * 81 + e] = r;
    }
    float* src = bufA;
    float* dst = bufB;
    for (int n = 16; n > 1; n >>= 1) {
      __syncthreads();
      const int half = n >> 1;
      for (int idx = t; idx < half * 81; idx += 256) {
        const int q = idx / 81, e = idx % 81, i = e / 9, j = e % 9;
        const float* A = src + (size_t)(2 * q) * 81;
        const float* Bm = src + (size_t)(2 * q + 1) * 81;
        float v[9], mx = -1e30f;
#pragma unroll
        for (int m = 0; m < 9; m++) {
          v[m] = A[i * 9 + m] + Bm[m * 9 + j];
          mx = fmaxf(mx, v[m]);
        }
        float sum = 0.f;
#pragma unroll
        for (int m = 0; m < 9; m++) sum += __expf(v[m] - mx);
        dst[q * 81 + e] = mx + __logf(sum);
      }
      float* tmp = src; src = dst; dst = tmp;
    }
    __syncthreads();
    if (t < 81) segm[((size_t)b * SEGS + seg) * 81 + t] = src[t];
  }
}

// ---------------- k_late: fused GAT2 MFMA (blocks 0..63) + CRF finalize (64..127) ----------------
__global__ __launch_bounds__(256) void k_late(
    const unsigned short* __restrict__ x1b, const unsigned short* __restrict__ wg2t,
    const float* __restrict__ as2, const float* __restrict__ ad2,
    const unsigned char* __restrict__ adj, const float* __restrict__ bias2,
    float* __restrict__ x2,
    const float* __restrict__ em, const int* __restrict__ tags,
    const int* __restrict__ mask, const float* __restrict__ startv,
    const float* __restrict__ endv, const float* __restrict__ trans,
    const float* __restrict__ segm, float* __restrict__ lossb) {
  __shared__ __align__(16) char smem[20736];
  const int bid = blockIdx.x, t = threadIdx.x;
  if (bid < 64) {
    // ======== GAT2: MFMA bf16 GEMM (K=512) + dots + softmax + aggregate ========
    unsigned short* As = (unsigned short*)smem;           // [32*40]
    unsigned short* Bs = (unsigned short*)(smem + 2560);  // [64*40]
    float* H2  = (float*)(smem + 7680);                   // [32*68]
    float* Att = (float*)(smem + 16384);                  // [32*32] ([j][i])
    float* Sv  = (float*)(smem + 20480);                  // [32]
    float* Dv  = (float*)(smem + 20608);                  // [32]
    const int b = bid;
    const int w = t >> 6, lane = t & 63, quad = lane >> 4, l15 = lane & 15;

    f32x4 acc[2];
#pragma unroll
    for (int r = 0; r < 2; r++) acc[r] = (f32x4){0.f, 0.f, 0.f, 0.f};

    const int rowA = t >> 2, koffA = (t & 3) * 8;  // t<128 stages A
    const unsigned short* aptr = x1b + ((size_t)(b * NE) + rowA) * 512 + koffA;

    for (int kt = 0; kt < 512; kt += 32) {
      __syncthreads();
      if (t < 128) {
        *reinterpret_cast<uint4*>(&As[rowA * 40 + koffA]) =
            *reinterpret_cast<const uint4*>(aptr + kt);
      }
      {
        const int col = t >> 2, koff = (t & 3) * 8;  // 64 cols x 4 chunks
        *reinterpret_cast<uint4*>(&Bs[col * 40 + koff]) =
            *reinterpret_cast<const uint4*>(&wg2t[(size_t)col * 512 + kt + koff]);
      }
      __syncthreads();
      const bf16x8 a0 = *reinterpret_cast<const bf16x8*>(&As[l15 * 40 + quad * 8]);
      const bf16x8 a1 = *reinterpret_cast<const bf16x8*>(&As[(16 + l15) * 40 + quad * 8]);
      const bf16x8 bb = *reinterpret_cast<const bf16x8*>(&Bs[(w * 16 + l15) * 40 + quad * 8]);
      acc[0] = __builtin_amdgcn_mfma_f32_16x16x32_bf16(a0, bb, acc[0], 0, 0, 0);
      acc[1] = __builtin_amdgcn_mfma_f32_16x16x32_bf16(a1, bb, acc[1], 0, 0, 0);
    }
#pragma unroll
    for (int r = 0; r < 2; r++)
#pragma unroll
      for (int reg = 0; reg < 4; reg++)
        H2[(r * 16 + quad * 4 + reg) * 68 + w * 16 + l15] = acc[r][reg];
    __syncthreads();
    {
      const int e = t >> 3, cg = t & 7;
      float sv = 0.f, dv = 0.f;
#pragma unroll
      for (int c = 0; c < 8; c++) {
        const float h = H2[e * 68 + cg * 8 + c];
        sv += h * as2[cg * 8 + c];
        dv += h * ad2[cg * 8 + c];
      }
#pragma unroll
      for (int o = 1; o < 8; o <<= 1) { sv += __shfl_xor(sv, o); dv += __shfl_xor(dv, o); }
      if (cg == 0) { Sv[e] = sv; Dv[e] = dv; }
    }
    __syncthreads();
    if (t < 32) {
      const int i = t;
      const float di = Dv[i];
      float lg[32];
      float m = -1e30f;
#pragma unroll
      for (int j = 0; j < 32; j++) {
        float v = di + Sv[j];
        v = v >= 0.f ? v : 0.2f * v;
        if (!adj[((size_t)b * NE + i) * NE + j]) v = -1e9f;
        lg[j] = v; m = fmaxf(m, v);
      }
      float sum = 0.f;
#pragma unroll
      for (int j = 0; j < 32; j++) { lg[j] = __expf(lg[j] - m); sum += lg[j]; }
      const float inv = 1.f / sum;
#pragma unroll
      for (int j = 0; j < 32; j++) Att[j * 32 + i] = lg[j] * inv;
    }
    __syncthreads();
    {
      const int tc = t & 15, tr2 = t >> 4;
#pragma unroll
      for (int i = 0; i < 2; i++) {
        const int row = tr2 * 2 + i;
        float o0 = bias2[tc * 4 + 0];
        float o1 = bias2[tc * 4 + 1];
        float o2 = bias2[tc * 4 + 2];
        float o3 = bias2[tc * 4 + 3];
#pragma unroll
        for (int j = 0; j < 32; j++) {
          const float a = Att[j * 32 + row];
          o0 = fmaf(a, H2[j * 68 + tc * 4 + 0], o0);
          o1 = fmaf(a, H2[j * 68 + tc * 4 + 1], o1);
          o2 = fmaf(a, H2[j * 68 + tc * 4 + 2], o2);
          o3 = fmaf(a, H2[j * 68 + tc * 4 + 3], o3);
        }
        float4 v;
        v.x = o0; v.y = o1; v.z = o2; v.w = o3;
        *reinterpret_cast<float4*>(&x2[((size_t)b * NE + row) * NC2 + tc * 4]) = v;
      }
    }
  } else {
    // ======== CRF finalize (256 threads; compute guarded to original lanes) ========
    float* sm  = (float*)smem;            // [SEGS*81]
    float* av  = (float*)(smem + 5184);   // [16]
    float* red = (float*)(smem + 5248);   // [2]
    const int b = bid - 64;
    const float* emb = em + (size_t)b * NS * NK;
    const int* mk = mask + b * NS;
    const int* tg = tags + b * NS;
    for (int i = t; i < SEGS * 81; i += 256) sm[i] = segm[(size_t)b * SEGS * 81 + i];
    if (t < 64) {
      float num = 0.f;
      int lastS = 0;
#pragma unroll
      for (int o = 0; o < 8; o++) {
        const int s = t * 8 + o;
        if (s >= 1 && mk[s] > 0) {
          const int cur = tg[s], prv = tg[s - 1];
          num += trans[prv * NK + cur] + emb[s * NK + cur];
          lastS = s;
        }
      }
#pragma unroll
      for (int o = 32; o > 0; o >>= 1) {
        num += __shfl_xor(num, o);
        lastS = max(lastS, __shfl_xor(lastS, o));
      }
      if (t == 0) {
        const int t0 = tg[0];
        red[0] = startv[t0] + emb[t0] + num + endv[tg[lastS]];
      }
    }
    __syncthreads();
    if (t < 9) av[t] = startv[t] + emb[t];
    __syncthreads();
    for (int h = 0; h < SEGS; h++) {
      float nv = 0.f;
      if (t < 9) {
        float v[9], mx = -1e30f;
#pragma unroll
        for (int i2 = 0; i2 < 9; i2++) {
          v[i2] = av[i2] + sm[h * 81 + i2 * 9 + t];
          mx = fmaxf(mx, v[i2]);
        }
        float sum = 0.f;
#pragma unroll
        for (int i2 = 0; i2 < 9; i2++) sum += __expf(v[i2] - mx);
        nv = mx + __logf(sum);
      }
      __syncthreads();
      if (t < 9) av[t] = nv;
      __syncthreads();
    }
    if (t == 0) {
      float mx = -1e30f;
#pragma unroll
      for (int j = 0; j < 9; j++) mx = fmaxf(mx, av[j] + endv[j]);
      float sum = 0.f;
#pragma unroll
      for (int j = 0; j < 9; j++) sum += __expf(av[j] + endv[j] - mx);
      lossb[b] = (mx + __logf(sum)) - red[0];
    }
  }
}

// ---------------- k_fe: pair-features (inlined, was k_pf) + MFMA + LN + leaky, bf16 out ----------------
__global__ __launch_bounds__(256) void k_fe(const float* __restrict__ x2,
    const int* __restrict__ pe1, const int* __restrict__ pe2,
    const unsigned short* __restrict__ wt, const float* __restrict__ bfe,
    const float* __restrict__ g, const float* __restrict__ be,
    unsigned short* __restrict__ feb) {
  __shared__ unsigned short Af[16 * 320];
  __shared__ float Cs[16 * 520];
  __shared__ float ctxs[64];
  const int b = blockIdx.x, t = threadIdx.x;
  const int w = t >> 6, lane = t & 63, quad = lane >> 4, l15 = lane & 15;
  if (t < 64) {
    float cs = 0.f;
    for (int e = 0; e < NE; e++) cs += x2[((size_t)b * NE + e) * NC2 + t];
    ctxs[t] = cs * (1.f / NE);
  }
  __syncthreads();
  for (int i = t; i < 16 * 320; i += 256) {
    const int p = i / 320, k = i - p * 320;
    unsigned short o = 0;
    if (k < 260) {
      const int e1 = pe1[b * NP + p], e2 = pe2[b * NP + p];
      float v;
      if (k < 64) v = x2[((size_t)b * NE + e1) * NC2 + k];
      else if (k < 128) v = x2[((size_t)b * NE + e2) * NC2 + (k - 64)];
      else if (k < 192) v = x2[((size_t)b * NE + e1) * NC2 + (k - 128)] *
                            x2[((size_t)b * NE + e2) * NC2 + (k - 128)];
      else if (k < 256) v = ctxs[k - 192];
      else if (k == 256) v = logf(fabsf((float)(e1 - e2)) + 1.f);
      else v = 0.f;
      o = f2bf(v);
    }
    Af[i] = o;
  }
  __syncthreads();
  f32x4 acc[8];
#pragma unroll
  for (int c = 0; c < 8; c++) acc[c] = (f32x4){0.f, 0.f, 0.f, 0.f};
#pragma unroll
  for (int kt = 0; kt < 10; kt++) {
    const bf16x8 a = *reinterpret_cast<const bf16x8*>(&Af[l15 * 320 + kt * 32 + quad * 8]);
#pragma unroll
    for (int c = 0; c < 8; c++) {
      const int col = w * 128 + c * 16 + l15;
      const bf16x8 bv = *reinterpret_cast<const bf16x8*>(&wt[(size_t)col * 320 + kt * 32 + quad * 8]);
      acc[c] = __builtin_amdgcn_mfma_f32_16x16x32_bf16(a, bv, acc[c], 0, 0, 0);
    }
  }
#pragma unroll
  for (int c = 0; c < 8; c++)
#pragma unroll
    for (int reg = 0; reg < 4; reg++)
      Cs[(quad * 4 + reg) * 520 + w * 128 + c * 16 + l15] = acc[c][reg];
  __syncthreads();
  float bfev[8], gv[8], bev[8];
#pragma unroll
  for (int ch = 0; ch < 8; ch++) {
    const int col = ch * 64 + lane;
    bfev[ch] = bfe[col]; gv[ch] = g[col]; bev[ch] = be[col];
  }
#pragma unroll
  for (int pp = 0; pp < 4; pp++) {
    const int p = w * 4 + pp;
    float v[8], s = 0.f, sq = 0.f;
#pragma unroll
    for (int ch = 0; ch < 8; ch++) {
      v[ch] = Cs[p * 520 + ch * 64 + lane] + bfev[ch];
      s += v[ch]; sq += v[ch] * v[ch];
    }
#pragma unroll
    for (int o = 32; o > 0; o >>= 1) { s += __shfl_xor(s, o); sq += __shfl_xor(sq, o); }
    const float mean = s * (1.f / 512.f);
    const float var = sq * (1.f / 512.f) - mean * mean;
    const float rr = rsqrtf(var + 1e-5f);
#pragma unroll
    for (int ch = 0; ch < 8; ch++) {
      float n = (v[ch] - mean) * rr * gv[ch] + bev[ch];
      n = n >= 0.f ? n : 0.01f * n;
      feb[(size_t)(b * NP + p) * 512 + ch * 64 + lane] = f2bf(n);
    }
  }
}

// ---------------- relation heads: MFMA bf16 GEMM + LN + leaky + dot + BCE ----------------
__global__ __launch_bounds__(256) void k_rc(const unsigned short* __restrict__ feb,
    const unsigned short* __restrict__ wrt, const float* __restrict__ b1,
    const float* __restrict__ g, const float* __restrict__ be,
    const float* __restrict__ w2, const float* __restrict__ b2,
    const int* __restrict__ ylab, float* __restrict__ zout, float* __restrict__ relacc) {
  __shared__ unsigned short Af[16 * 520];
  __shared__ float Cs[16 * 264];
  const int blk = blockIdx.x;
  const int r = blk >> 6, b = blk & 63;
  const int t = threadIdx.x;
  const int w = t >> 6, lane = t & 63, quad = lane >> 4, l15 = lane & 15;
#pragma unroll
  for (int i = 0; i < 4; i++) {
    const int slot = t + 256 * i;
    const int p = slot >> 6, q = slot & 63;
    *reinterpret_cast<uint4*>(&Af[p * 520 + q * 8]) =
        *reinterpret_cast<const uint4*>(&feb[(size_t)(b * NP + p) * 512 + q * 8]);
  }
  __syncthreads();
  f32x4 acc[4];
#pragma unroll
  for (int c = 0; c < 4; c++) acc[c] = (f32x4){0.f, 0.f, 0.f, 0.f};
#pragma unroll
  for (int kt = 0; kt < 16; kt++) {
    const bf16x8 a = *reinterpret_cast<const bf16x8*>(&Af[l15 * 520 + kt * 32 + quad * 8]);
#pragma unroll
    for (int c = 0; c < 4; c++) {
      const int col = w * 64 + c * 16 + l15;
      const bf16x8 bv = *reinterpret_cast<const bf16x8*>(
          &wrt[(size_t)(r * 256 + col) * 512 + kt * 32 + quad * 8]);
      acc[c] = __builtin_amdgcn_mfma_f32_16x16x32_bf16(a, bv, acc[c], 0, 0, 0);
    }
  }
#pragma unroll
  for (int c = 0; c < 4; c++)
#pragma unroll
    for (int reg = 0; reg < 4; reg++)
      Cs[(quad * 4 + reg) * 264 + w * 64 + c * 16 + l15] = acc[c][reg];
  __syncthreads();
  float b1v[4], gv[4], bev[4], w2v[4];
#pragma unroll
  for (int ch = 0; ch < 4; ch++) {
    const int col = r * 256 + ch * 64 + lane;
    b1v[ch] = b1[col]; gv[ch] = g[col]; bev[ch] = be[col]; w2v[ch] = w2[col];
  }
  const float b2v = b2[r];
  float local = 0.f;
#pragma unroll
  for (int pp = 0; pp < 4; pp++) {
    const int p = w * 4 + pp;
    float v[4], s = 0.f, sq = 0.f;
#pragma unroll
    for (int ch = 0; ch < 4; ch++) {
      v[ch] = Cs[p * 264 + ch * 64 + lane] + b1v[ch];
      s += v[ch]; sq += v[ch] * v[ch];
    }
#pragma unroll
    for (int o = 32; o > 0; o >>= 1) { s += __shfl_xor(s, o); sq += __shfl_xor(sq, o); }
    const float mean = s * (1.f / 256.f);
    const float var = sq * (1.f / 256.f) - mean * mean;
    const float rr = rsqrtf(var + 1e-5f);
    float zdot = 0.f;
#pragma unroll
    for (int ch = 0; ch < 4; ch++) {
      float n = (v[ch] - mean) * rr * gv[ch] + bev[ch];
      n = n >= 0.f ? n : 0.01f * n;
      zdot = fmaf(n, w2v[ch], zdot);
    }
#pragma unroll
    for (int o = 32; o > 0; o >>= 1) zdot += __shfl_xor(zdot, o);
    if (lane == 0) {
      const float zp = zdot + b2v;
      zout[(size_t)(r * NB + b) * NP + p] = zp;
      const float y = (float)ylab[b * NP + p];
      local += -(2.f * y * logsigf(zp) + (1.f - y) * logsigf(-zp));
    }
  }
  if (lane == 0) atomicAdd(relacc, local * (1.f / (NB * NP)));
}

// ---------------- finalize total loss ----------------
__global__ __launch_bounds__(64) void k_fin(const float* __restrict__ lossb,
    const float* __restrict__ rel, float* __restrict__ out) {
  float v = lossb[threadIdx.x];
#pragma unroll
  for (int o = 32; o > 0; o >>= 1) v += __shfl_down(v, o);
  if (threadIdx.x == 0) out[TOTOFF] = v * (1.f / NB) + rel[0];
}

extern "C" void kernel_launch(void* const* d_in, const int* in_sizes, int n_in,
                              void* d_out, int out_size, void* d_ws, size_t ws_size,
                              hipStream_t stream) {
  const float* seq = (const float*)d_in[0];
  const int* amask = (const int*)d_in[1];
  const int* nlab = (const int*)d_in[2];
  const int* est = (const int*)d_in[3];
  const int* elen = (const int*)d_in[4];
  const int* pe1 = (const int*)d_in[5];
  const int* pe2 = (const int*)d_in[6];
  const int* plab = (const int*)d_in[7];
  const unsigned char* adj = (const unsigned char*)d_in[8];
  const float* w_ner1 = (const float*)d_in[9];
  const float* b_ner1 = (const float*)d_in[10];
  const float* w_ner2 = (const float*)d_in[11];
  const float* b_ner2 = (const float*)d_in[12];
  const float* crf_start = (const float*)d_in[13];
  const float* crf_end = (const float*)d_in[14];
  const float* crf_trans = (const float*)d_in[15];
  const float* w_gat1 = (const float*)d_in[16];
  const float* a_src1 = (const float*)d_in[17];
  const float* a_dst1 = (const float*)d_in[18];
  const float* b_gat1 = (const float*)d_in[19];
  const float* w_gat2 = (const float*)d_in[20];
  const float* a_src2 = (const float*)d_in[21];
  const float* a_dst2 = (const float*)d_in[22];
  const float* b_gat2 = (const float*)d_in[23];
  const float* w_fe = (const float*)d_in[24];
  const float* b_fe = (const float*)d_in[25];
  const float* g_fe = (const float*)d_in[26];
  const float* be_fe = (const float*)d_in[27];
  const float* w_rc1 = (const float*)d_in[28];
  const float* b_rc1 = (const float*)d_in[29];
  const float* g_rc = (const float*)d_in[30];
  const float* be_rc = (const float*)d_in[31];
  const float* w_rc2 = (const float*)d_in[32];
  const float* b_rc2 = (const float*)d_in[33];

  float* out = (float*)d_out;
  float* ws = (float*)d_ws;
  float* x2 = ws + WS_X2;
  float* crfb = ws + WS_CRF;
  float* rel = ws + WS_REL;
  unsigned short* entb = (unsigned short*)(ws + WS_ENT);
  unsigned short* wg1t = (unsigned short*)(ws + WS_WG1T);
  unsigned short* wg2t = (unsigned short*)(ws + WS_WG2T);
  unsigned short* x1b = (unsigned short*)(ws + WS_X1);
  unsigned short* w1t = (unsigned short*)(ws + WS_W1T);
  unsigned short* feb = (unsigned short*)(ws + WS_FE);
  unsigned short* wrt = (unsigned short*)(ws + WS_WRT);    // dead ENT region
  unsigned short* wfet = (unsigned short*)(ws + WS_WFET);  // dead ENT region
  float* segm = ws + WS_SEG;                               // dead ENT region

  hipMemsetAsync(rel, 0, sizeof(float), stream);

  // 1) weight transposes + entity pooling (independent)
  k_prep<<<2074, 256, 0, stream>>>(w_ner1, w_gat1, w_gat2, seq, est, elen,
                                   w1t, wg1t, wg2t, entb);
  // 2) GAT1 (256 blocks) + NER head 32-tok (1024 blocks), co-resident
  k_main<<<1280, 256, 0, stream>>>(seq, w1t, b_ner1, w_ner2, b_ner2, out,
                                   entb, wg1t, a_src1, a_dst1, adj, b_gat1, x1b);
  // 3) weight converts (ENT region now dead) + CRF segment reduce
  k_mid<<<1082, 256, 0, stream>>>(w_rc1, w_fe, wrt, wfet, out, amask, crf_trans, segm);
  // 4) GAT2 MFMA + CRF finalize, co-resident
  k_late<<<128, 256, 0, stream>>>(x1b, wg2t, a_src2, a_dst2, adj, b_gat2, x2,
                                  out, nlab, amask, crf_start, crf_end, crf_trans,
                                  segm, crfb);
  // 5) pair features (inlined) + fe
  k_fe<<<64, 256, 0, stream>>>(x2, pe1, pe2, wfet, b_fe, g_fe, be_fe, feb);
  // 6) relation heads
  k_rc<<<NR * NB, 256, 0, stream>>>(feb, wrt, b_rc1, g_rc, be_rc, w_rc2, b_rc2,
                                    plab, out + ZOFF, rel);
  // 7) total
  k_fin<<<1, 64, 0, stream>>>(crfb, rel, out);
}

// Round 8
// 393.522 us; speedup vs baseline: 1.3307x; 1.0976x over previous
//
#include <hip/hip_runtime.h>
#include <math.h>

// Problem: NERRelationModel_84963043050124
// B=64 S=512 H=768 E=32 P=16 K=9 R=6 HEADS=4 C1=128 C2=64 FEAT=257
// Outputs: ner_logits [B,S,K]=294912, z [R,B,P]=6144, total [1] -> 301057 f32

#define NB 64
#define NS 512
#define NH 768
#define NE 32
#define NP 16
#define NK 9
#define NR 6
#define NHEADS 4
#define NC1 128
#define NC2 64
#define SEGS 16
#define SEGLEN 32

#define ZOFF 294912
#define TOTOFF 301056

// ---- workspace layout (float offsets) ----
#define WS_ENT   0u           // bf16 entb [B,E,768] (dead after k_g1f -> WRT/WFET/SEG)
#define WS_WG1T  1572864u     // bf16 wg1t [512][768]
#define WS_X1    2621440u     // bf16 x1b [B,E,512]
#define WS_X2    3801088u     // f32 [B,E,64]
#define WS_WG2T  3956736u     // bf16 wg2t [64][512]
#define WS_FE    4222976u     // bf16 [B,P,512]
#define WS_CRF   4747264u     // [64]
#define WS_REL   4747328u     // [1]
#define WS_W1T   4747392u     // bf16 [256][768]
// overlapped into dead ENT region (valid after k_g1f consumed entb):
#define WS_WRT   0u           // bf16 [R*256][512]
#define WS_WFET  393216u      // bf16 [512][320]
#define WS_SEG   475136u      // f32 [B][SEGS][81]

typedef __attribute__((ext_vector_type(8))) short bf16x8;
typedef __attribute__((ext_vector_type(4))) float f32x4;

__device__ __forceinline__ unsigned short f2bf(float x) {
  union { float f; unsigned u; } v; v.f = x;
  unsigned r = v.u + 0x7FFFu + ((v.u >> 16) & 1u);
  return (unsigned short)(r >> 16);
}

__device__ __forceinline__ float logsigf(float x) {
  if (x >= 0.f) return -log1pf(__expf(-x));
  return x - log1pf(__expf(x));
}

// ---------------- k_prep: weight transposes (w_ner1/w_gat1/w_gat2) + entity pool ----------------
// blocks 0..7: w1t; 8..23: wg1t; 24..25: wg2t; 26..2073: ent pool -> entb bf16.
__global__ __launch_bounds__(256) void k_prep(
    const float* __restrict__ w1, const float* __restrict__ wg1,
    const float* __restrict__ wg2, const float* __restrict__ seq,
    const int* __restrict__ est, const int* __restrict__ elen,
    unsigned short* __restrict__ w1t, unsigned short* __restrict__ wg1t,
    unsigned short* __restrict__ wg2t, unsigned short* __restrict__ entb) {
  __shared__ unsigned short tr[32 * 776];  // [col-in-tile][k]
  const int bid = blockIdx.x, t = threadIdx.x;
  if (bid < 26) {
    const float* src;
    unsigned short* dst;
    int c0, ncol, nkt, kdim;
    if (bid < 8)       { src = w1;  dst = w1t;  ncol = 256; c0 = bid * 32;        nkt = 24; kdim = 768; }
    else if (bid < 24) { src = wg1; dst = wg1t; ncol = 512; c0 = (bid - 8) * 32;  nkt = 24; kdim = 768; }
    else               { src = wg2; dst = wg2t; ncol = 64;  c0 = (bid - 24) * 32; nkt = 16; kdim = 512; }
    for (int p = 0; p < nkt; p++) {
      const int k = p * 32 + (t >> 3), c4 = t & 7;
      const float4 f = *reinterpret_cast<const float4*>(&src[(size_t)k * ncol + c0 + c4 * 4]);
      tr[(c4 * 4 + 0) * 776 + k] = f2bf(f.x);
      tr[(c4 * 4 + 1) * 776 + k] = f2bf(f.y);
      tr[(c4 * 4 + 2) * 776 + k] = f2bf(f.z);
      tr[(c4 * 4 + 3) * 776 + k] = f2bf(f.w);
    }
    __syncthreads();
    const int c = t >> 3, q = t & 7;
    const int chunk = kdim >> 3;  // 96 or 64 k per q
    for (int i = 0; i < (chunk >> 3); i++) {
      *reinterpret_cast<uint4*>(&dst[(size_t)(c0 + c) * kdim + q * chunk + i * 8]) =
          *reinterpret_cast<const uint4*>(&tr[c * 776 + q * chunk + i * 8]);
    }
  } else {
    const int be = bid - 26;
    const int b = be >> 5, e = be & 31;
    const int st = est[b * NE + e];
    int en = st + elen[b * NE + e];
    en = min(max(en, 0), NS - 1);
    const float inv = 1.f / (float)(en - st + 1);
    for (int c = t; c < NH; c += 256) {
      float s = 0.f;
      for (int r = st; r <= en; r++) s += seq[((size_t)b * NS + r) * NH + c];
      entb[((size_t)b * NE + e) * NH + c] = f2bf(s * inv);
    }
  }
}

// ---------------- fused GAT1 (standalone): MFMA GEMM + dots + softmax + aggregate + relu, bf16 out ----------------
__global__ __launch_bounds__(256) void k_g1f(
    const unsigned short* __restrict__ entb, const unsigned short* __restrict__ wg1t,
    const float* __restrict__ as1, const float* __restrict__ ad1,
    const unsigned char* __restrict__ adj, const float* __restrict__ bias1,
    unsigned short* __restrict__ x1b) {
  __shared__ unsigned short As[32 * 40];
  __shared__ unsigned short Bs[128 * 40];
  __shared__ float Hs[32 * 132];
  __shared__ float Att[32 * 32];   // [j][i]
  __shared__ float Sv[32], Dv[32];
  const int bid = blockIdx.x, t = threadIdx.x;
  const int w = t >> 6, lane = t & 63, quad = lane >> 4, l15 = lane & 15;
  const int b = bid >> 2, hd = bid & 3;

  f32x4 acc[2][2];
#pragma unroll
  for (int r = 0; r < 2; r++)
#pragma unroll
    for (int c = 0; c < 2; c++) acc[r][c] = (f32x4){0.f, 0.f, 0.f, 0.f};

  const int rowA = t >> 2, koffA = (t & 3) * 8;  // t<128 stages A
  const unsigned short* aptr = entb + ((size_t)(b * NE) + rowA) * NH + koffA;

  for (int kt = 0; kt < NH; kt += 32) {
    __syncthreads();
    if (t < 128) {
      *reinterpret_cast<uint4*>(&As[rowA * 40 + koffA]) =
          *reinterpret_cast<const uint4*>(aptr + kt);
    }
#pragma unroll
    for (int i = 0; i < 2; i++) {
      const int q = t + 256 * i;
      const int col = q >> 2, koff = (q & 3) * 8;
      *reinterpret_cast<uint4*>(&Bs[col * 40 + koff]) =
          *reinterpret_cast<const uint4*>(&wg1t[(size_t)(hd * 128 + col) * NH + kt + koff]);
    }
    __syncthreads();
    bf16x8 a[2], bb[2];
#pragma unroll
    for (int r = 0; r < 2; r++)
      a[r] = *reinterpret_cast<const bf16x8*>(&As[(r * 16 + l15) * 40 + quad * 8]);
#pragma unroll
    for (int c = 0; c < 2; c++)
      bb[c] = *reinterpret_cast<const bf16x8*>(&Bs[(w * 32 + c * 16 + l15) * 40 + quad * 8]);
#pragma unroll
    for (int r = 0; r < 2; r++)
#pragma unroll
      for (int c = 0; c < 2; c++)
        acc[r][c] = __builtin_amdgcn_mfma_f32_16x16x32_bf16(a[r], bb[c], acc[r][c], 0, 0, 0);
  }
#pragma unroll
  for (int r = 0; r < 2; r++)
#pragma unroll
    for (int c = 0; c < 2; c++)
#pragma unroll
      for (int reg = 0; reg < 4; reg++)
        Hs[(r * 16 + quad * 4 + reg) * 132 + w * 32 + c * 16 + l15] = acc[r][c][reg];
  __syncthreads();
  {
    const int e = t >> 3, cg = t & 7;
    float sv = 0.f, dv = 0.f;
#pragma unroll
    for (int c = 0; c < 16; c++) {
      const float h = Hs[e * 132 + cg * 16 + c];
      sv += h * as1[hd * NC1 + cg * 16 + c];
      dv += h * ad1[hd * NC1 + cg * 16 + c];
    }
#pragma unroll
    for (int o = 1; o < 8; o <<= 1) { sv += __shfl_xor(sv, o); dv += __shfl_xor(dv, o); }
    if (cg == 0) { Sv[e] = sv; Dv[e] = dv; }
  }
  __syncthreads();
  if (t < 32) {
    const int i = t;
    const float di = Dv[i];
    float lg[32];
    float m = -1e30f;
#pragma unroll
    for (int j = 0; j < 32; j++) {
      float v = di + Sv[j];
      v = v >= 0.f ? v : 0.2f * v;
      if (!adj[((size_t)b * NE + i) * NE + j]) v = -1e9f;
      lg[j] = v; m = fmaxf(m, v);
    }
    float sum = 0.f;
#pragma unroll
    for (int j = 0; j < 32; j++) { lg[j] = __expf(lg[j] - m); sum += lg[j]; }
    const float inv = 1.f / sum;
#pragma unroll
    for (int j = 0; j < 32; j++) Att[j * 32 + i] = lg[j] * inv;
  }
  __syncthreads();
  {
    const int tc = t & 31, tr2 = t >> 5;
#pragma unroll
    for (int i = 0; i < 4; i++) {
      const int row = tr2 * 4 + i;
      float o0 = bias1[hd * NC1 + tc * 4 + 0];
      float o1 = bias1[hd * NC1 + tc * 4 + 1];
      float o2 = bias1[hd * NC1 + tc * 4 + 2];
      float o3 = bias1[hd * NC1 + tc * 4 + 3];
#pragma unroll
      for (int j = 0; j < 32; j++) {
        const float a = Att[j * 32 + row];
        o0 = fmaf(a, Hs[j * 132 + tc * 4 + 0], o0);
        o1 = fmaf(a, Hs[j * 132 + tc * 4 + 1], o1);
        o2 = fmaf(a, Hs[j * 132 + tc * 4 + 2], o2);
        o3 = fmaf(a, Hs[j * 132 + tc * 4 + 3], o3);
      }
      uint2 v;
      v.x = (unsigned)f2bf(fmaxf(o0, 0.f)) | ((unsigned)f2bf(fmaxf(o1, 0.f)) << 16);
      v.y = (unsigned)f2bf(fmaxf(o2, 0.f)) | ((unsigned)f2bf(fmaxf(o3, 0.f)) << 16);
      *reinterpret_cast<uint2*>(&x1b[((size_t)b * NE + row) * 512 + hd * 128 + tc * 4]) = v;
    }
  }
}

// ---------------- NER head (standalone): MFMA bf16, 32-token x 256-col tiles ----------------
// 1024 blocks = 4 blocks/CU (vs R0's 2); proven 2-barrier structure, own 96-VGPR budget.
__global__ __launch_bounds__(256) void k_ner(const float* __restrict__ seq,
    const unsigned short* __restrict__ w1t, const float* __restrict__ b1,
    const float* __restrict__ w2, const float* __restrict__ b2,
    float* __restrict__ out) {
  __shared__ unsigned short AsS[32 * 40];
  __shared__ unsigned short BsS[256 * 40];
  __shared__ float zs[32 * 4 * 12];
  const int t = threadIdx.x;
  const int tok0 = blockIdx.x * 32;
  const int w = t >> 6, lane = t & 63, quad = lane >> 4, l15 = lane & 15;

  f32x4 acc[2][4];
#pragma unroll
  for (int r = 0; r < 2; r++)
#pragma unroll
    for (int c = 0; c < 4; c++) acc[r][c] = (f32x4){0.f, 0.f, 0.f, 0.f};

  const int tokA = t >> 3, koffA = (t & 7) * 4;  // 4 floats per thread
  const float* aptr = seq + (size_t)(tok0 + tokA) * NH + koffA;

  for (int kt = 0; kt < NH; kt += 32) {
    __syncthreads();
    {
      const float4 f0 = *reinterpret_cast<const float4*>(aptr + kt);
      uint2 v;
      v.x = (unsigned)f2bf(f0.x) | ((unsigned)f2bf(f0.y) << 16);
      v.y = (unsigned)f2bf(f0.z) | ((unsigned)f2bf(f0.w) << 16);
      *reinterpret_cast<uint2*>(&AsS[tokA * 40 + koffA]) = v;
    }
#pragma unroll
    for (int i = 0; i < 4; i++) {
      const int q = t + 256 * i;
      const int col = q >> 2, koff = (q & 3) * 8;
      *reinterpret_cast<uint4*>(&BsS[col * 40 + koff]) =
          *reinterpret_cast<const uint4*>(&w1t[(size_t)col * NH + kt + koff]);
    }
    __syncthreads();
    bf16x8 a[2], b[4];
#pragma unroll
    for (int r = 0; r < 2; r++)
      a[r] = *reinterpret_cast<const bf16x8*>(&AsS[(r * 16 + l15) * 40 + quad * 8]);
#pragma unroll
    for (int c = 0; c < 4; c++)
      b[c] = *reinterpret_cast<const bf16x8*>(&BsS[(w * 64 + c * 16 + l15) * 40 + quad * 8]);
#pragma unroll
    for (int r = 0; r < 2; r++)
#pragma unroll
      for (int c = 0; c < 4; c++)
        acc[r][c] = __builtin_amdgcn_mfma_f32_16x16x32_bf16(a[r], b[c], acc[r][c], 0, 0, 0);
  }

  float b1v[4], w2v[4][NK];
#pragma unroll
  for (int c = 0; c < 4; c++) {
    const int col = w * 64 + c * 16 + l15;
    b1v[c] = b1[col];
#pragma unroll
    for (int cc = 0; cc < NK; cc++) w2v[c][cc] = w2[col * NK + cc];
  }
#pragma unroll
  for (int r = 0; r < 2; r++) {
#pragma unroll
    for (int reg = 0; reg < 4; reg++) {
      float p[NK];
#pragma unroll
      for (int cc = 0; cc < NK; cc++) p[cc] = 0.f;
#pragma unroll
      for (int c = 0; c < 4; c++) {
        const float h = fmaxf(acc[r][c][reg] + b1v[c], 0.f);
#pragma unroll
        for (int cc = 0; cc < NK; cc++) p[cc] = fmaf(h, w2v[c][cc], p[cc]);
      }
#pragma unroll
      for (int o = 1; o < 16; o <<= 1)
#pragma unroll
        for (int cc = 0; cc < NK; cc++) p[cc] += __shfl_xor(p[cc], o);
      if (l15 == 0) {
        const int tokr = r * 16 + quad * 4 + reg;
#pragma unroll
        for (int cc = 0; cc < NK; cc++) zs[(tokr * 4 + w) * 12 + cc] = p[cc];
      }
    }
  }
  __syncthreads();
  if (t < 32) {
#pragma unroll
    for (int cc = 0; cc < NK; cc++) {
      const float z = zs[(t * 4 + 0) * 12 + cc] + zs[(t * 4 + 1) * 12 + cc] +
                      zs[(t * 4 + 2) * 12 + cc] + zs[(t * 4 + 3) * 12 + cc] + b2[cc];
      out[(size_t)(tok0 + t) * NK + cc] = z;
    }
  }
}

// ---------------- k_mid: weight converts (blocks 0..57) + CRF segment reduce (58..1081) ----------------
__global__ __launch_bounds__(256) void k_mid(
    const float* __restrict__ wrc, const float* __restrict__ wfe,
    unsigned short* __restrict__ wrt, unsigned short* __restrict__ wfet,
    const float* __restrict__ em, const int* __restrict__ mask,
    const float* __restrict__ trans, float* __restrict__ segm) {
  __shared__ __align__(16) char smem[36864];
  const int bid = blockIdx.x, t = threadIdx.x;
  if (bid < 58) {
    unsigned short* tr = (unsigned short*)smem;  // [256*72]
    if (bid < 48) {
      const int r = bid >> 3, kt = bid & 7;
      const int k0 = kt * 64;
#pragma unroll
      for (int i = 0; i < 16; i++) {
        const int slot = t + 256 * i;
        const int row = slot >> 6, c4 = slot & 63;
        const float4 f = *reinterpret_cast<const float4*>(
            &wrc[((size_t)(r * 512) + k0 + row) * 256 + c4 * 4]);
        tr[(c4 * 4 + 0) * 72 + row] = f2bf(f.x);
        tr[(c4 * 4 + 1) * 72 + row] = f2bf(f.y);
        tr[(c4 * 4 + 2) * 72 + row] = f2bf(f.z);
        tr[(c4 * 4 + 3) * 72 + row] = f2bf(f.w);
      }
      __syncthreads();
#pragma unroll
      for (int i = 0; i < 8; i++) {
        const int slot = t + 256 * i;
        const int col = slot >> 3, q = slot & 7;
        *reinterpret_cast<uint4*>(&wrt[((size_t)(r * 256 + col)) * 512 + k0 + q * 8]) =
            *reinterpret_cast<const uint4*>(&tr[col * 72 + q * 8]);
      }
    } else {
      const int b2 = bid - 48;
      const int kt = b2 % 5, cb = b2 / 5;
      const int k0 = kt * 64, c0 = cb * 256;
#pragma unroll
      for (int i = 0; i < 16; i++) {
        const int slot = t + 256 * i;
        const int row = slot >> 6, c4 = slot & 63;
        const int k = k0 + row;
        float4 f = {0.f, 0.f, 0.f, 0.f};
        if (k < 257)
          f = *reinterpret_cast<const float4*>(&wfe[(size_t)k * 512 + c0 + c4 * 4]);
        tr[(c4 * 4 + 0) * 72 + row] = f2bf(f.x);
        tr[(c4 * 4 + 1) * 72 + row] = f2bf(f.y);
        tr[(c4 * 4 + 2) * 72 + row] = f2bf(f.z);
        tr[(c4 * 4 + 3) * 72 + row] = f2bf(f.w);
      }
      __syncthreads();
#pragma unroll
      for (int i = 0; i < 8; i++) {
        const int slot = t + 256 * i;
        const int col = slot >> 3, q = slot & 7;
        *reinterpret_cast<uint4*>(&wfet[((size_t)(c0 + col)) * 320 + k0 + q * 8]) =
            *reinterpret_cast<const uint4*>(&tr[col * 72 + q * 8]);
      }
    }
  } else {
    float* bufA = (float*)smem;             // [16*81]
    float* bufB = (float*)(smem + 5184);    // [8*81]
    float* ems  = (float*)(smem + 7776);    // [SEGLEN*9]
    int*   mks  = (int*)(smem + 8928);      // [SEGLEN]
    float* trs  = (float*)(smem + 9056);    // [81]
    const int blk = bid - 58;
    const int b = blk >> 4, seg = blk & 15;
    const int s0 = 1 + seg * SEGLEN;
    const float* emb = em + (size_t)b * NS * NK;
    const int* mk = mask + b * NS;
    if (t < 81) trs[t] = trans[t];
    for (int i = t; i < SEGLEN * 9; i += 256) {
      const int g = s0 * 9 + i;
      ems[i] = (g < NS * 9) ? emb[g] : 0.f;
    }
    if (t < SEGLEN) {
      const int s = s0 + t;
      mks[t] = (s < NS) ? mk[s] : 0;
    }
    __syncthreads();
    for (int idx = t; idx < 16 * 81; idx += 256) {
      const int p = idx / 81, e = idx % 81, i = e / 9, j = e % 9;
      const int la = 2 * p, lb = la + 1;
      const bool ma = mks[la] > 0, mb = mks[lb] > 0;
      float r;
      if (ma && mb) {
        float v[9], mx = -1e30f;
#pragma unroll
        for (int m = 0; m < 9; m++) {
          v[m] = trs[i * 9 + m] + ems[la * 9 + m] + trs[m * 9 + j];
          mx = fmaxf(mx, v[m]);
        }
        float sum = 0.f;
#pragma unroll
        for (int m = 0; m < 9; m++) sum += __expf(v[m] - mx);
        r = mx + __logf(sum) + ems[lb * 9 + j];
      } else if (ma) {
        r = trs[e] + ems[la * 9 + j];
      } else if (mb) {
        r = trs[e] + ems[lb * 9 + j];
      } else {
        r = (i == j) ? 0.f : -1e30f;
      }
      bufA[p * 81 + e] = r;
    }
    float* src = bufA;
    float* dst = bufB;
    for (int n = 16; n > 1; n >>= 1) {
      __syncthreads();
      const int half = n >> 1;
      for (int idx = t; idx < half * 81; idx += 256) {
        const int q = idx / 81, e = idx % 81, i = e / 9, j = e % 9;
        const float* A = src + (size_t)(2 * q) * 81;
        const float* Bm = src + (size_t)(2 * q + 1) * 81;
        float v[9], mx = -1e30f;
#pragma unroll
        for (int m = 0; m < 9; m++) {
          v[m] = A[i * 9 + m] + Bm[m * 9 + j];
          mx = fmaxf(mx, v[m]);
        }
        float sum = 0.f;
#pragma unroll
        for (int m = 0; m < 9; m++) sum += __expf(v[m] - mx);
        dst[q * 81 + e] = mx + __logf(sum);
      }
      float* tmp = src; src = dst; dst = tmp;
    }
    __syncthreads();
    if (t < 81) segm[((size_t)b * SEGS + seg) * 81 + t] = src[t];
  }
}

// ---------------- k_late: fused GAT2 MFMA (blocks 0..63) + CRF finalize (64..127) ----------------
__global__ __launch_bounds__(256) void k_late(
    const unsigned short* __restrict__ x1b, const unsigned short* __restrict__ wg2t,
    const float* __restrict__ as2, const float* __restrict__ ad2,
    const unsigned char* __restrict__ adj, const float* __restrict__ bias2,
    float* __restrict__ x2,
    const float* __restrict__ em, const int* __restrict__ tags,
    const int* __restrict__ mask, const float* __restrict__ startv,
    const float* __restrict__ endv, const float* __restrict__ trans,
    const float* __restrict__ segm, float* __restrict__ lossb) {
  __shared__ __align__(16) char smem[20736];
  const int bid = blockIdx.x, t = threadIdx.x;
  if (bid < 64) {
    // ======== GAT2: MFMA bf16 GEMM (K=512) + dots + softmax + aggregate ========
    unsigned short* As = (unsigned short*)smem;           // [32*40]
    unsigned short* Bs = (unsigned short*)(smem + 2560);  // [64*40]
    float* H2  = (float*)(smem + 7680);                   // [32*68]
    float* Att = (float*)(smem + 16384);                  // [32*32] ([j][i])
    float* Sv  = (float*)(smem + 20480);                  // [32]
    float* Dv  = (float*)(smem + 20608);                  // [32]
    const int b = bid;
    const int w = t >> 6, lane = t & 63, quad = lane >> 4, l15 = lane & 15;

    f32x4 acc[2];
#pragma unroll
    for (int r = 0; r < 2; r++) acc[r] = (f32x4){0.f, 0.f, 0.f, 0.f};

    const int rowA = t >> 2, koffA = (t & 3) * 8;  // t<128 stages A
    const unsigned short* aptr = x1b + ((size_t)(b * NE) + rowA) * 512 + koffA;

    for (int kt = 0; kt < 512; kt += 32) {
      __syncthreads();
      if (t < 128) {
        *reinterpret_cast<uint4*>(&As[rowA * 40 + koffA]) =
            *reinterpret_cast<const uint4*>(aptr + kt);
      }
      {
        const int col = t >> 2, koff = (t & 3) * 8;  // 64 cols x 4 chunks
        *reinterpret_cast<uint4*>(&Bs[col * 40 + koff]) =
            *reinterpret_cast<const uint4*>(&wg2t[(size_t)col * 512 + kt + koff]);
      }
      __syncthreads();
      const bf16x8 a0 = *reinterpret_cast<const bf16x8*>(&As[l15 * 40 + quad * 8]);
      const bf16x8 a1 = *reinterpret_cast<const bf16x8*>(&As[(16 + l15) * 40 + quad * 8]);
      const bf16x8 bb = *reinterpret_cast<const bf16x8*>(&Bs[(w * 16 + l15) * 40 + quad * 8]);
      acc[0] = __builtin_amdgcn_mfma_f32_16x16x32_bf16(a0, bb, acc[0], 0, 0, 0);
      acc[1] = __builtin_amdgcn_mfma_f32_16x16x32_bf16(a1, bb, acc[1], 0, 0, 0);
    }
#pragma unroll
    for (int r = 0; r < 2; r++)
#pragma unroll
      for (int reg = 0; reg < 4; reg++)
        H2[(r * 16 + quad * 4 + reg) * 68 + w * 16 + l15] = acc[r][reg];
    __syncthreads();
    {
      const int e = t >> 3, cg = t & 7;
      float sv = 0.f, dv = 0.f;
#pragma unroll
      for (int c = 0; c < 8; c++) {
        const float h = H2[e * 68 + cg * 8 + c];
        sv += h * as2[cg * 8 + c];
        dv += h * ad2[cg * 8 + c];
      }
#pragma unroll
      for (int o = 1; o < 8; o <<= 1) { sv += __shfl_xor(sv, o); dv += __shfl_xor(dv, o); }
      if (cg == 0) { Sv[e] = sv; Dv[e] = dv; }
    }
    __syncthreads();
    if (t < 32) {
      const int i = t;
      const float di = Dv[i];
      float lg[32];
      float m = -1e30f;
#pragma unroll
      for (int j = 0; j < 32; j++) {
        float v = di + Sv[j];
        v = v >= 0.f ? v : 0.2f * v;
        if (!adj[((size_t)b * NE + i) * NE + j]) v = -1e9f;
        lg[j] = v; m = fmaxf(m, v);
      }
      float sum = 0.f;
#pragma unroll
      for (int j = 0; j < 32; j++) { lg[j] = __expf(lg[j] - m); sum += lg[j]; }
      const float inv = 1.f / sum;
#pragma unroll
      for (int j = 0; j < 32; j++) Att[j * 32 + i] = lg[j] * inv;
    }
    __syncthreads();
    {
      const int tc = t & 15, tr2 = t >> 4;
#pragma unroll
      for (int i = 0; i < 2; i++) {
        const int row = tr2 * 2 + i;
        float o0 = bias2[tc * 4 + 0];
        float o1 = bias2[tc * 4 + 1];
        float o2 = bias2[tc * 4 + 2];
        float o3 = bias2[tc * 4 + 3];
#pragma unroll
        for (int j = 0; j < 32; j++) {
          const float a = Att[j * 32 + row];
          o0 = fmaf(a, H2[j * 68 + tc * 4 + 0], o0);
          o1 = fmaf(a, H2[j * 68 + tc * 4 + 1], o1);
          o2 = fmaf(a, H2[j * 68 + tc * 4 + 2], o2);
          o3 = fmaf(a, H2[j * 68 + tc * 4 + 3], o3);
        }
        float4 v;
        v.x = o0; v.y = o1; v.z = o2; v.w = o3;
        *reinterpret_cast<float4*>(&x2[((size_t)b * NE + row) * NC2 + tc * 4]) = v;
      }
    }
  } else {
    // ======== CRF finalize (256 threads; compute guarded to original lanes) ========
    float* sm  = (float*)smem;            // [SEGS*81]
    float* av  = (float*)(smem + 5184);   // [16]
    float* red = (float*)(smem + 5248);   // [2]
    const int b = bid - 64;
    const float* emb = em + (size_t)b * NS * NK;
    const int* mk = mask + b * NS;
    const int* tg = tags + b * NS;
    for (int i = t; i < SEGS * 81; i += 256) sm[i] = segm[(size_t)b * SEGS * 81 + i];
    if (t < 64) {
      float num = 0.f;
      int lastS = 0;
#pragma unroll
      for (int o = 0; o < 8; o++) {
        const int s = t * 8 + o;
        if (s >= 1 && mk[s] > 0) {
          const int cur = tg[s], prv = tg[s - 1];
          num += trans[prv * NK + cur] + emb[s * NK + cur];
          lastS = s;
        }
      }
#pragma unroll
      for (int o = 32; o > 0; o >>= 1) {
        num += __shfl_xor(num, o);
        lastS = max(lastS, __shfl_xor(lastS, o));
      }
      if (t == 0) {
        const int t0 = tg[0];
        red[0] = startv[t0] + emb[t0] + num + endv[tg[lastS]];
      }
    }
    __syncthreads();
    if (t < 9) av[t] = startv[t] + emb[t];
    __syncthreads();
    for (int h = 0; h < SEGS; h++) {
      float nv = 0.f;
      if (t < 9) {
        float v[9], mx = -1e30f;
#pragma unroll
        for (int i2 = 0; i2 < 9; i2++) {
          v[i2] = av[i2] + sm[h * 81 + i2 * 9 + t];
          mx = fmaxf(mx, v[i2]);
        }
        float sum = 0.f;
#pragma unroll
        for (int i2 = 0; i2 < 9; i2++) sum += __expf(v[i2] - mx);
        nv = mx + __logf(sum);
      }
      __syncthreads();
      if (t < 9) av[t] = nv;
      __syncthreads();
    }
    if (t == 0) {
      float mx = -1e30f;
#pragma unroll
      for (int j = 0; j < 9; j++) mx = fmaxf(mx, av[j] + endv[j]);
      float sum = 0.f;
#pragma unroll
      for (int j = 0; j < 9; j++) sum += __expf(av[j] + endv[j] - mx);
      lossb[b] = (mx + __logf(sum)) - red[0];
    }
  }
}

// ---------------- k_fe: pair-features (inlined) + MFMA + LN + leaky, bf16 out ----------------
__global__ __launch_bounds__(256) void k_fe(const float* __restrict__ x2,
    const int* __restrict__ pe1, const int* __restrict__ pe2,
    const unsigned short* __restrict__ wt, const float* __restrict__ bfe,
    const float* __restrict__ g, const float* __restrict__ be,
    unsigned short* __restrict__ feb) {
  __shared__ unsigned short Af[16 * 320];
  __shared__ float Cs[16 * 520];
  __shared__ float ctxs[64];
  const int b = blockIdx.x, t = threadIdx.x;
  const int w = t >> 6, lane = t & 63, quad = lane >> 4, l15 = lane & 15;
  if (t < 64) {
    float cs = 0.f;
    for (int e = 0; e < NE; e++) cs += x2[((size_t)b * NE + e) * NC2 + t];
    ctxs[t] = cs * (1.f / NE);
  }
  __syncthreads();
  for (int i = t; i < 16 * 320; i += 256) {
    const int p = i / 320, k = i - p * 320;
    unsigned short o = 0;
    if (k < 260) {
      const int e1 = pe1[b * NP + p], e2 = pe2[b * NP + p];
      float v;
      if (k < 64) v = x2[((size_t)b * NE + e1) * NC2 + k];
      else if (k < 128) v = x2[((size_t)b * NE + e2) * NC2 + (k - 64)];
      else if (k < 192) v = x2[((size_t)b * NE + e1) * NC2 + (k - 128)] *
                            x2[((size_t)b * NE + e2) * NC2 + (k - 128)];
      else if (k < 256) v = ctxs[k - 192];
      else if (k == 256) v = logf(fabsf((float)(e1 - e2)) + 1.f);
      else v = 0.f;
      o = f2bf(v);
    }
    Af[i] = o;
  }
  __syncthreads();
  f32x4 acc[8];
#pragma unroll
  for (int c = 0; c < 8; c++) acc[c] = (f32x4){0.f, 0.f, 0.f, 0.f};
#pragma unroll
  for (int kt = 0; kt < 10; kt++) {
    const bf16x8 a = *reinterpret_cast<const bf16x8*>(&Af[l15 * 320 + kt * 32 + quad * 8]);
#pragma unroll
    for (int c = 0; c < 8; c++) {
      const int col = w * 128 + c * 16 + l15;
      const bf16x8 bv = *reinterpret_cast<const bf16x8*>(&wt[(size_t)col * 320 + kt * 32 + quad * 8]);
      acc[c] = __builtin_amdgcn_mfma_f32_16x16x32_bf16(a, bv, acc[c], 0, 0, 0);
    }
  }
#pragma unroll
  for (int c = 0; c < 8; c++)
#pragma unroll
    for (int reg = 0; reg < 4; reg++)
      Cs[(quad * 4 + reg) * 520 + w * 128 + c * 16 + l15] = acc[c][reg];
  __syncthreads();
  float bfev[8], gv[8], bev[8];
#pragma unroll
  for (int ch = 0; ch < 8; ch++) {
    const int col = ch * 64 + lane;
    bfev[ch] = bfe[col]; gv[ch] = g[col]; bev[ch] = be[col];
  }
#pragma unroll
  for (int pp = 0; pp < 4; pp++) {
    const int p = w * 4 + pp;
    float v[8], s = 0.f, sq = 0.f;
#pragma unroll
    for (int ch = 0; ch < 8; ch++) {
      v[ch] = Cs[p * 520 + ch * 64 + lane] + bfev[ch];
      s += v[ch]; sq += v[ch] * v[ch];
    }
#pragma unroll
    for (int o = 32; o > 0; o >>= 1) { s += __shfl_xor(s, o); sq += __shfl_xor(sq, o); }
    const float mean = s * (1.f / 512.f);
    const float var = sq * (1.f / 512.f) - mean * mean;
    const float rr = rsqrtf(var + 1e-5f);
#pragma unroll
    for (int ch = 0; ch < 8; ch++) {
      float n = (v[ch] - mean) * rr * gv[ch] + bev[ch];
      n = n >= 0.f ? n : 0.01f * n;
      feb[(size_t)(b * NP + p) * 512 + ch * 64 + lane] = f2bf(n);
    }
  }
}

// ---------------- relation heads: MFMA bf16 GEMM + LN + leaky + dot + BCE ----------------
__global__ __launch_bounds__(256) void k_rc(const unsigned short* __restrict__ feb,
    const unsigned short* __restrict__ wrt, const float* __restrict__ b1,
    const float* __restrict__ g, const float* __restrict__ be,
    const float* __restrict__ w2, const float* __restrict__ b2,
    const int* __restrict__ ylab, float* __restrict__ zout, float* __restrict__ relacc) {
  __shared__ unsigned short Af[16 * 520];
  __shared__ float Cs[16 * 264];
  const int blk = blockIdx.x;
  const int r = blk >> 6, b = blk & 63;
  const int t = threadIdx.x;
  const int w = t >> 6, lane = t & 63, quad = lane >> 4, l15 = lane & 15;
#pragma unroll
  for (int i = 0; i < 4; i++) {
    const int slot = t + 256 * i;
    const int p = slot >> 6, q = slot & 63;
    *reinterpret_cast<uint4*>(&Af[p * 520 + q * 8]) =
        *reinterpret_cast<const uint4*>(&feb[(size_t)(b * NP + p) * 512 + q * 8]);
  }
  __syncthreads();
  f32x4 acc[4];
#pragma unroll
  for (int c = 0; c < 4; c++) acc[c] = (f32x4){0.f, 0.f, 0.f, 0.f};
#pragma unroll
  for (int kt = 0; kt < 16; kt++) {
    const bf16x8 a = *reinterpret_cast<const bf16x8*>(&Af[l15 * 520 + kt * 32 + quad * 8]);
#pragma unroll
    for (int c = 0; c < 4; c++) {
      const int col = w * 64 + c * 16 + l15;
      const bf16x8 bv = *reinterpret_cast<const bf16x8*>(
          &wrt[(size_t)(r * 256 + col) * 512 + kt * 32 + quad * 8]);
      acc[c] = __builtin_amdgcn_mfma_f32_16x16x32_bf16(a, bv, acc[c], 0, 0, 0);
    }
  }
#pragma unroll
  for (int c = 0; c < 4; c++)
#pragma unroll
    for (int reg = 0; reg < 4; reg++)
      Cs[(quad * 4 + reg) * 264 + w * 64 + c * 16 + l15] = acc[c][reg];
  __syncthreads();
  float b1v[4], gv[4], bev[4], w2v[4];
#pragma unroll
  for (int ch = 0; ch < 4; ch++) {
    const int col = r * 256 + ch * 64 + lane;
    b1v[ch] = b1[col]; gv[ch] = g[col]; bev[ch] = be[col]; w2v[ch] = w2[col];
  }
  const float b2v = b2[r];
  float local = 0.f;
#pragma unroll
  for (int pp = 0; pp < 4; pp++) {
    const int p = w * 4 + pp;
    float v[4], s = 0.f, sq = 0.f;
#pragma unroll
    for (int ch = 0; ch < 4; ch++) {
      v[ch] = Cs[p * 264 + ch * 64 + lane] + b1v[ch];
      s += v[ch]; sq += v[ch] * v[ch];
    }
#pragma unroll
    for (int o = 32; o > 0; o >>= 1) { s += __shfl_xor(s, o); sq += __shfl_xor(sq, o); }
    const float mean = s * (1.f / 256.f);
    const float var = sq * (1.f / 256.f) - mean * mean;
    const float rr = rsqrtf(var + 1e-5f);
    float zdot = 0.f;
#pragma unroll
    for (int ch = 0; ch < 4; ch++) {
      float n = (v[ch] - mean) * rr * gv[ch] + bev[ch];
      n = n >= 0.f ? n : 0.01f * n;
      zdot = fmaf(n, w2v[ch], zdot);
    }
#pragma unroll
    for (int o = 32; o > 0; o >>= 1) zdot += __shfl_xor(zdot, o);
    if (lane == 0) {
      const float zp = zdot + b2v;
      zout[(size_t)(r * NB + b) * NP + p] = zp;
      const float y = (float)ylab[b * NP + p];
      local += -(2.f * y * logsigf(zp) + (1.f - y) * logsigf(-zp));
    }
  }
  if (lane == 0) atomicAdd(relacc, local * (1.f / (NB * NP)));
}

// ---------------- finalize total loss ----------------
__global__ __launch_bounds__(64) void k_fin(const float* __restrict__ lossb,
    const float* __restrict__ rel, float* __restrict__ out) {
  float v = lossb[threadIdx.x];
#pragma unroll
  for (int o = 32; o > 0; o >>= 1) v += __shfl_down(v, o);
  if (threadIdx.x == 0) out[TOTOFF] = v * (1.f / NB) + rel[0];
}

extern "C" void kernel_launch(void* const* d_in, const int* in_sizes, int n_in,
                              void* d_out, int out_size, void* d_ws, size_t ws_size,
                              hipStream_t stream) {
  const float* seq = (const float*)d_in[0];
  const int* amask = (const int*)d_in[1];
  const int* nlab = (const int*)d_in[2];
  const int* est = (const int*)d_in[3];
  const int* elen = (const int*)d_in[4];
  const int* pe1 = (const int*)d_in[5];
  const int* pe2 = (const int*)d_in[6];
  const int* plab = (const int*)d_in[7];
  const unsigned char* adj = (const unsigned char*)d_in[8];
  const float* w_ner1 = (const float*)d_in[9];
  const float* b_ner1 = (const float*)d_in[10];
  const float* w_ner2 = (const float*)d_in[11];
  const float* b_ner2 = (const float*)d_in[12];
  const float* crf_start = (const float*)d_in[13];
  const float* crf_end = (const float*)d_in[14];
  const float* crf_trans = (const float*)d_in[15];
  const float* w_gat1 = (const float*)d_in[16];
  const float* a_src1 = (const float*)d_in[17];
  const float* a_dst1 = (const float*)d_in[18];
  const float* b_gat1 = (const float*)d_in[19];
  const float* w_gat2 = (const float*)d_in[20];
  const float* a_src2 = (const float*)d_in[21];
  const float* a_dst2 = (const float*)d_in[22];
  const float* b_gat2 = (const float*)d_in[23];
  const float* w_fe = (const float*)d_in[24];
  const float* b_fe = (const float*)d_in[25];
  const float* g_fe = (const float*)d_in[26];
  const float* be_fe = (const float*)d_in[27];
  const float* w_rc1 = (const float*)d_in[28];
  const float* b_rc1 = (const float*)d_in[29];
  const float* g_rc = (const float*)d_in[30];
  const float* be_rc = (const float*)d_in[31];
  const float* w_rc2 = (const float*)d_in[32];
  const float* b_rc2 = (const float*)d_in[33];

  float* out = (float*)d_out;
  float* ws = (float*)d_ws;
  float* x2 = ws + WS_X2;
  float* crfb = ws + WS_CRF;
  float* rel = ws + WS_REL;
  unsigned short* entb = (unsigned short*)(ws + WS_ENT);
  unsigned short* wg1t = (unsigned short*)(ws + WS_WG1T);
  unsigned short* wg2t = (unsigned short*)(ws + WS_WG2T);
  unsigned short* x1b = (unsigned short*)(ws + WS_X1);
  unsigned short* w1t = (unsigned short*)(ws + WS_W1T);
  unsigned short* feb = (unsigned short*)(ws + WS_FE);
  unsigned short* wrt = (unsigned short*)(ws + WS_WRT);    // dead ENT region
  unsigned short* wfet = (unsigned short*)(ws + WS_WFET);  // dead ENT region
  float* segm = ws + WS_SEG;                               // dead ENT region

  hipMemsetAsync(rel, 0, sizeof(float), stream);

  // 1) weight transposes + entity pooling (independent)
  k_prep<<<2074, 256, 0, stream>>>(w_ner1, w_gat1, w_gat2, seq, est, elen,
                                   w1t, wg1t, wg2t, entb);
  // 2) GAT1 (own 232-VGPR budget), then NER (own ~96-VGPR budget, 4 blocks/CU)
  k_g1f<<<NB * NHEADS, 256, 0, stream>>>(entb, wg1t, a_src1, a_dst1, adj, b_gat1, x1b);
  k_ner<<<1024, 256, 0, stream>>>(seq, w1t, b_ner1, w_ner2, b_ner2, out);
  // 3) weight converts (ENT region now dead) + CRF segment reduce
  k_mid<<<1082, 256, 0, stream>>>(w_rc1, w_fe, wrt, wfet, out, amask, crf_trans, segm);
  // 4) GAT2 MFMA + CRF finalize, co-resident
  k_late<<<128, 256, 0, stream>>>(x1b, wg2t, a_src2, a_dst2, adj, b_gat2, x2,
                                  out, nlab, amask, crf_start, crf_end, crf_trans,
                                  segm, crfb);
  // 5) pair features (inlined) + fe
  k_fe<<<64, 256, 0, stream>>>(x2, pe1, pe2, wfet, b_fe, g_fe, be_fe, feb);
  // 6) relation heads
  k_rc<<<NR * NB, 256, 0, stream>>>(feb, wrt, b_rc1, g_rc, be_rc, w_rc2, b_rc2,
                                    plab, out + ZOFF, rel);
  // 7) total
  k_fin<<<1, 64, 0, stream>>>(crfb, rel, out);
}